// Round 1
// baseline (4910.120 us; speedup 1.0000x reference)
//
#include <hip/hip_runtime.h>
#include <math.h>

#define B_ 8
#define N_ 2048
#define KNN 16

// ---------------------------------------------------------------------------
// KNN on 3D input points. One block = 256 queries of one batch; all 2048
// points staged in LDS. Top-16 kept as a sorted (dist,idx) register array,
// fully unrolled so it stays in VGPRs. Tie-break: (d, idx) lexicographic
// ascending == lax.top_k(-d) semantics.
// ---------------------------------------------------------------------------
__global__ __launch_bounds__(256) void knn3_kernel(const float* __restrict__ x,
                                                   int* __restrict__ idx) {
    __shared__ float pts[N_ * 3];
    int b = blockIdx.y;
    const float* xb = x + (size_t)b * N_ * 3;
    for (int e = threadIdx.x; e < N_ * 3; e += 256) pts[e] = xb[e];
    __syncthreads();

    int i = blockIdx.x * 256 + threadIdx.x;
    float qx = pts[i * 3 + 0], qy = pts[i * 3 + 1], qz = pts[i * 3 + 2];

    float bd[KNN];
    int bi[KNN];
#pragma unroll
    for (int s = 0; s < KNN; s++) { bd[s] = 3.4e38f; bi[s] = 0x7fffffff; }

    for (int j = 0; j < N_; j++) {
        float dx = pts[j * 3 + 0] - qx;
        float dy = pts[j * 3 + 1] - qy;
        float dz = pts[j * 3 + 2] - qz;
        float d = dx * dx + dy * dy + dz * dz;
        bool better = (d < bd[KNN - 1]) || (d == bd[KNN - 1] && j < bi[KNN - 1]);
        if (better) {
            bd[KNN - 1] = d; bi[KNN - 1] = j;
#pragma unroll
            for (int s = KNN - 1; s > 0; --s) {
                bool sw = (bd[s] < bd[s - 1]) || (bd[s] == bd[s - 1] && bi[s] < bi[s - 1]);
                if (sw) {
                    float td = bd[s]; bd[s] = bd[s - 1]; bd[s - 1] = td;
                    int ti = bi[s]; bi[s] = bi[s - 1]; bi[s - 1] = ti;
                }
            }
        }
    }
    int* op = idx + ((size_t)b * N_ + i) * KNN;
#pragma unroll
    for (int s = 0; s < KNN; s++) op[s] = bi[s];
}

// ---------------------------------------------------------------------------
// Covariance features: h0 (B,12,N). ch0..2 = x^T; ch 3+3c+d = cov[c][d].
// ---------------------------------------------------------------------------
__global__ __launch_bounds__(256) void cov_kernel(const float* __restrict__ x,
                                                  const int* __restrict__ idx,
                                                  float* __restrict__ h0) {
    int b = blockIdx.y;
    int n = blockIdx.x * 256 + threadIdx.x;
    const int* ip = idx + ((size_t)b * N_ + n) * KNN;

    float px[KNN], py[KNN], pz[KNN];
    float mx = 0.f, my = 0.f, mz = 0.f;
#pragma unroll
    for (int k = 0; k < KNN; k++) {
        int j = ip[k];
        const float* p = x + ((size_t)b * N_ + j) * 3;
        px[k] = p[0]; py[k] = p[1]; pz[k] = p[2];
        mx += px[k]; my += py[k]; mz += pz[k];
    }
    mx *= (1.f / KNN); my *= (1.f / KNN); mz *= (1.f / KNN);

    float c00 = 0, c01 = 0, c02 = 0, c11 = 0, c12 = 0, c22 = 0;
#pragma unroll
    for (int k = 0; k < KNN; k++) {
        float dx = px[k] - mx, dy = py[k] - my, dz = pz[k] - mz;
        c00 += dx * dx; c01 += dx * dy; c02 += dx * dz;
        c11 += dy * dy; c12 += dy * dz; c22 += dz * dz;
    }
    float* hb = h0 + (size_t)b * 12 * N_;
    const float* xp = x + ((size_t)b * N_ + n) * 3;
    hb[0 * N_ + n] = xp[0];
    hb[1 * N_ + n] = xp[1];
    hb[2 * N_ + n] = xp[2];
    hb[3 * N_ + n] = c00; hb[4 * N_ + n] = c01; hb[5 * N_ + n] = c02;
    hb[6 * N_ + n] = c01; hb[7 * N_ + n] = c11; hb[8 * N_ + n] = c12;
    hb[9 * N_ + n] = c02; hb[10 * N_ + n] = c12; hb[11 * N_ + n] = c22;
}

// ---------------------------------------------------------------------------
// Tiled fp32 GEMM. 128(o) x 128(n) block tile, K-chunk 16, 8x8 micro-tile.
// MODE 0: Y[b,o,n] = sum_c A[o,c]*X[b,c,n] + bias[o]           (conv)
// MODE 1: Y[o,n]   = nrmR[o] + nrmC[n] - 2*sum_c A[o,c]*X[c,n] (distance,
//         launched per batch with pre-offset pointers, gridDim.z == 1)
// XLAYOUT 0: X[(b*C+c)*N+n]   XLAYOUT 1: X[(b*N+n)*C+c]
// ---------------------------------------------------------------------------
template <int XLAYOUT, int MODE>
__global__ __launch_bounds__(256) void gemm_kernel(const float* __restrict__ A,
                                                   const float* __restrict__ X,
                                                   const float* __restrict__ bias,
                                                   float* __restrict__ Y,
                                                   int O, int C,
                                                   const float* __restrict__ nrmR,
                                                   const float* __restrict__ nrmC) {
    __shared__ float Wt[16][132];
    __shared__ float Xt[16][132];
    const int N = N_;
    int b = blockIdx.z;
    int oB = blockIdx.y * 128, nB = blockIdx.x * 128;
    const float* Xb = X + (size_t)b * C * N;
    int tid = threadIdx.x;
    int tn = tid & 15, to = tid >> 4;

    float acc[8][8];
#pragma unroll
    for (int i = 0; i < 8; i++)
#pragma unroll
        for (int j = 0; j < 8; j++) acc[i][j] = 0.f;

    for (int c0 = 0; c0 < C; c0 += 16) {
#pragma unroll
        for (int r = 0; r < 8; r++) {
            int e = tid + r * 256;
            int k = e & 15, o = e >> 4;
            float v = 0.f;
            if (c0 + k < C && oB + o < O) v = A[(size_t)(oB + o) * C + c0 + k];
            Wt[k][o] = v;
        }
#pragma unroll
        for (int r = 0; r < 8; r++) {
            int e = tid + r * 256;
            float v = 0.f;
            int k, n;
            if (XLAYOUT == 0) {
                n = e & 127; k = e >> 7;
                if (c0 + k < C) v = Xb[(size_t)(c0 + k) * N + nB + n];
            } else {
                k = e & 15; n = e >> 4;
                if (c0 + k < C) v = Xb[(size_t)(nB + n) * C + c0 + k];
            }
            Xt[k][n] = v;
        }
        __syncthreads();
#pragma unroll
        for (int k = 0; k < 16; k++) {
            float a[8], xv[8];
#pragma unroll
            for (int i = 0; i < 8; i++) a[i] = Wt[k][to * 8 + i];
#pragma unroll
            for (int m = 0; m < 4; m++) {
                xv[2 * m] = Xt[k][tn * 2 + 32 * m];
                xv[2 * m + 1] = Xt[k][tn * 2 + 32 * m + 1];
            }
#pragma unroll
            for (int i = 0; i < 8; i++)
#pragma unroll
                for (int j = 0; j < 8; j++) acc[i][j] = fmaf(a[i], xv[j], acc[i][j]);
        }
        __syncthreads();
    }

#pragma unroll
    for (int i = 0; i < 8; i++) {
        int o = oB + to * 8 + i;
        if (o >= O) continue;
        float bv = (MODE == 0) ? bias[o] : 0.f;
        float nr = (MODE == 1) ? nrmR[o] : 0.f;
#pragma unroll
        for (int m = 0; m < 4; m++) {
            int n0 = nB + tn * 2 + 32 * m;
            float v0 = acc[i][2 * m], v1 = acc[i][2 * m + 1];
            if (MODE == 0) { v0 += bv; v1 += bv; }
            else {
                v0 = nr + nrmC[n0] - 2.f * v0;
                v1 = nr + nrmC[n0 + 1] - 2.f * v1;
            }
            float2 st = make_float2(v0, v1);
            *reinterpret_cast<float2*>(&Y[((size_t)b * O + o) * N + n0]) = st;
        }
    }
}

// ---------------------------------------------------------------------------
// Per-channel BN stats over (B,N): scale = gm/sqrt(var+eps), shift = bt-mu*scale
// ---------------------------------------------------------------------------
__global__ __launch_bounds__(256) void bnstats_kernel(const float* __restrict__ y,
                                                      const float* __restrict__ gm,
                                                      const float* __restrict__ bt,
                                                      float* __restrict__ scale,
                                                      float* __restrict__ shift, int O) {
    int o = blockIdx.x;
    float s = 0.f, s2 = 0.f;
    for (int e = threadIdx.x; e < B_ * N_; e += 256) {
        int b = e >> 11, n = e & (N_ - 1);
        float v = y[((size_t)b * O + o) * N_ + n];
        s += v;
        s2 = fmaf(v, v, s2);
    }
#pragma unroll
    for (int off = 32; off; off >>= 1) {
        s += __shfl_down(s, off, 64);
        s2 += __shfl_down(s2, off, 64);
    }
    __shared__ float red[8];
    int lane = threadIdx.x & 63, w = threadIdx.x >> 6;
    if (lane == 0) { red[w] = s; red[4 + w] = s2; }
    __syncthreads();
    if (threadIdx.x == 0) {
        s = red[0] + red[1] + red[2] + red[3];
        s2 = red[4] + red[5] + red[6] + red[7];
        float mu = s * (1.f / (B_ * N_));
        float var = s2 * (1.f / (B_ * N_)) - mu * mu;
        float inv = 1.f / sqrtf(var + 1e-5f);
        float sc = gm[o] * inv;
        scale[o] = sc;
        shift[o] = fmaf(-mu, sc, bt[o]);
    }
}

// ---------------------------------------------------------------------------
// Apply BN (+ReLU). Optionally also write transposed (B,N,C) copy for KNN.
// ---------------------------------------------------------------------------
__global__ __launch_bounds__(256) void bnapply_kernel(float* __restrict__ y,
                                                      const float* __restrict__ scale,
                                                      const float* __restrict__ shift,
                                                      int oLog, int relu,
                                                      float* __restrict__ ft) {
    size_t i = (size_t)blockIdx.x * 256 + threadIdx.x;
    int n = (int)(i & (N_ - 1));
    size_t t = i >> 11;
    int o = (int)(t & ((1u << oLog) - 1));
    int b = (int)(t >> oLog);
    float v = fmaf(y[i], scale[o], shift[o]);
    if (relu) v = fmaxf(v, 0.f);
    y[i] = v;
    if (ft) ft[(((size_t)b << 11) + n) * (1u << oLog) + o] = v;
}

// ---------------------------------------------------------------------------
// Squared norms per point from (B,C,N) layout (coalesced over n). fma order
// ascending c == GEMM accumulation order -> exact self-distance 0.
// ---------------------------------------------------------------------------
__global__ __launch_bounds__(256) void norms_kernel(const float* __restrict__ h,
                                                    float* __restrict__ nrm, int C) {
    int b = blockIdx.y;
    int i = blockIdx.x * 256 + threadIdx.x;
    const float* hp = h + (size_t)b * C * N_;
    float s = 0.f;
    for (int c = 0; c < C; c++) {
        float v = hp[(size_t)c * N_ + i];
        s = fmaf(v, v, s);
    }
    nrm[(b << 11) + i] = s;
}

// ---------------------------------------------------------------------------
// Top-16 per row of a 2048x2048 distance matrix. One wave per row; row staged
// in LDS; 16 rounds of lexicographic (d,idx) min via shuffle butterfly, with
// only the winning lane rescanning its 32 elements.
// ---------------------------------------------------------------------------
__global__ __launch_bounds__(256) void topk_kernel(const float* __restrict__ D,
                                                   int* __restrict__ idx) {
    __shared__ float row[4][N_];
    int wave = threadIdx.x >> 6, lane = threadIdx.x & 63;
    int i = blockIdx.x * 4 + wave;
    const float* dp = D + (size_t)i * N_;
    for (int t = 0; t < 32; t++) row[wave][lane + t * 64] = dp[lane + t * 64];

    float lmin = 3.4e38f;
    int lidx = 0x7fffffff;
    for (int t = 0; t < 32; t++) {
        float v = row[wave][lane + t * 64];
        int j = lane + t * 64;
        if (v < lmin || (v == lmin && j < lidx)) { lmin = v; lidx = j; }
    }
    int* op = idx + (size_t)i * KNN;
    for (int r = 0; r < KNN; r++) {
        float md = lmin; int mi = lidx;
#pragma unroll
        for (int s = 32; s > 0; s >>= 1) {
            float od = __shfl_xor(md, s, 64);
            int oi = __shfl_xor(mi, s, 64);
            if (od < md || (od == md && oi < mi)) { md = od; mi = oi; }
        }
        if (lane == 0) op[r] = mi;
        if ((mi & 63) == lane) {
            row[wave][mi] = 3.4e38f;
            lmin = 3.4e38f; lidx = 0x7fffffff;
            for (int t = 0; t < 32; t++) {
                float v = row[wave][lane + t * 64];
                int j = lane + t * 64;
                if (v < lmin || (v == lmin && j < lidx)) { lmin = v; lidx = j; }
            }
        }
    }
}

// ---------------------------------------------------------------------------
// Gather 16 neighbor feature rows (B,N,C) and max over k -> (B,N,C).
// ---------------------------------------------------------------------------
__global__ __launch_bounds__(256) void gathermax_kernel(const float* __restrict__ ft,
                                                        const int* __restrict__ idx,
                                                        float* __restrict__ out, int cLog) {
    int C = 1 << cLog;
    int b = blockIdx.y;
    int nb = (blockIdx.x << (8 - cLog)) + (threadIdx.x >> cLog);
    int c = threadIdx.x & (C - 1);
    const int* ip = idx + (((size_t)b << 11) + nb) * KNN;
    float m = -3.4e38f;
#pragma unroll
    for (int k = 0; k < KNN; k++) {
        int j = ip[k];
        m = fmaxf(m, ft[(((size_t)b << 11) + j) * C + c]);
    }
    out[(((size_t)b << 11) + nb) * C + c] = m;
}

// ---------------------------------------------------------------------------
// Final: out[b,o] = max_n (y4[b,o,n]*scale[o]+shift[o])
// ---------------------------------------------------------------------------
__global__ __launch_bounds__(256) void finalmax_kernel(const float* __restrict__ y,
                                                       const float* __restrict__ scale,
                                                       const float* __restrict__ shift,
                                                       float* __restrict__ out) {
    int o = blockIdx.x, b = blockIdx.y;
    float s = scale[o], t = shift[o];
    const float* yp = y + ((size_t)b * 512 + o) * N_;
    float m = -3.4e38f;
    for (int n = threadIdx.x; n < N_; n += 256) m = fmaxf(m, fmaf(yp[n], s, t));
#pragma unroll
    for (int off = 32; off; off >>= 1) m = fmaxf(m, __shfl_down(m, off, 64));
    __shared__ float red[4];
    int lane = threadIdx.x & 63, w = threadIdx.x >> 6;
    if (lane == 0) red[w] = m;
    __syncthreads();
    if (threadIdx.x == 0)
        out[b * 512 + o] = fmaxf(fmaxf(red[0], red[1]), fmaxf(red[2], red[3]));
}

// ---------------------------------------------------------------------------
extern "C" void kernel_launch(void* const* d_in, const int* in_sizes, int n_in,
                              void* d_out, int out_size, void* d_ws, size_t ws_size,
                              hipStream_t stream) {
    const float* x = (const float*)d_in[0];
    const float* W1 = (const float*)d_in[1];
    const float* b1 = (const float*)d_in[2];
    const float* gm1 = (const float*)d_in[3];
    const float* bt1 = (const float*)d_in[4];
    const float* W2 = (const float*)d_in[5];
    const float* b2 = (const float*)d_in[6];
    const float* gm2 = (const float*)d_in[7];
    const float* bt2 = (const float*)d_in[8];
    const float* W3 = (const float*)d_in[9];
    const float* b3 = (const float*)d_in[10];
    const float* gm3 = (const float*)d_in[11];
    const float* bt3 = (const float*)d_in[12];
    const float* Wg1 = (const float*)d_in[13];
    const float* bg1 = (const float*)d_in[14];
    const float* gmg1 = (const float*)d_in[15];
    const float* btg1 = (const float*)d_in[16];
    const float* Wg2 = (const float*)d_in[17];
    const float* bg2 = (const float*)d_in[18];
    const float* gmg2 = (const float*)d_in[19];
    const float* btg2 = (const float*)d_in[20];
    const float* W4 = (const float*)d_in[21];
    const float* b4 = (const float*)d_in[22];
    const float* gm4 = (const float*)d_in[23];
    const float* bt4 = (const float*)d_in[24];
    float* out = (float*)d_out;

    // ---- workspace arena (float offsets), total 157,097,984 bytes ----
    if (ws_size < 157097984ull) return;  // insufficient scratch -> clean fail
    float* ws = (float*)d_ws;
    float* scale = ws + 0;              // 1024
    float* shift = ws + 1024;           // 1024
    float* nrm = ws + 2048;             // 16384
    int* idx = (int*)(ws + 18432);      // 262144 ints
    float* h0 = ws + 280576;            // (8,12,2048)
    float* bufA = ws + 477184;          // (8,64,2048)
    float* bufB = ws + 1525760;         // (8,64,2048)
    float* bufC = ws + 2574336;         // (8,2048,64)
    float* bufD = ws + 3622912;         // (2048,2048) per-batch dist
    float* bufM1 = ws + 7817216;        // (8,128,2048)
    float* bufM2 = ws + 9914368;        // (8,2048,128)
    float* bufM3 = ws + 12011520;       // (8,2048,128)
    float* bufL = ws + 14108672;        // (8,1024,2048)
    float* bufY4 = ws + 30885888;       // (8,512,2048)

    // Stage 0/1: 3D KNN + covariance features
    knn3_kernel<<<dim3(8, 8), 256, 0, stream>>>(x, idx);
    cov_kernel<<<dim3(8, 8), 256, 0, stream>>>(x, idx, h0);

    // conv1: 12 -> 64
    gemm_kernel<0, 0><<<dim3(16, 1, 8), 256, 0, stream>>>(W1, h0, b1, bufA, 64, 12, nullptr, nullptr);
    bnstats_kernel<<<64, 256, 0, stream>>>(bufA, gm1, bt1, scale, shift, 64);
    bnapply_kernel<<<4096, 256, 0, stream>>>(bufA, scale, shift, 6, 1, nullptr);

    // conv2: 64 -> 64
    gemm_kernel<0, 0><<<dim3(16, 1, 8), 256, 0, stream>>>(W2, bufA, b2, bufB, 64, 64, nullptr, nullptr);
    bnstats_kernel<<<64, 256, 0, stream>>>(bufB, gm2, bt2, scale, shift, 64);
    bnapply_kernel<<<4096, 256, 0, stream>>>(bufB, scale, shift, 6, 1, nullptr);

    // conv3: 64 -> 64 (dual write: bufA (B,64,N) + bufC (B,N,64))
    gemm_kernel<0, 0><<<dim3(16, 1, 8), 256, 0, stream>>>(W3, bufB, b3, bufA, 64, 64, nullptr, nullptr);
    bnstats_kernel<<<64, 256, 0, stream>>>(bufA, gm3, bt3, scale, shift, 64);
    bnapply_kernel<<<4096, 256, 0, stream>>>(bufA, scale, shift, 6, 1, bufC);

    // graph layer 1 KNN (C=64)
    norms_kernel<<<dim3(8, 8), 256, 0, stream>>>(bufA, nrm, 64);
    for (int b = 0; b < B_; b++) {
        gemm_kernel<0, 1><<<dim3(16, 16, 1), 256, 0, stream>>>(
            bufC + (size_t)b * N_ * 64, bufA + (size_t)b * 64 * N_, nullptr, bufD,
            2048, 64, nrm + b * N_, nrm + b * N_);
        topk_kernel<<<512, 256, 0, stream>>>(bufD, idx + (size_t)b * N_ * KNN);
    }
    gathermax_kernel<<<dim3(512, 8), 256, 0, stream>>>(bufC, idx, bufB, 6);

    // conv g1: 64 -> 128 (input (B,N,64) layout1)
    gemm_kernel<1, 0><<<dim3(16, 1, 8), 256, 0, stream>>>(Wg1, bufB, bg1, bufM1, 128, 64, nullptr, nullptr);
    bnstats_kernel<<<128, 256, 0, stream>>>(bufM1, gmg1, btg1, scale, shift, 128);
    bnapply_kernel<<<8192, 256, 0, stream>>>(bufM1, scale, shift, 7, 1, bufM2);

    // graph layer 2 KNN (C=128)
    norms_kernel<<<dim3(8, 8), 256, 0, stream>>>(bufM1, nrm, 128);
    for (int b = 0; b < B_; b++) {
        gemm_kernel<0, 1><<<dim3(16, 16, 1), 256, 0, stream>>>(
            bufM2 + (size_t)b * N_ * 128, bufM1 + (size_t)b * 128 * N_, nullptr, bufD,
            2048, 128, nrm + b * N_, nrm + b * N_);
        topk_kernel<<<512, 256, 0, stream>>>(bufD, idx + (size_t)b * N_ * KNN);
    }
    gathermax_kernel<<<dim3(1024, 8), 256, 0, stream>>>(bufM2, idx, bufM3, 7);

    // conv g2: 128 -> 1024
    gemm_kernel<1, 0><<<dim3(16, 8, 8), 256, 0, stream>>>(Wg2, bufM3, bg2, bufL, 1024, 128, nullptr, nullptr);
    bnstats_kernel<<<1024, 256, 0, stream>>>(bufL, gmg2, btg2, scale, shift, 1024);
    bnapply_kernel<<<65536, 256, 0, stream>>>(bufL, scale, shift, 10, 1, nullptr);

    // conv4: 1024 -> 512, no ReLU; BN folded into final max
    gemm_kernel<0, 0><<<dim3(16, 4, 8), 256, 0, stream>>>(W4, bufL, b4, bufY4, 512, 1024, nullptr, nullptr);
    bnstats_kernel<<<512, 256, 0, stream>>>(bufY4, gm4, bt4, scale, shift, 512);
    finalmax_kernel<<<dim3(512, 8), 256, 0, stream>>>(bufY4, scale, shift, out);
}

// Round 2
// 2552.840 us; speedup vs baseline: 1.9234x; 1.9234x over previous
//
#include <hip/hip_runtime.h>
#include <math.h>

#define B_ 8
#define N_ 2048
#define KNN 16

// ---------------------------------------------------------------------------
// KNN on 3D input points — wave-per-query extraction (same verified pattern
// as topk_kernel). Block = 4 waves = 4 query rows; all 2048 points staged in
// LDS (SoA). Each wave computes its row's 2048 distances on the fly (32 per
// lane, conflict-free), keeps a running per-lane (d,idx) min, then extracts
// the 16 smallest via lexicographic shuffle butterflies. Tie-break (d, idx)
// ascending == lax.top_k(-d). Self-distance is exactly 0.
// ---------------------------------------------------------------------------
__global__ __launch_bounds__(256) void knn3_kernel(const float* __restrict__ x,
                                                   int* __restrict__ idx) {
    __shared__ float px[N_], py[N_], pz[N_];
    __shared__ float row[4][N_];
    int b = blockIdx.y;
    const float* xb = x + (size_t)b * N_ * 3;
    for (int e = threadIdx.x; e < N_; e += 256) {
        px[e] = xb[e * 3 + 0];
        py[e] = xb[e * 3 + 1];
        pz[e] = xb[e * 3 + 2];
    }
    __syncthreads();

    int wave = threadIdx.x >> 6, lane = threadIdx.x & 63;
    int i = blockIdx.x * 4 + wave;  // query row
    float qx = px[i], qy = py[i], qz = pz[i];

    float lmin = 3.4e38f;
    int lidx = 0x7fffffff;
    for (int t = 0; t < 32; t++) {
        int j = lane + t * 64;
        float dx = px[j] - qx, dy = py[j] - qy, dz = pz[j] - qz;
        float d = dx * dx + dy * dy + dz * dz;
        row[wave][j] = d;
        if (d < lmin || (d == lmin && j < lidx)) { lmin = d; lidx = j; }
    }

    int* op = idx + ((size_t)b * N_ + i) * KNN;
    for (int r = 0; r < KNN; r++) {
        float md = lmin; int mi = lidx;
#pragma unroll
        for (int s = 32; s > 0; s >>= 1) {
            float od = __shfl_xor(md, s, 64);
            int oi = __shfl_xor(mi, s, 64);
            if (od < md || (od == md && oi < mi)) { md = od; mi = oi; }
        }
        if (lane == 0) op[r] = mi;
        if ((mi & 63) == lane) {
            row[wave][mi] = 3.4e38f;
            lmin = 3.4e38f; lidx = 0x7fffffff;
            for (int t = 0; t < 32; t++) {
                float v = row[wave][lane + t * 64];
                int j = lane + t * 64;
                if (v < lmin || (v == lmin && j < lidx)) { lmin = v; lidx = j; }
            }
        }
    }
}

// ---------------------------------------------------------------------------
// Covariance features: h0 (B,12,N). ch0..2 = x^T; ch 3+3c+d = cov[c][d].
// ---------------------------------------------------------------------------
__global__ __launch_bounds__(256) void cov_kernel(const float* __restrict__ x,
                                                  const int* __restrict__ idx,
                                                  float* __restrict__ h0) {
    int b = blockIdx.y;
    int n = blockIdx.x * 256 + threadIdx.x;
    const int* ip = idx + ((size_t)b * N_ + n) * KNN;

    float px[KNN], py[KNN], pz[KNN];
    float mx = 0.f, my = 0.f, mz = 0.f;
#pragma unroll
    for (int k = 0; k < KNN; k++) {
        int j = ip[k];
        const float* p = x + ((size_t)b * N_ + j) * 3;
        px[k] = p[0]; py[k] = p[1]; pz[k] = p[2];
        mx += px[k]; my += py[k]; mz += pz[k];
    }
    mx *= (1.f / KNN); my *= (1.f / KNN); mz *= (1.f / KNN);

    float c00 = 0, c01 = 0, c02 = 0, c11 = 0, c12 = 0, c22 = 0;
#pragma unroll
    for (int k = 0; k < KNN; k++) {
        float dx = px[k] - mx, dy = py[k] - my, dz = pz[k] - mz;
        c00 += dx * dx; c01 += dx * dy; c02 += dx * dz;
        c11 += dy * dy; c12 += dy * dz; c22 += dz * dz;
    }
    float* hb = h0 + (size_t)b * 12 * N_;
    const float* xp = x + ((size_t)b * N_ + n) * 3;
    hb[0 * N_ + n] = xp[0];
    hb[1 * N_ + n] = xp[1];
    hb[2 * N_ + n] = xp[2];
    hb[3 * N_ + n] = c00; hb[4 * N_ + n] = c01; hb[5 * N_ + n] = c02;
    hb[6 * N_ + n] = c01; hb[7 * N_ + n] = c11; hb[8 * N_ + n] = c12;
    hb[9 * N_ + n] = c02; hb[10 * N_ + n] = c12; hb[11 * N_ + n] = c22;
}

// ---------------------------------------------------------------------------
// Tiled fp32 GEMM. 128(o) x 128(n) block tile, K-chunk 16, 8x8 micro-tile.
// MODE 0: Y[b,o,n] = sum_c A[o,c]*X[b,c,n] + bias[o]           (conv)
// MODE 1: Y[o,n]   = nrmR[o] + nrmC[n] - 2*sum_c A[o,c]*X[c,n] (distance,
//         launched per batch with pre-offset pointers, gridDim.z == 1)
// XLAYOUT 0: X[(b*C+c)*N+n]   XLAYOUT 1: X[(b*N+n)*C+c]
// ---------------------------------------------------------------------------
template <int XLAYOUT, int MODE>
__global__ __launch_bounds__(256) void gemm_kernel(const float* __restrict__ A,
                                                   const float* __restrict__ X,
                                                   const float* __restrict__ bias,
                                                   float* __restrict__ Y,
                                                   int O, int C,
                                                   const float* __restrict__ nrmR,
                                                   const float* __restrict__ nrmC) {
    __shared__ float Wt[16][132];
    __shared__ float Xt[16][132];
    const int N = N_;
    int b = blockIdx.z;
    int oB = blockIdx.y * 128, nB = blockIdx.x * 128;
    const float* Xb = X + (size_t)b * C * N;
    int tid = threadIdx.x;
    int tn = tid & 15, to = tid >> 4;

    float acc[8][8];
#pragma unroll
    for (int i = 0; i < 8; i++)
#pragma unroll
        for (int j = 0; j < 8; j++) acc[i][j] = 0.f;

    for (int c0 = 0; c0 < C; c0 += 16) {
#pragma unroll
        for (int r = 0; r < 8; r++) {
            int e = tid + r * 256;
            int k = e & 15, o = e >> 4;
            float v = 0.f;
            if (c0 + k < C && oB + o < O) v = A[(size_t)(oB + o) * C + c0 + k];
            Wt[k][o] = v;
        }
#pragma unroll
        for (int r = 0; r < 8; r++) {
            int e = tid + r * 256;
            float v = 0.f;
            int k, n;
            if (XLAYOUT == 0) {
                n = e & 127; k = e >> 7;
                if (c0 + k < C) v = Xb[(size_t)(c0 + k) * N + nB + n];
            } else {
                k = e & 15; n = e >> 4;
                if (c0 + k < C) v = Xb[(size_t)(nB + n) * C + c0 + k];
            }
            Xt[k][n] = v;
        }
        __syncthreads();
#pragma unroll
        for (int k = 0; k < 16; k++) {
            float a[8], xv[8];
#pragma unroll
            for (int i = 0; i < 8; i++) a[i] = Wt[k][to * 8 + i];
#pragma unroll
            for (int m = 0; m < 4; m++) {
                xv[2 * m] = Xt[k][tn * 2 + 32 * m];
                xv[2 * m + 1] = Xt[k][tn * 2 + 32 * m + 1];
            }
#pragma unroll
            for (int i = 0; i < 8; i++)
#pragma unroll
                for (int j = 0; j < 8; j++) acc[i][j] = fmaf(a[i], xv[j], acc[i][j]);
        }
        __syncthreads();
    }

#pragma unroll
    for (int i = 0; i < 8; i++) {
        int o = oB + to * 8 + i;
        if (o >= O) continue;
        float bv = (MODE == 0) ? bias[o] : 0.f;
        float nr = (MODE == 1) ? nrmR[o] : 0.f;
#pragma unroll
        for (int m = 0; m < 4; m++) {
            int n0 = nB + tn * 2 + 32 * m;
            float v0 = acc[i][2 * m], v1 = acc[i][2 * m + 1];
            if (MODE == 0) { v0 += bv; v1 += bv; }
            else {
                v0 = nr + nrmC[n0] - 2.f * v0;
                v1 = nr + nrmC[n0 + 1] - 2.f * v1;
            }
            float2 st = make_float2(v0, v1);
            *reinterpret_cast<float2*>(&Y[((size_t)b * O + o) * N + n0]) = st;
        }
    }
}

// ---------------------------------------------------------------------------
// Per-channel BN stats over (B,N): scale = gm/sqrt(var+eps), shift = bt-mu*scale
// ---------------------------------------------------------------------------
__global__ __launch_bounds__(256) void bnstats_kernel(const float* __restrict__ y,
                                                      const float* __restrict__ gm,
                                                      const float* __restrict__ bt,
                                                      float* __restrict__ scale,
                                                      float* __restrict__ shift, int O) {
    int o = blockIdx.x;
    float s = 0.f, s2 = 0.f;
    for (int e = threadIdx.x; e < B_ * N_; e += 256) {
        int b = e >> 11, n = e & (N_ - 1);
        float v = y[((size_t)b * O + o) * N_ + n];
        s += v;
        s2 = fmaf(v, v, s2);
    }
#pragma unroll
    for (int off = 32; off; off >>= 1) {
        s += __shfl_down(s, off, 64);
        s2 += __shfl_down(s2, off, 64);
    }
    __shared__ float red[8];
    int lane = threadIdx.x & 63, w = threadIdx.x >> 6;
    if (lane == 0) { red[w] = s; red[4 + w] = s2; }
    __syncthreads();
    if (threadIdx.x == 0) {
        s = red[0] + red[1] + red[2] + red[3];
        s2 = red[4] + red[5] + red[6] + red[7];
        float mu = s * (1.f / (B_ * N_));
        float var = s2 * (1.f / (B_ * N_)) - mu * mu;
        float inv = 1.f / sqrtf(var + 1e-5f);
        float sc = gm[o] * inv;
        scale[o] = sc;
        shift[o] = fmaf(-mu, sc, bt[o]);
    }
}

// ---------------------------------------------------------------------------
// Apply BN (+ReLU). Optionally also write transposed (B,N,C) copy for KNN.
// ---------------------------------------------------------------------------
__global__ __launch_bounds__(256) void bnapply_kernel(float* __restrict__ y,
                                                      const float* __restrict__ scale,
                                                      const float* __restrict__ shift,
                                                      int oLog, int relu,
                                                      float* __restrict__ ft) {
    size_t i = (size_t)blockIdx.x * 256 + threadIdx.x;
    int n = (int)(i & (N_ - 1));
    size_t t = i >> 11;
    int o = (int)(t & ((1u << oLog) - 1));
    int b = (int)(t >> oLog);
    float v = fmaf(y[i], scale[o], shift[o]);
    if (relu) v = fmaxf(v, 0.f);
    y[i] = v;
    if (ft) ft[(((size_t)b << 11) + n) * (1u << oLog) + o] = v;
}

// ---------------------------------------------------------------------------
// Squared norms per point from (B,C,N) layout (coalesced over n). fma order
// ascending c == GEMM accumulation order -> exact self-distance 0.
// ---------------------------------------------------------------------------
__global__ __launch_bounds__(256) void norms_kernel(const float* __restrict__ h,
                                                    float* __restrict__ nrm, int C) {
    int b = blockIdx.y;
    int i = blockIdx.x * 256 + threadIdx.x;
    const float* hp = h + (size_t)b * C * N_;
    float s = 0.f;
    for (int c = 0; c < C; c++) {
        float v = hp[(size_t)c * N_ + i];
        s = fmaf(v, v, s);
    }
    nrm[(b << 11) + i] = s;
}

// ---------------------------------------------------------------------------
// Top-16 per row of a 2048x2048 distance matrix. One wave per row; row staged
// in LDS; 16 rounds of lexicographic (d,idx) min via shuffle butterfly, with
// only the winning lane rescanning its 32 elements.
// ---------------------------------------------------------------------------
__global__ __launch_bounds__(256) void topk_kernel(const float* __restrict__ D,
                                                   int* __restrict__ idx) {
    __shared__ float row[4][N_];
    int wave = threadIdx.x >> 6, lane = threadIdx.x & 63;
    int i = blockIdx.x * 4 + wave;
    const float* dp = D + (size_t)i * N_;
    for (int t = 0; t < 32; t++) row[wave][lane + t * 64] = dp[lane + t * 64];

    float lmin = 3.4e38f;
    int lidx = 0x7fffffff;
    for (int t = 0; t < 32; t++) {
        float v = row[wave][lane + t * 64];
        int j = lane + t * 64;
        if (v < lmin || (v == lmin && j < lidx)) { lmin = v; lidx = j; }
    }
    int* op = idx + (size_t)i * KNN;
    for (int r = 0; r < KNN; r++) {
        float md = lmin; int mi = lidx;
#pragma unroll
        for (int s = 32; s > 0; s >>= 1) {
            float od = __shfl_xor(md, s, 64);
            int oi = __shfl_xor(mi, s, 64);
            if (od < md || (od == md && oi < mi)) { md = od; mi = oi; }
        }
        if (lane == 0) op[r] = mi;
        if ((mi & 63) == lane) {
            row[wave][mi] = 3.4e38f;
            lmin = 3.4e38f; lidx = 0x7fffffff;
            for (int t = 0; t < 32; t++) {
                float v = row[wave][lane + t * 64];
                int j = lane + t * 64;
                if (v < lmin || (v == lmin && j < lidx)) { lmin = v; lidx = j; }
            }
        }
    }
}

// ---------------------------------------------------------------------------
// Gather 16 neighbor feature rows (B,N,C) and max over k -> (B,N,C).
// ---------------------------------------------------------------------------
__global__ __launch_bounds__(256) void gathermax_kernel(const float* __restrict__ ft,
                                                        const int* __restrict__ idx,
                                                        float* __restrict__ out, int cLog) {
    int C = 1 << cLog;
    int b = blockIdx.y;
    int nb = (blockIdx.x << (8 - cLog)) + (threadIdx.x >> cLog);
    int c = threadIdx.x & (C - 1);
    const int* ip = idx + (((size_t)b << 11) + nb) * KNN;
    float m = -3.4e38f;
#pragma unroll
    for (int k = 0; k < KNN; k++) {
        int j = ip[k];
        m = fmaxf(m, ft[(((size_t)b << 11) + j) * C + c]);
    }
    out[(((size_t)b << 11) + nb) * C + c] = m;
}

// ---------------------------------------------------------------------------
// Final: out[b,o] = max_n (y4[b,o,n]*scale[o]+shift[o])
// ---------------------------------------------------------------------------
__global__ __launch_bounds__(256) void finalmax_kernel(const float* __restrict__ y,
                                                       const float* __restrict__ scale,
                                                       const float* __restrict__ shift,
                                                       float* __restrict__ out) {
    int o = blockIdx.x, b = blockIdx.y;
    float s = scale[o], t = shift[o];
    const float* yp = y + ((size_t)b * 512 + o) * N_;
    float m = -3.4e38f;
    for (int n = threadIdx.x; n < N_; n += 256) m = fmaxf(m, fmaf(yp[n], s, t));
#pragma unroll
    for (int off = 32; off; off >>= 1) m = fmaxf(m, __shfl_down(m, off, 64));
    __shared__ float red[4];
    int lane = threadIdx.x & 63, w = threadIdx.x >> 6;
    if (lane == 0) red[w] = m;
    __syncthreads();
    if (threadIdx.x == 0)
        out[b * 512 + o] = fmaxf(fmaxf(red[0], red[1]), fmaxf(red[2], red[3]));
}

// ---------------------------------------------------------------------------
extern "C" void kernel_launch(void* const* d_in, const int* in_sizes, int n_in,
                              void* d_out, int out_size, void* d_ws, size_t ws_size,
                              hipStream_t stream) {
    const float* x = (const float*)d_in[0];
    const float* W1 = (const float*)d_in[1];
    const float* b1 = (const float*)d_in[2];
    const float* gm1 = (const float*)d_in[3];
    const float* bt1 = (const float*)d_in[4];
    const float* W2 = (const float*)d_in[5];
    const float* b2 = (const float*)d_in[6];
    const float* gm2 = (const float*)d_in[7];
    const float* bt2 = (const float*)d_in[8];
    const float* W3 = (const float*)d_in[9];
    const float* b3 = (const float*)d_in[10];
    const float* gm3 = (const float*)d_in[11];
    const float* bt3 = (const float*)d_in[12];
    const float* Wg1 = (const float*)d_in[13];
    const float* bg1 = (const float*)d_in[14];
    const float* gmg1 = (const float*)d_in[15];
    const float* btg1 = (const float*)d_in[16];
    const float* Wg2 = (const float*)d_in[17];
    const float* bg2 = (const float*)d_in[18];
    const float* gmg2 = (const float*)d_in[19];
    const float* btg2 = (const float*)d_in[20];
    const float* W4 = (const float*)d_in[21];
    const float* b4 = (const float*)d_in[22];
    const float* gm4 = (const float*)d_in[23];
    const float* bt4 = (const float*)d_in[24];
    float* out = (float*)d_out;

    // ---- workspace arena (float offsets), total 157,097,984 bytes ----
    if (ws_size < 157097984ull) return;  // insufficient scratch -> clean fail
    float* ws = (float*)d_ws;
    float* scale = ws + 0;              // 1024
    float* shift = ws + 1024;           // 1024
    float* nrm = ws + 2048;             // 16384
    int* idx = (int*)(ws + 18432);      // 262144 ints
    float* h0 = ws + 280576;            // (8,12,2048)
    float* bufA = ws + 477184;          // (8,64,2048)
    float* bufB = ws + 1525760;         // (8,64,2048)
    float* bufC = ws + 2574336;         // (8,2048,64)
    float* bufD = ws + 3622912;         // (2048,2048) per-batch dist
    float* bufM1 = ws + 7817216;        // (8,128,2048)
    float* bufM2 = ws + 9914368;        // (8,2048,128)
    float* bufM3 = ws + 12011520;       // (8,2048,128)
    float* bufL = ws + 14108672;        // (8,1024,2048)
    float* bufY4 = ws + 30885888;       // (8,512,2048)

    // Stage 0/1: 3D KNN (wave-per-query) + covariance features
    knn3_kernel<<<dim3(512, 8), 256, 0, stream>>>(x, idx);
    cov_kernel<<<dim3(8, 8), 256, 0, stream>>>(x, idx, h0);

    // conv1: 12 -> 64
    gemm_kernel<0, 0><<<dim3(16, 1, 8), 256, 0, stream>>>(W1, h0, b1, bufA, 64, 12, nullptr, nullptr);
    bnstats_kernel<<<64, 256, 0, stream>>>(bufA, gm1, bt1, scale, shift, 64);
    bnapply_kernel<<<4096, 256, 0, stream>>>(bufA, scale, shift, 6, 1, nullptr);

    // conv2: 64 -> 64
    gemm_kernel<0, 0><<<dim3(16, 1, 8), 256, 0, stream>>>(W2, bufA, b2, bufB, 64, 64, nullptr, nullptr);
    bnstats_kernel<<<64, 256, 0, stream>>>(bufB, gm2, bt2, scale, shift, 64);
    bnapply_kernel<<<4096, 256, 0, stream>>>(bufB, scale, shift, 6, 1, nullptr);

    // conv3: 64 -> 64 (dual write: bufA (B,64,N) + bufC (B,N,64))
    gemm_kernel<0, 0><<<dim3(16, 1, 8), 256, 0, stream>>>(W3, bufB, b3, bufA, 64, 64, nullptr, nullptr);
    bnstats_kernel<<<64, 256, 0, stream>>>(bufA, gm3, bt3, scale, shift, 64);
    bnapply_kernel<<<4096, 256, 0, stream>>>(bufA, scale, shift, 6, 1, bufC);

    // graph layer 1 KNN (C=64)
    norms_kernel<<<dim3(8, 8), 256, 0, stream>>>(bufA, nrm, 64);
    for (int b = 0; b < B_; b++) {
        gemm_kernel<0, 1><<<dim3(16, 16, 1), 256, 0, stream>>>(
            bufC + (size_t)b * N_ * 64, bufA + (size_t)b * 64 * N_, nullptr, bufD,
            2048, 64, nrm + b * N_, nrm + b * N_);
        topk_kernel<<<512, 256, 0, stream>>>(bufD, idx + (size_t)b * N_ * KNN);
    }
    gathermax_kernel<<<dim3(512, 8), 256, 0, stream>>>(bufC, idx, bufB, 6);

    // conv g1: 64 -> 128 (input (B,N,64) layout1)
    gemm_kernel<1, 0><<<dim3(16, 1, 8), 256, 0, stream>>>(Wg1, bufB, bg1, bufM1, 128, 64, nullptr, nullptr);
    bnstats_kernel<<<128, 256, 0, stream>>>(bufM1, gmg1, btg1, scale, shift, 128);
    bnapply_kernel<<<8192, 256, 0, stream>>>(bufM1, scale, shift, 7, 1, bufM2);

    // graph layer 2 KNN (C=128)
    norms_kernel<<<dim3(8, 8), 256, 0, stream>>>(bufM1, nrm, 128);
    for (int b = 0; b < B_; b++) {
        gemm_kernel<0, 1><<<dim3(16, 16, 1), 256, 0, stream>>>(
            bufM2 + (size_t)b * N_ * 128, bufM1 + (size_t)b * 128 * N_, nullptr, bufD,
            2048, 128, nrm + b * N_, nrm + b * N_);
        topk_kernel<<<512, 256, 0, stream>>>(bufD, idx + (size_t)b * N_ * KNN);
    }
    gathermax_kernel<<<dim3(1024, 8), 256, 0, stream>>>(bufM2, idx, bufM3, 7);

    // conv g2: 128 -> 1024
    gemm_kernel<1, 0><<<dim3(16, 8, 8), 256, 0, stream>>>(Wg2, bufM3, bg2, bufL, 1024, 128, nullptr, nullptr);
    bnstats_kernel<<<1024, 256, 0, stream>>>(bufL, gmg2, btg2, scale, shift, 1024);
    bnapply_kernel<<<65536, 256, 0, stream>>>(bufL, scale, shift, 10, 1, nullptr);

    // conv4: 1024 -> 512, no ReLU; BN folded into final max
    gemm_kernel<0, 0><<<dim3(16, 4, 8), 256, 0, stream>>>(W4, bufL, b4, bufY4, 512, 1024, nullptr, nullptr);
    bnstats_kernel<<<512, 256, 0, stream>>>(bufY4, gm4, bt4, scale, shift, 512);
    finalmax_kernel<<<dim3(512, 8), 256, 0, stream>>>(bufY4, scale, shift, out);
}

// Round 4
// 2148.814 us; speedup vs baseline: 2.2850x; 1.1880x over previous
//
#include <hip/hip_runtime.h>
#include <math.h>

#define B_ 8
#define N_ 2048
#define KNN 16

typedef __attribute__((ext_vector_type(4))) float f32x4;
typedef __attribute__((ext_vector_type(8))) short bf16x8;

__device__ inline unsigned short f2bf(float f) {
    unsigned int x = __float_as_uint(f);
    unsigned int r = (x + 0x7fffu + ((x >> 16) & 1u)) >> 16;  // RNE
    return (unsigned short)r;
}

// ---------------------------------------------------------------------------
// KNN on 3D input points — wave-per-query extraction.
// ---------------------------------------------------------------------------
__global__ __launch_bounds__(256) void knn3_kernel(const float* __restrict__ x,
                                                   int* __restrict__ idx) {
    __shared__ float px[N_], py[N_], pz[N_];
    __shared__ float row[4][N_];
    int b = blockIdx.y;
    const float* xb = x + (size_t)b * N_ * 3;
    for (int e = threadIdx.x; e < N_; e += 256) {
        px[e] = xb[e * 3 + 0];
        py[e] = xb[e * 3 + 1];
        pz[e] = xb[e * 3 + 2];
    }
    __syncthreads();

    int wave = threadIdx.x >> 6, lane = threadIdx.x & 63;
    int i = blockIdx.x * 4 + wave;
    float qx = px[i], qy = py[i], qz = pz[i];

    float lmin = 3.4e38f;
    int lidx = 0x7fffffff;
    for (int t = 0; t < 32; t++) {
        int j = lane + t * 64;
        float dx = px[j] - qx, dy = py[j] - qy, dz = pz[j] - qz;
        float d = dx * dx + dy * dy + dz * dz;
        row[wave][j] = d;
        if (d < lmin || (d == lmin && j < lidx)) { lmin = d; lidx = j; }
    }

    int* op = idx + ((size_t)b * N_ + i) * KNN;
    for (int r = 0; r < KNN; r++) {
        float md = lmin; int mi = lidx;
#pragma unroll
        for (int s = 32; s > 0; s >>= 1) {
            float od = __shfl_xor(md, s, 64);
            int oi = __shfl_xor(mi, s, 64);
            if (od < md || (od == md && oi < mi)) { md = od; mi = oi; }
        }
        if (lane == 0) op[r] = mi;
        if ((mi & 63) == lane) {
            row[wave][mi] = 3.4e38f;
            lmin = 3.4e38f; lidx = 0x7fffffff;
            for (int t = 0; t < 32; t++) {
                float v = row[wave][lane + t * 64];
                int j = lane + t * 64;
                if (v < lmin || (v == lmin && j < lidx)) { lmin = v; lidx = j; }
            }
        }
    }
}

// ---------------------------------------------------------------------------
// Covariance features: h0 (B,12,N).
// ---------------------------------------------------------------------------
__global__ __launch_bounds__(256) void cov_kernel(const float* __restrict__ x,
                                                  const int* __restrict__ idx,
                                                  float* __restrict__ h0) {
    int b = blockIdx.y;
    int n = blockIdx.x * 256 + threadIdx.x;
    const int* ip = idx + ((size_t)b * N_ + n) * KNN;

    float px[KNN], py[KNN], pz[KNN];
    float mx = 0.f, my = 0.f, mz = 0.f;
#pragma unroll
    for (int k = 0; k < KNN; k++) {
        int j = ip[k];
        const float* p = x + ((size_t)b * N_ + j) * 3;
        px[k] = p[0]; py[k] = p[1]; pz[k] = p[2];
        mx += px[k]; my += py[k]; mz += pz[k];
    }
    mx *= (1.f / KNN); my *= (1.f / KNN); mz *= (1.f / KNN);

    float c00 = 0, c01 = 0, c02 = 0, c11 = 0, c12 = 0, c22 = 0;
#pragma unroll
    for (int k = 0; k < KNN; k++) {
        float dx = px[k] - mx, dy = py[k] - my, dz = pz[k] - mz;
        c00 += dx * dx; c01 += dx * dy; c02 += dx * dz;
        c11 += dy * dy; c12 += dy * dz; c22 += dz * dz;
    }
    float* hb = h0 + (size_t)b * 12 * N_;
    const float* xp = x + ((size_t)b * N_ + n) * 3;
    hb[0 * N_ + n] = xp[0];
    hb[1 * N_ + n] = xp[1];
    hb[2 * N_ + n] = xp[2];
    hb[3 * N_ + n] = c00; hb[4 * N_ + n] = c01; hb[5 * N_ + n] = c02;
    hb[6 * N_ + n] = c01; hb[7 * N_ + n] = c11; hb[8 * N_ + n] = c12;
    hb[9 * N_ + n] = c02; hb[10 * N_ + n] = c12; hb[11 * N_ + n] = c22;
}

// ---------------------------------------------------------------------------
// Tiled fp32 GEMM (KNN-selection path: conv1-3, g1 conv, distance GEMMs).
// MODE 0: Y[b,o,n] = sum_c A[o,c]*X[b,c,n] + bias[o]
// MODE 1: Y[o,n]   = nrmR[o] + nrmC[n] - 2*sum_c A[o,c]*X[c,n]  (z==1)
// XLAYOUT 0: X[(b*C+c)*N+n]   XLAYOUT 1: X[(b*N+n)*C+c]
// ---------------------------------------------------------------------------
template <int XLAYOUT, int MODE>
__global__ __launch_bounds__(256) void gemm_kernel(const float* __restrict__ A,
                                                   const float* __restrict__ X,
                                                   const float* __restrict__ bias,
                                                   float* __restrict__ Y,
                                                   int O, int C,
                                                   const float* __restrict__ nrmR,
                                                   const float* __restrict__ nrmC) {
    __shared__ float Wt[16][132];
    __shared__ float Xt[16][132];
    const int N = N_;
    int b = blockIdx.z;
    int oB = blockIdx.y * 128, nB = blockIdx.x * 128;
    const float* Xb = X + (size_t)b * C * N;
    int tid = threadIdx.x;
    int tn = tid & 15, to = tid >> 4;

    float acc[8][8];
#pragma unroll
    for (int i = 0; i < 8; i++)
#pragma unroll
        for (int j = 0; j < 8; j++) acc[i][j] = 0.f;

    for (int c0 = 0; c0 < C; c0 += 16) {
#pragma unroll
        for (int r = 0; r < 8; r++) {
            int e = tid + r * 256;
            int k = e & 15, o = e >> 4;
            float v = 0.f;
            if (c0 + k < C && oB + o < O) v = A[(size_t)(oB + o) * C + c0 + k];
            Wt[k][o] = v;
        }
#pragma unroll
        for (int r = 0; r < 8; r++) {
            int e = tid + r * 256;
            float v = 0.f;
            int k, n;
            if (XLAYOUT == 0) {
                n = e & 127; k = e >> 7;
                if (c0 + k < C) v = Xb[(size_t)(c0 + k) * N + nB + n];
            } else {
                k = e & 15; n = e >> 4;
                if (c0 + k < C) v = Xb[(size_t)(nB + n) * C + c0 + k];
            }
            Xt[k][n] = v;
        }
        __syncthreads();
#pragma unroll
        for (int k = 0; k < 16; k++) {
            float a[8], xv[8];
#pragma unroll
            for (int i = 0; i < 8; i++) a[i] = Wt[k][to * 8 + i];
#pragma unroll
            for (int m = 0; m < 4; m++) {
                xv[2 * m] = Xt[k][tn * 2 + 32 * m];
                xv[2 * m + 1] = Xt[k][tn * 2 + 32 * m + 1];
            }
#pragma unroll
            for (int i = 0; i < 8; i++)
#pragma unroll
                for (int j = 0; j < 8; j++) acc[i][j] = fmaf(a[i], xv[j], acc[i][j]);
        }
        __syncthreads();
    }

#pragma unroll
    for (int i = 0; i < 8; i++) {
        int o = oB + to * 8 + i;
        if (o >= O) continue;
        float bv = (MODE == 0) ? bias[o] : 0.f;
        float nr = (MODE == 1) ? nrmR[o] : 0.f;
#pragma unroll
        for (int m = 0; m < 4; m++) {
            int n0 = nB + tn * 2 + 32 * m;
            float v0 = acc[i][2 * m], v1 = acc[i][2 * m + 1];
            if (MODE == 0) { v0 += bv; v1 += bv; }
            else {
                v0 = nr + nrmC[n0] - 2.f * v0;
                v1 = nr + nrmC[n0 + 1] - 2.f * v1;
            }
            float2 st = make_float2(v0, v1);
            *reinterpret_cast<float2*>(&Y[((size_t)b * O + o) * N + n0]) = st;
        }
    }
}

// ---------------------------------------------------------------------------
// bf16 MFMA GEMM (value path only: g2 conv, conv4).
// A (O,C) bf16 row-major; X (B,N,C) bf16 row-major. Y fp32 (B,O,N).
// 128x128 tile, BK=64, 4 waves (2x2), 4x4 frags of 16x16x32.
// ---------------------------------------------------------------------------
__global__ __launch_bounds__(256) void mgemm_kernel(const unsigned short* __restrict__ A,
                                                    const unsigned short* __restrict__ X,
                                                    const float* __restrict__ bias,
                                                    float* __restrict__ Y,
                                                    int O, int C) {
    __shared__ unsigned short At[128][72];
    __shared__ unsigned short Bt[128][72];
    int b = blockIdx.z;
    int oB = blockIdx.y * 128, nB = blockIdx.x * 128;
    const unsigned short* Xb = X + (size_t)b * N_ * C;
    int tid = threadIdx.x;
    int lane = tid & 63, w = tid >> 6;
    int wm = w & 1, wn = w >> 1;
    int lr = lane & 15, lg = lane >> 4;

    f32x4 acc[4][4];
#pragma unroll
    for (int m = 0; m < 4; m++)
#pragma unroll
        for (int n = 0; n < 4; n++) acc[m][n] = (f32x4){0.f, 0.f, 0.f, 0.f};

    for (int c0 = 0; c0 < C; c0 += 64) {
#pragma unroll
        for (int r = 0; r < 4; r++) {
            int t = tid + r * 256;
            int row = t >> 3, c8 = (t & 7) * 8;
            float4 va = *reinterpret_cast<const float4*>(&A[(size_t)(oB + row) * C + c0 + c8]);
            *reinterpret_cast<float4*>(&At[row][c8]) = va;
            float4 vb = *reinterpret_cast<const float4*>(&Xb[(size_t)(nB + row) * C + c0 + c8]);
            *reinterpret_cast<float4*>(&Bt[row][c8]) = vb;
        }
        __syncthreads();
#pragma unroll
        for (int kk = 0; kk < 2; kk++) {
            bf16x8 af[4], bfv[4];
#pragma unroll
            for (int m = 0; m < 4; m++)
                af[m] = *reinterpret_cast<const bf16x8*>(&At[wm * 64 + m * 16 + lr][kk * 32 + lg * 8]);
#pragma unroll
            for (int n = 0; n < 4; n++)
                bfv[n] = *reinterpret_cast<const bf16x8*>(&Bt[wn * 64 + n * 16 + lr][kk * 32 + lg * 8]);
#pragma unroll
            for (int m = 0; m < 4; m++)
#pragma unroll
                for (int n = 0; n < 4; n++)
                    acc[m][n] = __builtin_amdgcn_mfma_f32_16x16x32_bf16(af[m], bfv[n], acc[m][n], 0, 0, 0);
        }
        __syncthreads();
    }

#pragma unroll
    for (int m = 0; m < 4; m++) {
#pragma unroll
        for (int r = 0; r < 4; r++) {
            int o = oB + wm * 64 + m * 16 + lg * 4 + r;
            float bv = bias[o];
#pragma unroll
            for (int n = 0; n < 4; n++) {
                int nv = nB + wn * 64 + n * 16 + lr;
                Y[((size_t)b * O + o) * N_ + nv] = acc[m][n][r] + bv;
            }
        }
    }
}

// ---------------------------------------------------------------------------
// Per-channel BN stats over (B,N)
// ---------------------------------------------------------------------------
__global__ __launch_bounds__(256) void bnstats_kernel(const float* __restrict__ y,
                                                      const float* __restrict__ gm,
                                                      const float* __restrict__ bt,
                                                      float* __restrict__ scale,
                                                      float* __restrict__ shift, int O) {
    int o = blockIdx.x;
    float s = 0.f, s2 = 0.f;
    for (int e = threadIdx.x; e < B_ * N_; e += 256) {
        int b = e >> 11, n = e & (N_ - 1);
        float v = y[((size_t)b * O + o) * N_ + n];
        s += v;
        s2 = fmaf(v, v, s2);
    }
#pragma unroll
    for (int off = 32; off; off >>= 1) {
        s += __shfl_down(s, off, 64);
        s2 += __shfl_down(s2, off, 64);
    }
    __shared__ float red[8];
    int lane = threadIdx.x & 63, w = threadIdx.x >> 6;
    if (lane == 0) { red[w] = s; red[4 + w] = s2; }
    __syncthreads();
    if (threadIdx.x == 0) {
        s = red[0] + red[1] + red[2] + red[3];
        s2 = red[4] + red[5] + red[6] + red[7];
        float mu = s * (1.f / (B_ * N_));
        float var = s2 * (1.f / (B_ * N_)) - mu * mu;
        float inv = 1.f / sqrtf(var + 1e-5f);
        float sc = gm[o] * inv;
        scale[o] = sc;
        shift[o] = fmaf(-mu, sc, bt[o]);
    }
}

// ---------------------------------------------------------------------------
// Apply BN + ReLU in place; optional transposed fp32 (B,N,C) copy.
// ---------------------------------------------------------------------------
__global__ __launch_bounds__(256) void bnapply_kernel(float* __restrict__ y,
                                                      const float* __restrict__ scale,
                                                      const float* __restrict__ shift,
                                                      int oLog, int relu,
                                                      float* __restrict__ ft) {
    size_t i = (size_t)blockIdx.x * 256 + threadIdx.x;
    int n = (int)(i & (N_ - 1));
    size_t t = i >> 11;
    int o = (int)(t & ((1u << oLog) - 1));
    int b = (int)(t >> oLog);
    float v = fmaf(y[i], scale[o], shift[o]);
    if (relu) v = fmaxf(v, 0.f);
    y[i] = v;
    if (ft) ft[(((size_t)b << 11) + n) * (1u << oLog) + o] = v;
}

// ---------------------------------------------------------------------------
// BN apply + ReLU + transpose, fp32 (B,O,N) -> bf16 (B,N,O). 64x64 LDS tile.
// ---------------------------------------------------------------------------
__global__ __launch_bounds__(256) void bnt_kernel(const float* __restrict__ y,
                                                  const float* __restrict__ scale,
                                                  const float* __restrict__ shift,
                                                  unsigned short* __restrict__ ft, int O) {
    __shared__ float tile[64][65];
    int b = blockIdx.z;
    int n0 = blockIdx.x * 64, o0 = blockIdx.y * 64;
    int t = threadIdx.x;
#pragma unroll
    for (int rr = 0; rr < 16; rr++) {
        int ol = rr * 4 + (t >> 6), nl = t & 63;
        float v = y[((size_t)b * O + o0 + ol) * N_ + n0 + nl];
        v = fmaf(v, scale[o0 + ol], shift[o0 + ol]);
        tile[ol][nl] = fmaxf(v, 0.f);
    }
    __syncthreads();
#pragma unroll
    for (int rr = 0; rr < 2; rr++) {
        int e = t + rr * 256;
        int n = e >> 3, og = (e & 7) * 8;
        unsigned short u[8];
#pragma unroll
        for (int j = 0; j < 8; j++) u[j] = f2bf(tile[og + j][n]);
        uint4 pk;
        pk.x = (unsigned)u[0] | ((unsigned)u[1] << 16);
        pk.y = (unsigned)u[2] | ((unsigned)u[3] << 16);
        pk.z = (unsigned)u[4] | ((unsigned)u[5] << 16);
        pk.w = (unsigned)u[6] | ((unsigned)u[7] << 16);
        *reinterpret_cast<uint4*>(&ft[((size_t)b * N_ + n0 + n) * O + o0 + og]) = pk;
    }
}

// ---------------------------------------------------------------------------
// Squared norms per point from (B,C,N) fp32 (ascending-c fma == GEMM order).
// ---------------------------------------------------------------------------
__global__ __launch_bounds__(256) void norms_kernel(const float* __restrict__ h,
                                                    float* __restrict__ nrm, int C) {
    int b = blockIdx.y;
    int i = blockIdx.x * 256 + threadIdx.x;
    const float* hp = h + (size_t)b * C * N_;
    float s = 0.f;
    for (int c = 0; c < C; c++) {
        float v = hp[(size_t)c * N_ + i];
        s = fmaf(v, v, s);
    }
    nrm[(b << 11) + i] = s;
}

// ---------------------------------------------------------------------------
// Top-16 per row of 2048x2048 distance matrix (wave per row).
// ---------------------------------------------------------------------------
__global__ __launch_bounds__(256) void topk_kernel(const float* __restrict__ D,
                                                   int* __restrict__ idx) {
    __shared__ float row[4][N_];
    int wave = threadIdx.x >> 6, lane = threadIdx.x & 63;
    int i = blockIdx.x * 4 + wave;
    const float* dp = D + (size_t)i * N_;
    for (int t = 0; t < 32; t++) row[wave][lane + t * 64] = dp[lane + t * 64];

    float lmin = 3.4e38f;
    int lidx = 0x7fffffff;
    for (int t = 0; t < 32; t++) {
        float v = row[wave][lane + t * 64];
        int j = lane + t * 64;
        if (v < lmin || (v == lmin && j < lidx)) { lmin = v; lidx = j; }
    }
    int* op = idx + (size_t)i * KNN;
    for (int r = 0; r < KNN; r++) {
        float md = lmin; int mi = lidx;
#pragma unroll
        for (int s = 32; s > 0; s >>= 1) {
            float od = __shfl_xor(md, s, 64);
            int oi = __shfl_xor(mi, s, 64);
            if (od < md || (od == md && oi < mi)) { md = od; mi = oi; }
        }
        if (lane == 0) op[r] = mi;
        if ((mi & 63) == lane) {
            row[wave][mi] = 3.4e38f;
            lmin = 3.4e38f; lidx = 0x7fffffff;
            for (int t = 0; t < 32; t++) {
                float v = row[wave][lane + t * 64];
                int j = lane + t * 64;
                if (v < lmin || (v == lmin && j < lidx)) { lmin = v; lidx = j; }
            }
        }
    }
}

// ---------------------------------------------------------------------------
// Gather 16 neighbor fp32 rows (B,N,C), max over k -> fp32 (B,N,C).
// ---------------------------------------------------------------------------
__global__ __launch_bounds__(256) void gathermax_kernel(const float* __restrict__ ft,
                                                        const int* __restrict__ idx,
                                                        float* __restrict__ out, int cLog) {
    int C = 1 << cLog;
    int b = blockIdx.y;
    int nb = (blockIdx.x << (8 - cLog)) + (threadIdx.x >> cLog);
    int c = threadIdx.x & (C - 1);
    const int* ip = idx + (((size_t)b << 11) + nb) * KNN;
    float m = -3.4e38f;
#pragma unroll
    for (int k = 0; k < KNN; k++) {
        int j = ip[k];
        m = fmaxf(m, ft[(((size_t)b << 11) + j) * C + c]);
    }
    out[(((size_t)b << 11) + nb) * C + c] = m;
}

// ---------------------------------------------------------------------------
// Gather-max: fp32 (B,N,128) in -> bf16 (B,N,128) out (feeds g2 MFMA only).
// ---------------------------------------------------------------------------
__global__ __launch_bounds__(256) void gmaxh2_kernel(const float* __restrict__ ft,
                                                     const int* __restrict__ idx,
                                                     unsigned short* __restrict__ out) {
    const int C = 128;
    int b = blockIdx.y;
    int nb = blockIdx.x * 16 + (threadIdx.x >> 4);
    int cc = (threadIdx.x & 15) * 8;
    const int* ip = idx + (((size_t)b << 11) + nb) * KNN;
    float m[8];
#pragma unroll
    for (int q = 0; q < 8; q++) m[q] = -3.4e38f;
#pragma unroll
    for (int k = 0; k < KNN; k++) {
        int j = ip[k];
        const float* p = &ft[(((size_t)b << 11) + j) * C + cc];
        float4 a = *reinterpret_cast<const float4*>(p);
        float4 c2 = *reinterpret_cast<const float4*>(p + 4);
        m[0] = fmaxf(m[0], a.x); m[1] = fmaxf(m[1], a.y);
        m[2] = fmaxf(m[2], a.z); m[3] = fmaxf(m[3], a.w);
        m[4] = fmaxf(m[4], c2.x); m[5] = fmaxf(m[5], c2.y);
        m[6] = fmaxf(m[6], c2.z); m[7] = fmaxf(m[7], c2.w);
    }
    unsigned short u[8];
#pragma unroll
    for (int q = 0; q < 8; q++) u[q] = f2bf(m[q]);
    uint4 pk;
    pk.x = (unsigned)u[0] | ((unsigned)u[1] << 16);
    pk.y = (unsigned)u[2] | ((unsigned)u[3] << 16);
    pk.z = (unsigned)u[4] | ((unsigned)u[5] << 16);
    pk.w = (unsigned)u[6] | ((unsigned)u[7] << 16);
    *reinterpret_cast<uint4*>(&out[(((size_t)b << 11) + nb) * C + cc]) = pk;
}

// ---------------------------------------------------------------------------
// fp32 -> bf16 weight conversion
// ---------------------------------------------------------------------------
__global__ __launch_bounds__(256) void wcvt_kernel(const float* __restrict__ w,
                                                   unsigned short* __restrict__ wh, int count) {
    int i = blockIdx.x * 256 + threadIdx.x;
    if (i < count) wh[i] = f2bf(w[i]);
}

// ---------------------------------------------------------------------------
// Final: out[b,o] = max_n (y4[b,o,n]*scale[o]+shift[o])
// ---------------------------------------------------------------------------
__global__ __launch_bounds__(256) void finalmax_kernel(const float* __restrict__ y,
                                                       const float* __restrict__ scale,
                                                       const float* __restrict__ shift,
                                                       float* __restrict__ out) {
    int o = blockIdx.x, b = blockIdx.y;
    float s = scale[o], t = shift[o];
    const float* yp = y + ((size_t)b * 512 + o) * N_;
    float m = -3.4e38f;
    for (int n = threadIdx.x; n < N_; n += 256) m = fmaxf(m, fmaf(yp[n], s, t));
#pragma unroll
    for (int off = 32; off; off >>= 1) m = fmaxf(m, __shfl_down(m, off, 64));
    __shared__ float red[4];
    int lane = threadIdx.x & 63, w = threadIdx.x >> 6;
    if (lane == 0) red[w] = m;
    __syncthreads();
    if (threadIdx.x == 0)
        out[b * 512 + o] = fmaxf(fmaxf(red[0], red[1]), fmaxf(red[2], red[3]));
}

// ---------------------------------------------------------------------------
extern "C" void kernel_launch(void* const* d_in, const int* in_sizes, int n_in,
                              void* d_out, int out_size, void* d_ws, size_t ws_size,
                              hipStream_t stream) {
    const float* x = (const float*)d_in[0];
    const float* W1 = (const float*)d_in[1];
    const float* b1 = (const float*)d_in[2];
    const float* gm1 = (const float*)d_in[3];
    const float* bt1 = (const float*)d_in[4];
    const float* W2 = (const float*)d_in[5];
    const float* b2 = (const float*)d_in[6];
    const float* gm2 = (const float*)d_in[7];
    const float* bt2 = (const float*)d_in[8];
    const float* W3 = (const float*)d_in[9];
    const float* b3 = (const float*)d_in[10];
    const float* gm3 = (const float*)d_in[11];
    const float* bt3 = (const float*)d_in[12];
    const float* Wg1 = (const float*)d_in[13];
    const float* bg1 = (const float*)d_in[14];
    const float* gmg1 = (const float*)d_in[15];
    const float* btg1 = (const float*)d_in[16];
    const float* Wg2 = (const float*)d_in[17];
    const float* bg2 = (const float*)d_in[18];
    const float* gmg2 = (const float*)d_in[19];
    const float* btg2 = (const float*)d_in[20];
    const float* W4 = (const float*)d_in[21];
    const float* b4 = (const float*)d_in[22];
    const float* gm4 = (const float*)d_in[23];
    const float* bt4 = (const float*)d_in[24];
    float* out = (float*)d_out;

    // ---- workspace arena (byte offsets), total 154,214,400 bytes ----
    if (ws_size < 154214400ull) return;
    char* base = (char*)d_ws;
    float* scale = (float*)(base + 0);
    float* shift = (float*)(base + 4096);
    float* nrm = (float*)(base + 8192);
    int* idx = (int*)(base + 73728);
    unsigned short* Wg2h = (unsigned short*)(base + 1122304);
    unsigned short* W4h = (unsigned short*)(base + 1384448);
    float* bufD = (float*)(base + 2433024);                     // 16 MB
    float* bufL = (float*)(base + 19210240);                    // (8,1024,2048) f32
    unsigned short* bufLh = (unsigned short*)(base + 86319104); // (8,2048,1024) bf16
    char* E = base + 119873536;                                 // early region
    float* h0 = (float*)(E + 0);                                // (8,12,2048)
    float* bufA = (float*)(E + 786432);                         // (8,64,2048)
    float* bufB = (float*)(E + 4980736);                        // (8,64,2048)
    float* bufC = (float*)(E + 9175040);                        // (8,2048,64)
    float* bufM1 = (float*)(E + 13369344);                      // (8,128,2048)
    float* bufM2 = (float*)(E + 21757952);                      // (8,2048,128)
    unsigned short* bufM3h = (unsigned short*)(E + 30146560);   // (8,2048,128) bf16
    float* bufY4 = (float*)(E + 0);                             // (8,512,2048) aliases E

    // weight conversion (value-path weights only)
    wcvt_kernel<<<512, 256, 0, stream>>>(Wg2, Wg2h, 1024 * 128);
    wcvt_kernel<<<2048, 256, 0, stream>>>(W4, W4h, 512 * 1024);

    // Stage 0/1: 3D KNN + covariance features
    knn3_kernel<<<dim3(512, 8), 256, 0, stream>>>(x, idx);
    cov_kernel<<<dim3(8, 8), 256, 0, stream>>>(x, idx, h0);

    // conv1: 12 -> 64 (fp32)
    gemm_kernel<0, 0><<<dim3(16, 1, 8), 256, 0, stream>>>(W1, h0, b1, bufA, 64, 12, nullptr, nullptr);
    bnstats_kernel<<<64, 256, 0, stream>>>(bufA, gm1, bt1, scale, shift, 64);
    bnapply_kernel<<<4096, 256, 0, stream>>>(bufA, scale, shift, 6, 1, nullptr);

    // conv2: 64 -> 64 (fp32)
    gemm_kernel<0, 0><<<dim3(16, 1, 8), 256, 0, stream>>>(W2, bufA, b2, bufB, 64, 64, nullptr, nullptr);
    bnstats_kernel<<<64, 256, 0, stream>>>(bufB, gm2, bt2, scale, shift, 64);
    bnapply_kernel<<<4096, 256, 0, stream>>>(bufB, scale, shift, 6, 1, nullptr);

    // conv3: 64 -> 64 (fp32), dual write bufA (B,64,N) + bufC (B,N,64)
    gemm_kernel<0, 0><<<dim3(16, 1, 8), 256, 0, stream>>>(W3, bufB, b3, bufA, 64, 64, nullptr, nullptr);
    bnstats_kernel<<<64, 256, 0, stream>>>(bufA, gm3, bt3, scale, shift, 64);
    bnapply_kernel<<<4096, 256, 0, stream>>>(bufA, scale, shift, 6, 1, bufC);

    // graph layer 1 KNN (C=64, fp32 distances)
    norms_kernel<<<dim3(8, 8), 256, 0, stream>>>(bufA, nrm, 64);
    for (int b = 0; b < B_; b++) {
        gemm_kernel<0, 1><<<dim3(16, 16, 1), 256, 0, stream>>>(
            bufC + (size_t)b * N_ * 64, bufA + (size_t)b * 64 * N_, nullptr, bufD,
            2048, 64, nrm + b * N_, nrm + b * N_);
        topk_kernel<<<512, 256, 0, stream>>>(bufD, idx + (size_t)b * N_ * KNN);
    }
    gathermax_kernel<<<dim3(512, 8), 256, 0, stream>>>(bufC, idx, bufB, 6);

    // conv g1: 64 -> 128 (fp32, input (B,N,64))
    gemm_kernel<1, 0><<<dim3(16, 1, 8), 256, 0, stream>>>(Wg1, bufB, bg1, bufM1, 128, 64, nullptr, nullptr);
    bnstats_kernel<<<128, 256, 0, stream>>>(bufM1, gmg1, btg1, scale, shift, 128);
    bnapply_kernel<<<8192, 256, 0, stream>>>(bufM1, scale, shift, 7, 1, bufM2);

    // graph layer 2 KNN (C=128, fp32 distances)
    norms_kernel<<<dim3(8, 8), 256, 0, stream>>>(bufM1, nrm, 128);
    for (int b = 0; b < B_; b++) {
        gemm_kernel<0, 1><<<dim3(16, 16, 1), 256, 0, stream>>>(
            bufM2 + (size_t)b * N_ * 128, bufM1 + (size_t)b * 128 * N_, nullptr, bufD,
            2048, 128, nrm + b * N_, nrm + b * N_);
        topk_kernel<<<512, 256, 0, stream>>>(bufD, idx + (size_t)b * N_ * KNN);
    }
    gmaxh2_kernel<<<dim3(128, 8), 256, 0, stream>>>(bufM2, idx, bufM3h);

    // conv g2: 128 -> 1024 (bf16 MFMA, value path)
    mgemm_kernel<<<dim3(16, 8, 8), 256, 0, stream>>>(Wg2h, bufM3h, bg2, bufL, 1024, 128);
    bnstats_kernel<<<1024, 256, 0, stream>>>(bufL, gmg2, btg2, scale, shift, 1024);
    bnt_kernel<<<dim3(32, 16, 8), 256, 0, stream>>>(bufL, scale, shift, bufLh, 1024);

    // conv4: 1024 -> 512 (bf16 MFMA), BN folded into final max
    mgemm_kernel<<<dim3(16, 4, 8), 256, 0, stream>>>(W4h, bufLh, b4, bufY4, 512, 1024);
    bnstats_kernel<<<512, 256, 0, stream>>>(bufY4, gm4, bt4, scale, shift, 512);
    finalmax_kernel<<<dim3(512, 8), 256, 0, stream>>>(bufY4, scale, shift, out);
}

// Round 5
// 2081.088 us; speedup vs baseline: 2.3594x; 1.0325x over previous
//
#include <hip/hip_runtime.h>
#include <math.h>

#define B_ 8
#define N_ 2048
#define KNN 16

typedef __attribute__((ext_vector_type(4))) float f32x4;
typedef __attribute__((ext_vector_type(8))) short bf16x8;

__device__ inline unsigned short f2bf(float f) {
    unsigned int x = __float_as_uint(f);
    unsigned int r = (x + 0x7fffu + ((x >> 16) & 1u)) >> 16;  // RNE
    return (unsigned short)r;
}

// Lexicographic (value, slot) min-tree over 32 register-resident candidates.
// All indices compile-time (fully unrolled) -> stays in VGPRs. Full (v,u)
// compare at every node: after the first fold the leaf ranges interleave,
// so a value-only compare would break ties wrongly.
#define TREE32(dd, LV, LU)                                                  \
    {                                                                       \
        float tv[16]; int tu[16];                                           \
        _Pragma("unroll") for (int p = 0; p < 16; p++) {                    \
            bool c = dd[2 * p + 1] < dd[2 * p];                             \
            tv[p] = c ? dd[2 * p + 1] : dd[2 * p];                          \
            tu[p] = c ? 2 * p + 1 : 2 * p;                                  \
        }                                                                   \
        _Pragma("unroll") for (int p = 0; p < 8; p++) {                     \
            bool c = tv[p + 8] < tv[p] ||                                   \
                     (tv[p + 8] == tv[p] && tu[p + 8] < tu[p]);             \
            tv[p] = c ? tv[p + 8] : tv[p];                                  \
            tu[p] = c ? tu[p + 8] : tu[p];                                  \
        }                                                                   \
        _Pragma("unroll") for (int p = 0; p < 4; p++) {                     \
            bool c = tv[p + 4] < tv[p] ||                                   \
                     (tv[p + 4] == tv[p] && tu[p + 4] < tu[p]);             \
            tv[p] = c ? tv[p + 4] : tv[p];                                  \
            tu[p] = c ? tu[p + 4] : tu[p];                                  \
        }                                                                   \
        _Pragma("unroll") for (int p = 0; p < 2; p++) {                     \
            bool c = tv[p + 2] < tv[p] ||                                   \
                     (tv[p + 2] == tv[p] && tu[p + 2] < tu[p]);             \
            tv[p] = c ? tv[p + 2] : tv[p];                                  \
            tu[p] = c ? tu[p + 2] : tu[p];                                  \
        }                                                                   \
        {                                                                   \
            bool c = tv[1] < tv[0] || (tv[1] == tv[0] && tu[1] < tu[0]);    \
            LV = c ? tv[1] : tv[0];                                         \
            LU = c ? tu[1] : tu[0];                                         \
        }                                                                   \
    }

// ---------------------------------------------------------------------------
// KNN on 3D input points — wave-per-query, register-resident extraction.
// ---------------------------------------------------------------------------
__global__ __launch_bounds__(256) void knn3_kernel(const float* __restrict__ x,
                                                   int* __restrict__ idx) {
    __shared__ float px[N_], py[N_], pz[N_];
    int b = blockIdx.y;
    const float* xb = x + (size_t)b * N_ * 3;
    for (int e = threadIdx.x; e < N_; e += 256) {
        px[e] = xb[e * 3 + 0];
        py[e] = xb[e * 3 + 1];
        pz[e] = xb[e * 3 + 2];
    }
    __syncthreads();

    int wave = threadIdx.x >> 6, lane = threadIdx.x & 63;
    int i = blockIdx.x * 4 + wave;
    float qx = px[i], qy = py[i], qz = pz[i];

    float d[32];
#pragma unroll
    for (int t = 0; t < 32; t++) {
        int j = lane + t * 64;
        float dx = px[j] - qx, dy = py[j] - qy, dz = pz[j] - qz;
        d[t] = dx * dx + dy * dy + dz * dz;
    }

    int* op = idx + ((size_t)b * N_ + i) * KNN;
    for (int r = 0; r < KNN; r++) {
        float lv; int lu;
        TREE32(d, lv, lu);
        float md = lv;
        int mi = lane + lu * 64;  // global index; u monotone in j per lane
#pragma unroll
        for (int s = 32; s > 0; s >>= 1) {
            float od = __shfl_xor(md, s, 64);
            int oi = __shfl_xor(mi, s, 64);
            if (od < md || (od == md && oi < mi)) { md = od; mi = oi; }
        }
        if (lane == 0) op[r] = mi;
        bool kill = ((mi & 63) == lane);
        int tw = mi >> 6;
#pragma unroll
        for (int t = 0; t < 32; t++)
            if (kill && t == tw) d[t] = 3.4e38f;
    }
}

// ---------------------------------------------------------------------------
// Covariance features: h0 (B,12,N).
// ---------------------------------------------------------------------------
__global__ __launch_bounds__(256) void cov_kernel(const float* __restrict__ x,
                                                  const int* __restrict__ idx,
                                                  float* __restrict__ h0) {
    int b = blockIdx.y;
    int n = blockIdx.x * 256 + threadIdx.x;
    const int* ip = idx + ((size_t)b * N_ + n) * KNN;

    float px[KNN], py[KNN], pz[KNN];
    float mx = 0.f, my = 0.f, mz = 0.f;
#pragma unroll
    for (int k = 0; k < KNN; k++) {
        int j = ip[k];
        const float* p = x + ((size_t)b * N_ + j) * 3;
        px[k] = p[0]; py[k] = p[1]; pz[k] = p[2];
        mx += px[k]; my += py[k]; mz += pz[k];
    }
    mx *= (1.f / KNN); my *= (1.f / KNN); mz *= (1.f / KNN);

    float c00 = 0, c01 = 0, c02 = 0, c11 = 0, c12 = 0, c22 = 0;
#pragma unroll
    for (int k = 0; k < KNN; k++) {
        float dx = px[k] - mx, dy = py[k] - my, dz = pz[k] - mz;
        c00 += dx * dx; c01 += dx * dy; c02 += dx * dz;
        c11 += dy * dy; c12 += dy * dz; c22 += dz * dz;
    }
    float* hb = h0 + (size_t)b * 12 * N_;
    const float* xp = x + ((size_t)b * N_ + n) * 3;
    hb[0 * N_ + n] = xp[0];
    hb[1 * N_ + n] = xp[1];
    hb[2 * N_ + n] = xp[2];
    hb[3 * N_ + n] = c00; hb[4 * N_ + n] = c01; hb[5 * N_ + n] = c02;
    hb[6 * N_ + n] = c01; hb[7 * N_ + n] = c11; hb[8 * N_ + n] = c12;
    hb[9 * N_ + n] = c02; hb[10 * N_ + n] = c12; hb[11 * N_ + n] = c22;
}

// ---------------------------------------------------------------------------
// Tiled fp32 GEMM (KNN-selection path: conv1-3, g1 conv, distance GEMMs).
// MODE 0: Y[b,o,n] = sum_c A[o,c]*X[b,c,n] + bias[o]
// MODE 1: Y[o,n]   = nrmR[o] + nrmC[n] - 2*sum_c A[o,c]*X[c,n]  (z==1)
// XLAYOUT 0: X[(b*C+c)*N+n]   XLAYOUT 1: X[(b*N+n)*C+c]
// ---------------------------------------------------------------------------
template <int XLAYOUT, int MODE>
__global__ __launch_bounds__(256) void gemm_kernel(const float* __restrict__ A,
                                                   const float* __restrict__ X,
                                                   const float* __restrict__ bias,
                                                   float* __restrict__ Y,
                                                   int O, int C,
                                                   const float* __restrict__ nrmR,
                                                   const float* __restrict__ nrmC) {
    __shared__ float Wt[16][132];
    __shared__ float Xt[16][132];
    const int N = N_;
    int b = blockIdx.z;
    int oB = blockIdx.y * 128, nB = blockIdx.x * 128;
    const float* Xb = X + (size_t)b * C * N;
    int tid = threadIdx.x;
    int tn = tid & 15, to = tid >> 4;

    float acc[8][8];
#pragma unroll
    for (int i = 0; i < 8; i++)
#pragma unroll
        for (int j = 0; j < 8; j++) acc[i][j] = 0.f;

    for (int c0 = 0; c0 < C; c0 += 16) {
#pragma unroll
        for (int r = 0; r < 8; r++) {
            int e = tid + r * 256;
            int k = e & 15, o = e >> 4;
            float v = 0.f;
            if (c0 + k < C && oB + o < O) v = A[(size_t)(oB + o) * C + c0 + k];
            Wt[k][o] = v;
        }
#pragma unroll
        for (int r = 0; r < 8; r++) {
            int e = tid + r * 256;
            float v = 0.f;
            int k, n;
            if (XLAYOUT == 0) {
                n = e & 127; k = e >> 7;
                if (c0 + k < C) v = Xb[(size_t)(c0 + k) * N + nB + n];
            } else {
                k = e & 15; n = e >> 4;
                if (c0 + k < C) v = Xb[(size_t)(nB + n) * C + c0 + k];
            }
            Xt[k][n] = v;
        }
        __syncthreads();
#pragma unroll
        for (int k = 0; k < 16; k++) {
            float a[8], xv[8];
#pragma unroll
            for (int i = 0; i < 8; i++) a[i] = Wt[k][to * 8 + i];
#pragma unroll
            for (int m = 0; m < 4; m++) {
                xv[2 * m] = Xt[k][tn * 2 + 32 * m];
                xv[2 * m + 1] = Xt[k][tn * 2 + 32 * m + 1];
            }
#pragma unroll
            for (int i = 0; i < 8; i++)
#pragma unroll
                for (int j = 0; j < 8; j++) acc[i][j] = fmaf(a[i], xv[j], acc[i][j]);
        }
        __syncthreads();
    }

#pragma unroll
    for (int i = 0; i < 8; i++) {
        int o = oB + to * 8 + i;
        if (o >= O) continue;
        float bv = (MODE == 0) ? bias[o] : 0.f;
        float nr = (MODE == 1) ? nrmR[o] : 0.f;
#pragma unroll
        for (int m = 0; m < 4; m++) {
            int n0 = nB + tn * 2 + 32 * m;
            float v0 = acc[i][2 * m], v1 = acc[i][2 * m + 1];
            if (MODE == 0) { v0 += bv; v1 += bv; }
            else {
                v0 = nr + nrmC[n0] - 2.f * v0;
                v1 = nr + nrmC[n0 + 1] - 2.f * v1;
            }
            float2 st = make_float2(v0, v1);
            *reinterpret_cast<float2*>(&Y[((size_t)b * O + o) * N + n0]) = st;
        }
    }
}

// ---------------------------------------------------------------------------
// bf16 MFMA GEMM (value path only: g2 conv, conv4).
// ---------------------------------------------------------------------------
__global__ __launch_bounds__(256) void mgemm_kernel(const unsigned short* __restrict__ A,
                                                    const unsigned short* __restrict__ X,
                                                    const float* __restrict__ bias,
                                                    float* __restrict__ Y,
                                                    int O, int C) {
    __shared__ unsigned short At[128][72];
    __shared__ unsigned short Bt[128][72];
    int b = blockIdx.z;
    int oB = blockIdx.y * 128, nB = blockIdx.x * 128;
    const unsigned short* Xb = X + (size_t)b * N_ * C;
    int tid = threadIdx.x;
    int lane = tid & 63, w = tid >> 6;
    int wm = w & 1, wn = w >> 1;
    int lr = lane & 15, lg = lane >> 4;

    f32x4 acc[4][4];
#pragma unroll
    for (int m = 0; m < 4; m++)
#pragma unroll
        for (int n = 0; n < 4; n++) acc[m][n] = (f32x4){0.f, 0.f, 0.f, 0.f};

    for (int c0 = 0; c0 < C; c0 += 64) {
#pragma unroll
        for (int r = 0; r < 4; r++) {
            int t = tid + r * 256;
            int row = t >> 3, c8 = (t & 7) * 8;
            float4 va = *reinterpret_cast<const float4*>(&A[(size_t)(oB + row) * C + c0 + c8]);
            *reinterpret_cast<float4*>(&At[row][c8]) = va;
            float4 vb = *reinterpret_cast<const float4*>(&Xb[(size_t)(nB + row) * C + c0 + c8]);
            *reinterpret_cast<float4*>(&Bt[row][c8]) = vb;
        }
        __syncthreads();
#pragma unroll
        for (int kk = 0; kk < 2; kk++) {
            bf16x8 af[4], bfv[4];
#pragma unroll
            for (int m = 0; m < 4; m++)
                af[m] = *reinterpret_cast<const bf16x8*>(&At[wm * 64 + m * 16 + lr][kk * 32 + lg * 8]);
#pragma unroll
            for (int n = 0; n < 4; n++)
                bfv[n] = *reinterpret_cast<const bf16x8*>(&Bt[wn * 64 + n * 16 + lr][kk * 32 + lg * 8]);
#pragma unroll
            for (int m = 0; m < 4; m++)
#pragma unroll
                for (int n = 0; n < 4; n++)
                    acc[m][n] = __builtin_amdgcn_mfma_f32_16x16x32_bf16(af[m], bfv[n], acc[m][n], 0, 0, 0);
        }
        __syncthreads();
    }

#pragma unroll
    for (int m = 0; m < 4; m++) {
#pragma unroll
        for (int r = 0; r < 4; r++) {
            int o = oB + wm * 64 + m * 16 + lg * 4 + r;
            float bv = bias[o];
#pragma unroll
            for (int n = 0; n < 4; n++) {
                int nv = nB + wn * 64 + n * 16 + lr;
                Y[((size_t)b * O + o) * N_ + nv] = acc[m][n][r] + bv;
            }
        }
    }
}

// ---------------------------------------------------------------------------
// Per-channel BN stats over (B,N)
// ---------------------------------------------------------------------------
__global__ __launch_bounds__(256) void bnstats_kernel(const float* __restrict__ y,
                                                      const float* __restrict__ gm,
                                                      const float* __restrict__ bt,
                                                      float* __restrict__ scale,
                                                      float* __restrict__ shift, int O) {
    int o = blockIdx.x;
    float s = 0.f, s2 = 0.f;
    for (int e = threadIdx.x; e < B_ * N_; e += 256) {
        int b = e >> 11, n = e & (N_ - 1);
        float v = y[((size_t)b * O + o) * N_ + n];
        s += v;
        s2 = fmaf(v, v, s2);
    }
#pragma unroll
    for (int off = 32; off; off >>= 1) {
        s += __shfl_down(s, off, 64);
        s2 += __shfl_down(s2, off, 64);
    }
    __shared__ float red[8];
    int lane = threadIdx.x & 63, w = threadIdx.x >> 6;
    if (lane == 0) { red[w] = s; red[4 + w] = s2; }
    __syncthreads();
    if (threadIdx.x == 0) {
        s = red[0] + red[1] + red[2] + red[3];
        s2 = red[4] + red[5] + red[6] + red[7];
        float mu = s * (1.f / (B_ * N_));
        float var = s2 * (1.f / (B_ * N_)) - mu * mu;
        float inv = 1.f / sqrtf(var + 1e-5f);
        float sc = gm[o] * inv;
        scale[o] = sc;
        shift[o] = fmaf(-mu, sc, bt[o]);
    }
}

// ---------------------------------------------------------------------------
// Apply BN + ReLU in place; optional transposed fp32 (B,N,C) copy.
// ---------------------------------------------------------------------------
__global__ __launch_bounds__(256) void bnapply_kernel(float* __restrict__ y,
                                                      const float* __restrict__ scale,
                                                      const float* __restrict__ shift,
                                                      int oLog, int relu,
                                                      float* __restrict__ ft) {
    size_t i = (size_t)blockIdx.x * 256 + threadIdx.x;
    int n = (int)(i & (N_ - 1));
    size_t t = i >> 11;
    int o = (int)(t & ((1u << oLog) - 1));
    int b = (int)(t >> oLog);
    float v = fmaf(y[i], scale[o], shift[o]);
    if (relu) v = fmaxf(v, 0.f);
    y[i] = v;
    if (ft) ft[(((size_t)b << 11) + n) * (1u << oLog) + o] = v;
}

// ---------------------------------------------------------------------------
// BN apply + ReLU + transpose, fp32 (B,O,N) -> bf16 (B,N,O). 64x64 LDS tile.
// ---------------------------------------------------------------------------
__global__ __launch_bounds__(256) void bnt_kernel(const float* __restrict__ y,
                                                  const float* __restrict__ scale,
                                                  const float* __restrict__ shift,
                                                  unsigned short* __restrict__ ft, int O) {
    __shared__ float tile[64][65];
    int b = blockIdx.z;
    int n0 = blockIdx.x * 64, o0 = blockIdx.y * 64;
    int t = threadIdx.x;
#pragma unroll
    for (int rr = 0; rr < 16; rr++) {
        int ol = rr * 4 + (t >> 6), nl = t & 63;
        float v = y[((size_t)b * O + o0 + ol) * N_ + n0 + nl];
        v = fmaf(v, scale[o0 + ol], shift[o0 + ol]);
        tile[ol][nl] = fmaxf(v, 0.f);
    }
    __syncthreads();
#pragma unroll
    for (int rr = 0; rr < 2; rr++) {
        int e = t + rr * 256;
        int n = e >> 3, og = (e & 7) * 8;
        unsigned short u[8];
#pragma unroll
        for (int j = 0; j < 8; j++) u[j] = f2bf(tile[og + j][n]);
        uint4 pk;
        pk.x = (unsigned)u[0] | ((unsigned)u[1] << 16);
        pk.y = (unsigned)u[2] | ((unsigned)u[3] << 16);
        pk.z = (unsigned)u[4] | ((unsigned)u[5] << 16);
        pk.w = (unsigned)u[6] | ((unsigned)u[7] << 16);
        *reinterpret_cast<uint4*>(&ft[((size_t)b * N_ + n0 + n) * O + o0 + og]) = pk;
    }
}

// ---------------------------------------------------------------------------
// Squared norms per point from (B,C,N) fp32 (ascending-c fma == GEMM order).
// ---------------------------------------------------------------------------
__global__ __launch_bounds__(256) void norms_kernel(const float* __restrict__ h,
                                                    float* __restrict__ nrm, int C) {
    int b = blockIdx.y;
    int i = blockIdx.x * 256 + threadIdx.x;
    const float* hp = h + (size_t)b * C * N_;
    float s = 0.f;
    for (int c = 0; c < C; c++) {
        float v = hp[(size_t)c * N_ + i];
        s = fmaf(v, v, s);
    }
    nrm[(b << 11) + i] = s;
}

// ---------------------------------------------------------------------------
// Top-16 per row of 2048x2048 distance matrix — wave per row, register-
// resident (no LDS). float4 row loads; j = t*256 + lane*4 + q.
// ---------------------------------------------------------------------------
__global__ __launch_bounds__(256) void topk_kernel(const float* __restrict__ D,
                                                   int* __restrict__ idx) {
    int wave = threadIdx.x >> 6, lane = threadIdx.x & 63;
    int i = blockIdx.x * 4 + wave;
    const float* dp = D + (size_t)i * N_;

    float d[32];
#pragma unroll
    for (int t = 0; t < 8; t++) {
        float4 v = *reinterpret_cast<const float4*>(&dp[t * 256 + lane * 4]);
        d[t * 4 + 0] = v.x; d[t * 4 + 1] = v.y;
        d[t * 4 + 2] = v.z; d[t * 4 + 3] = v.w;
    }

    int* op = idx + (size_t)i * KNN;
    for (int r = 0; r < KNN; r++) {
        float lv; int lu;
        TREE32(d, lv, lu);
        float md = lv;
        int mi = ((lu >> 2) << 8) + lane * 4 + (lu & 3);  // global j, monotone in u
#pragma unroll
        for (int s = 32; s > 0; s >>= 1) {
            float od = __shfl_xor(md, s, 64);
            int oi = __shfl_xor(mi, s, 64);
            if (od < md || (od == md && oi < mi)) { md = od; mi = oi; }
        }
        if (lane == 0) op[r] = mi;
        bool kill = (((mi >> 2) & 63) == lane);
        int uw = ((mi >> 8) << 2) | (mi & 3);
#pragma unroll
        for (int t = 0; t < 32; t++)
            if (kill && t == uw) d[t] = 3.4e38f;
    }
}

// ---------------------------------------------------------------------------
// Gather 16 neighbor fp32 rows (B,N,C), max over k -> fp32 (B,N,C).
// ---------------------------------------------------------------------------
__global__ __launch_bounds__(256) void gathermax_kernel(const float* __restrict__ ft,
                                                        const int* __restrict__ idx,
                                                        float* __restrict__ out, int cLog) {
    int C = 1 << cLog;
    int b = blockIdx.y;
    int nb = (blockIdx.x << (8 - cLog)) + (threadIdx.x >> cLog);
    int c = threadIdx.x & (C - 1);
    const int* ip = idx + (((size_t)b << 11) + nb) * KNN;
    float m = -3.4e38f;
#pragma unroll
    for (int k = 0; k < KNN; k++) {
        int j = ip[k];
        m = fmaxf(m, ft[(((size_t)b << 11) + j) * C + c]);
    }
    out[(((size_t)b << 11) + nb) * C + c] = m;
}

// ---------------------------------------------------------------------------
// Gather-max: fp32 (B,N,128) in -> bf16 (B,N,128) out (feeds g2 MFMA only).
// ---------------------------------------------------------------------------
__global__ __launch_bounds__(256) void gmaxh2_kernel(const float* __restrict__ ft,
                                                     const int* __restrict__ idx,
                                                     unsigned short* __restrict__ out) {
    const int C = 128;
    int b = blockIdx.y;
    int nb = blockIdx.x * 16 + (threadIdx.x >> 4);
    int cc = (threadIdx.x & 15) * 8;
    const int* ip = idx + (((size_t)b << 11) + nb) * KNN;
    float m[8];
#pragma unroll
    for (int q = 0; q < 8; q++) m[q] = -3.4e38f;
#pragma unroll
    for (int k = 0; k < KNN; k++) {
        int j = ip[k];
        const float* p = &ft[(((size_t)b << 11) + j) * C + cc];
        float4 a = *reinterpret_cast<const float4*>(p);
        float4 c2 = *reinterpret_cast<const float4*>(p + 4);
        m[0] = fmaxf(m[0], a.x); m[1] = fmaxf(m[1], a.y);
        m[2] = fmaxf(m[2], a.z); m[3] = fmaxf(m[3], a.w);
        m[4] = fmaxf(m[4], c2.x); m[5] = fmaxf(m[5], c2.y);
        m[6] = fmaxf(m[6], c2.z); m[7] = fmaxf(m[7], c2.w);
    }
    unsigned short u[8];
#pragma unroll
    for (int q = 0; q < 8; q++) u[q] = f2bf(m[q]);
    uint4 pk;
    pk.x = (unsigned)u[0] | ((unsigned)u[1] << 16);
    pk.y = (unsigned)u[2] | ((unsigned)u[3] << 16);
    pk.z = (unsigned)u[4] | ((unsigned)u[5] << 16);
    pk.w = (unsigned)u[6] | ((unsigned)u[7] << 16);
    *reinterpret_cast<uint4*>(&out[(((size_t)b << 11) + nb) * C + cc]) = pk;
}

// ---------------------------------------------------------------------------
// fp32 -> bf16 weight conversion
// ---------------------------------------------------------------------------
__global__ __launch_bounds__(256) void wcvt_kernel(const float* __restrict__ w,
                                                   unsigned short* __restrict__ wh, int count) {
    int i = blockIdx.x * 256 + threadIdx.x;
    if (i < count) wh[i] = f2bf(w[i]);
}

// ---------------------------------------------------------------------------
// Final: out[b,o] = max_n (y4[b,o,n]*scale[o]+shift[o])
// ---------------------------------------------------------------------------
__global__ __launch_bounds__(256) void finalmax_kernel(const float* __restrict__ y,
                                                       const float* __restrict__ scale,
                                                       const float* __restrict__ shift,
                                                       float* __restrict__ out) {
    int o = blockIdx.x, b = blockIdx.y;
    float s = scale[o], t = shift[o];
    const float* yp = y + ((size_t)b * 512 + o) * N_;
    float m = -3.4e38f;
    for (int n = threadIdx.x; n < N_; n += 256) m = fmaxf(m, fmaf(yp[n], s, t));
#pragma unroll
    for (int off = 32; off; off >>= 1) m = fmaxf(m, __shfl_down(m, off, 64));
    __shared__ float red[4];
    int lane = threadIdx.x & 63, w = threadIdx.x >> 6;
    if (lane == 0) red[w] = m;
    __syncthreads();
    if (threadIdx.x == 0)
        out[b * 512 + o] = fmaxf(fmaxf(red[0], red[1]), fmaxf(red[2], red[3]));
}

// ---------------------------------------------------------------------------
extern "C" void kernel_launch(void* const* d_in, const int* in_sizes, int n_in,
                              void* d_out, int out_size, void* d_ws, size_t ws_size,
                              hipStream_t stream) {
    const float* x = (const float*)d_in[0];
    const float* W1 = (const float*)d_in[1];
    const float* b1 = (const float*)d_in[2];
    const float* gm1 = (const float*)d_in[3];
    const float* bt1 = (const float*)d_in[4];
    const float* W2 = (const float*)d_in[5];
    const float* b2 = (const float*)d_in[6];
    const float* gm2 = (const float*)d_in[7];
    const float* bt2 = (const float*)d_in[8];
    const float* W3 = (const float*)d_in[9];
    const float* b3 = (const float*)d_in[10];
    const float* gm3 = (const float*)d_in[11];
    const float* bt3 = (const float*)d_in[12];
    const float* Wg1 = (const float*)d_in[13];
    const float* bg1 = (const float*)d_in[14];
    const float* gmg1 = (const float*)d_in[15];
    const float* btg1 = (const float*)d_in[16];
    const float* Wg2 = (const float*)d_in[17];
    const float* bg2 = (const float*)d_in[18];
    const float* gmg2 = (const float*)d_in[19];
    const float* btg2 = (const float*)d_in[20];
    const float* W4 = (const float*)d_in[21];
    const float* b4 = (const float*)d_in[22];
    const float* gm4 = (const float*)d_in[23];
    const float* bt4 = (const float*)d_in[24];
    float* out = (float*)d_out;

    // ---- workspace arena (byte offsets), total 154,214,400 bytes ----
    if (ws_size < 154214400ull) return;
    char* base = (char*)d_ws;
    float* scale = (float*)(base + 0);
    float* shift = (float*)(base + 4096);
    float* nrm = (float*)(base + 8192);
    int* idx = (int*)(base + 73728);
    unsigned short* Wg2h = (unsigned short*)(base + 1122304);
    unsigned short* W4h = (unsigned short*)(base + 1384448);
    float* bufD = (float*)(base + 2433024);                     // 16 MB
    float* bufL = (float*)(base + 19210240);                    // (8,1024,2048) f32
    unsigned short* bufLh = (unsigned short*)(base + 86319104); // (8,2048,1024) bf16
    char* E = base + 119873536;                                 // early region
    float* h0 = (float*)(E + 0);                                // (8,12,2048)
    float* bufA = (float*)(E + 786432);                         // (8,64,2048)
    float* bufB = (float*)(E + 4980736);                        // (8,64,2048)
    float* bufC = (float*)(E + 9175040);                        // (8,2048,64)
    float* bufM1 = (float*)(E + 13369344);                      // (8,128,2048)
    float* bufM2 = (float*)(E + 21757952);                      // (8,2048,128)
    unsigned short* bufM3h = (unsigned short*)(E + 30146560);   // (8,2048,128) bf16
    float* bufY4 = (float*)(E + 0);                             // (8,512,2048) aliases E

    // weight conversion (value-path weights only)
    wcvt_kernel<<<512, 256, 0, stream>>>(Wg2, Wg2h, 1024 * 128);
    wcvt_kernel<<<2048, 256, 0, stream>>>(W4, W4h, 512 * 1024);

    // Stage 0/1: 3D KNN + covariance features
    knn3_kernel<<<dim3(512, 8), 256, 0, stream>>>(x, idx);
    cov_kernel<<<dim3(8, 8), 256, 0, stream>>>(x, idx, h0);

    // conv1: 12 -> 64 (fp32)
    gemm_kernel<0, 0><<<dim3(16, 1, 8), 256, 0, stream>>>(W1, h0, b1, bufA, 64, 12, nullptr, nullptr);
    bnstats_kernel<<<64, 256, 0, stream>>>(bufA, gm1, bt1, scale, shift, 64);
    bnapply_kernel<<<4096, 256, 0, stream>>>(bufA, scale, shift, 6, 1, nullptr);

    // conv2: 64 -> 64 (fp32)
    gemm_kernel<0, 0><<<dim3(16, 1, 8), 256, 0, stream>>>(W2, bufA, b2, bufB, 64, 64, nullptr, nullptr);
    bnstats_kernel<<<64, 256, 0, stream>>>(bufB, gm2, bt2, scale, shift, 64);
    bnapply_kernel<<<4096, 256, 0, stream>>>(bufB, scale, shift, 6, 1, nullptr);

    // conv3: 64 -> 64 (fp32), dual write bufA (B,64,N) + bufC (B,N,64)
    gemm_kernel<0, 0><<<dim3(16, 1, 8), 256, 0, stream>>>(W3, bufB, b3, bufA, 64, 64, nullptr, nullptr);
    bnstats_kernel<<<64, 256, 0, stream>>>(bufA, gm3, bt3, scale, shift, 64);
    bnapply_kernel<<<4096, 256, 0, stream>>>(bufA, scale, shift, 6, 1, bufC);

    // graph layer 1 KNN (C=64, fp32 distances)
    norms_kernel<<<dim3(8, 8), 256, 0, stream>>>(bufA, nrm, 64);
    for (int b = 0; b < B_; b++) {
        gemm_kernel<0, 1><<<dim3(16, 16, 1), 256, 0, stream>>>(
            bufC + (size_t)b * N_ * 64, bufA + (size_t)b * 64 * N_, nullptr, bufD,
            2048, 64, nrm + b * N_, nrm + b * N_);
        topk_kernel<<<512, 256, 0, stream>>>(bufD, idx + (size_t)b * N_ * KNN);
    }
    gathermax_kernel<<<dim3(512, 8), 256, 0, stream>>>(bufC, idx, bufB, 6);

    // conv g1: 64 -> 128 (fp32, input (B,N,64))
    gemm_kernel<1, 0><<<dim3(16, 1, 8), 256, 0, stream>>>(Wg1, bufB, bg1, bufM1, 128, 64, nullptr, nullptr);
    bnstats_kernel<<<128, 256, 0, stream>>>(bufM1, gmg1, btg1, scale, shift, 128);
    bnapply_kernel<<<8192, 256, 0, stream>>>(bufM1, scale, shift, 7, 1, bufM2);

    // graph layer 2 KNN (C=128, fp32 distances)
    norms_kernel<<<dim3(8, 8), 256, 0, stream>>>(bufM1, nrm, 128);
    for (int b = 0; b < B_; b++) {
        gemm_kernel<0, 1><<<dim3(16, 16, 1), 256, 0, stream>>>(
            bufM2 + (size_t)b * N_ * 128, bufM1 + (size_t)b * 128 * N_, nullptr, bufD,
            2048, 128, nrm + b * N_, nrm + b * N_);
        topk_kernel<<<512, 256, 0, stream>>>(bufD, idx + (size_t)b * N_ * KNN);
    }
    gmaxh2_kernel<<<dim3(128, 8), 256, 0, stream>>>(bufM2, idx, bufM3h);

    // conv g2: 128 -> 1024 (bf16 MFMA, value path)
    mgemm_kernel<<<dim3(16, 8, 8), 256, 0, stream>>>(Wg2h, bufM3h, bg2, bufL, 1024, 128);
    bnstats_kernel<<<1024, 256, 0, stream>>>(bufL, gmg2, btg2, scale, shift, 1024);
    bnt_kernel<<<dim3(32, 16, 8), 256, 0, stream>>>(bufL, scale, shift, bufLh, 1024);

    // conv4: 1024 -> 512 (bf16 MFMA), BN folded into final max
    mgemm_kernel<<<dim3(16, 4, 8), 256, 0, stream>>>(W4h, bufLh, b4, bufY4, 512, 1024);
    bnstats_kernel<<<512, 256, 0, stream>>>(bufY4, gm4, bt4, scale, shift, 512);
    finalmax_kernel<<<dim3(512, 8), 256, 0, stream>>>(bufY4, scale, shift, out);
}

// Round 6
// 1012.012 us; speedup vs baseline: 4.8518x; 2.0564x over previous
//
#include <hip/hip_runtime.h>
#include <math.h>

#define B_ 8
#define N_ 2048
#define KNN 16

typedef __attribute__((ext_vector_type(4))) float f32x4;
typedef __attribute__((ext_vector_type(8))) short bf16x8;

__device__ inline unsigned short f2bf(float f) {
    unsigned int x = __float_as_uint(f);
    unsigned int r = (x + 0x7fffu + ((x >> 16) & 1u)) >> 16;  // RNE
    return (unsigned short)r;
}

// Monotone bijection fp32 -> u32 (handles negatives; order-preserving).
__device__ inline unsigned int fflip(float f) {
    unsigned int u = __float_as_uint(f);
    return u ^ (0x80000000u | (unsigned int)((int)u >> 31));
}

// 64-bit shuffle-xor across the 64-lane wave.
__device__ inline unsigned long long shflx64(unsigned long long v, int m) {
    int lo = __shfl_xor((int)(unsigned int)(v & 0xffffffffull), m, 64);
    int hi = __shfl_xor((int)(unsigned int)(v >> 32), m, 64);
    return ((unsigned long long)(unsigned int)hi << 32) | (unsigned int)lo;
}

// Min-tree over 32 register-resident u64 keys (fully unrolled, static idx).
// Key = (flip(d) << 11) | global_idx  ->  plain u64 '<' is exact (d, idx)
// lexicographic order == lax.top_k tie semantics.
#define TREE32K(kk, MK)                                                     \
    {                                                                       \
        unsigned long long tv[16];                                          \
        _Pragma("unroll") for (int p = 0; p < 16; p++)                      \
            tv[p] = kk[2 * p + 1] < kk[2 * p] ? kk[2 * p + 1] : kk[2 * p];  \
        _Pragma("unroll") for (int p = 0; p < 8; p++)                       \
            if (tv[p + 8] < tv[p]) tv[p] = tv[p + 8];                       \
        _Pragma("unroll") for (int p = 0; p < 4; p++)                       \
            if (tv[p + 4] < tv[p]) tv[p] = tv[p + 4];                       \
        _Pragma("unroll") for (int p = 0; p < 2; p++)                       \
            if (tv[p + 2] < tv[p]) tv[p] = tv[p + 2];                       \
        MK = tv[1] < tv[0] ? tv[1] : tv[0];                                 \
    }

// ---------------------------------------------------------------------------
// KNN on 3D input points — wave-per-query, u64-key register extraction.
// ---------------------------------------------------------------------------
__global__ __launch_bounds__(256, 4) void knn3_kernel(const float* __restrict__ x,
                                                      int* __restrict__ idx) {
    __shared__ float px[N_], py[N_], pz[N_];
    int b = blockIdx.y;
    const float* xb = x + (size_t)b * N_ * 3;
    for (int e = threadIdx.x; e < N_; e += 256) {
        px[e] = xb[e * 3 + 0];
        py[e] = xb[e * 3 + 1];
        pz[e] = xb[e * 3 + 2];
    }
    __syncthreads();

    int wave = threadIdx.x >> 6, lane = threadIdx.x & 63;
    int i = blockIdx.x * 4 + wave;
    float qx = px[i], qy = py[i], qz = pz[i];

    unsigned long long k[32];
#pragma unroll
    for (int t = 0; t < 32; t++) {
        int j = lane + t * 64;
        float dx = px[j] - qx, dy = py[j] - qy, dz = pz[j] - qz;
        float d = dx * dx + dy * dy + dz * dz;
        k[t] = ((unsigned long long)fflip(d) << 11) | (unsigned int)j;
    }

    int* op = idx + ((size_t)b * N_ + i) * KNN;
    for (int r = 0; r < KNN; r++) {
        unsigned long long mk;
        TREE32K(k, mk);
#pragma unroll
        for (int s = 32; s > 0; s >>= 1) {
            unsigned long long ok = shflx64(mk, s);
            if (ok < mk) mk = ok;
        }
        if (lane == 0) op[r] = (int)(mk & 2047u);
#pragma unroll
        for (int t = 0; t < 32; t++)
            if (k[t] == mk) k[t] = ~0ull;  // unique key -> kills exactly one
    }
}

// ---------------------------------------------------------------------------
// Covariance features: h0 (B,12,N).
// ---------------------------------------------------------------------------
__global__ __launch_bounds__(256) void cov_kernel(const float* __restrict__ x,
                                                  const int* __restrict__ idx,
                                                  float* __restrict__ h0) {
    int b = blockIdx.y;
    int n = blockIdx.x * 256 + threadIdx.x;
    const int* ip = idx + ((size_t)b * N_ + n) * KNN;

    float px[KNN], py[KNN], pz[KNN];
    float mx = 0.f, my = 0.f, mz = 0.f;
#pragma unroll
    for (int k = 0; k < KNN; k++) {
        int j = ip[k];
        const float* p = x + ((size_t)b * N_ + j) * 3;
        px[k] = p[0]; py[k] = p[1]; pz[k] = p[2];
        mx += px[k]; my += py[k]; mz += pz[k];
    }
    mx *= (1.f / KNN); my *= (1.f / KNN); mz *= (1.f / KNN);

    float c00 = 0, c01 = 0, c02 = 0, c11 = 0, c12 = 0, c22 = 0;
#pragma unroll
    for (int k = 0; k < KNN; k++) {
        float dx = px[k] - mx, dy = py[k] - my, dz = pz[k] - mz;
        c00 += dx * dx; c01 += dx * dy; c02 += dx * dz;
        c11 += dy * dy; c12 += dy * dz; c22 += dz * dz;
    }
    float* hb = h0 + (size_t)b * 12 * N_;
    const float* xp = x + ((size_t)b * N_ + n) * 3;
    hb[0 * N_ + n] = xp[0];
    hb[1 * N_ + n] = xp[1];
    hb[2 * N_ + n] = xp[2];
    hb[3 * N_ + n] = c00; hb[4 * N_ + n] = c01; hb[5 * N_ + n] = c02;
    hb[6 * N_ + n] = c01; hb[7 * N_ + n] = c11; hb[8 * N_ + n] = c12;
    hb[9 * N_ + n] = c02; hb[10 * N_ + n] = c12; hb[11 * N_ + n] = c22;
}

// ---------------------------------------------------------------------------
// Tiled fp32 GEMM (KNN-selection path: conv1-3, g1 conv, distance GEMMs).
// MODE 0: Y[b,o,n] = sum_c A[o,c]*X[b,c,n] + bias[o]   (A shared over b)
// MODE 1: Y[b,o,n] = nrmR[b,o]+nrmC[b,n]-2*sum_c A[b,o,c]*X[b,c,n]
//         (A, nrm advance per batch; O == N_ )
// XLAYOUT 0: X[(b*C+c)*N+n]   XLAYOUT 1: X[(b*N+n)*C+c]
// ---------------------------------------------------------------------------
template <int XLAYOUT, int MODE>
__global__ __launch_bounds__(256) void gemm_kernel(const float* __restrict__ A,
                                                   const float* __restrict__ X,
                                                   const float* __restrict__ bias,
                                                   float* __restrict__ Y,
                                                   int O, int C,
                                                   const float* __restrict__ nrmR,
                                                   const float* __restrict__ nrmC) {
    __shared__ float Wt[16][132];
    __shared__ float Xt[16][132];
    const int N = N_;
    int b = blockIdx.z;
    int oB = blockIdx.y * 128, nB = blockIdx.x * 128;
    const float* Ab = (MODE == 1) ? A + (size_t)b * N_ * C : A;
    const float* Xb = X + (size_t)b * C * N;
    const float* nR = (MODE == 1) ? nrmR + (size_t)b * N_ : nrmR;
    const float* nC = (MODE == 1) ? nrmC + (size_t)b * N_ : nrmC;
    int tid = threadIdx.x;
    int tn = tid & 15, to = tid >> 4;

    float acc[8][8];
#pragma unroll
    for (int i = 0; i < 8; i++)
#pragma unroll
        for (int j = 0; j < 8; j++) acc[i][j] = 0.f;

    for (int c0 = 0; c0 < C; c0 += 16) {
#pragma unroll
        for (int r = 0; r < 8; r++) {
            int e = tid + r * 256;
            int k = e & 15, o = e >> 4;
            float v = 0.f;
            if (c0 + k < C && oB + o < O) v = Ab[(size_t)(oB + o) * C + c0 + k];
            Wt[k][o] = v;
        }
#pragma unroll
        for (int r = 0; r < 8; r++) {
            int e = tid + r * 256;
            float v = 0.f;
            int k, n;
            if (XLAYOUT == 0) {
                n = e & 127; k = e >> 7;
                if (c0 + k < C) v = Xb[(size_t)(c0 + k) * N + nB + n];
            } else {
                k = e & 15; n = e >> 4;
                if (c0 + k < C) v = Xb[(size_t)(nB + n) * C + c0 + k];
            }
            Xt[k][n] = v;
        }
        __syncthreads();
#pragma unroll
        for (int k = 0; k < 16; k++) {
            float a[8], xv[8];
#pragma unroll
            for (int i = 0; i < 8; i++) a[i] = Wt[k][to * 8 + i];
#pragma unroll
            for (int m = 0; m < 4; m++) {
                xv[2 * m] = Xt[k][tn * 2 + 32 * m];
                xv[2 * m + 1] = Xt[k][tn * 2 + 32 * m + 1];
            }
#pragma unroll
            for (int i = 0; i < 8; i++)
#pragma unroll
                for (int j = 0; j < 8; j++) acc[i][j] = fmaf(a[i], xv[j], acc[i][j]);
        }
        __syncthreads();
    }

#pragma unroll
    for (int i = 0; i < 8; i++) {
        int o = oB + to * 8 + i;
        if (o >= O) continue;
        float bv = (MODE == 0) ? bias[o] : 0.f;
        float nr = (MODE == 1) ? nR[o] : 0.f;
#pragma unroll
        for (int m = 0; m < 4; m++) {
            int n0 = nB + tn * 2 + 32 * m;
            float v0 = acc[i][2 * m], v1 = acc[i][2 * m + 1];
            if (MODE == 0) { v0 += bv; v1 += bv; }
            else {
                v0 = nr + nC[n0] - 2.f * v0;
                v1 = nr + nC[n0 + 1] - 2.f * v1;
            }
            float2 st = make_float2(v0, v1);
            *reinterpret_cast<float2*>(&Y[((size_t)b * O + o) * N + n0]) = st;
        }
    }
}

// ---------------------------------------------------------------------------
// bf16 MFMA GEMM (value path only: g2 conv, conv4).
// ---------------------------------------------------------------------------
__global__ __launch_bounds__(256) void mgemm_kernel(const unsigned short* __restrict__ A,
                                                    const unsigned short* __restrict__ X,
                                                    const float* __restrict__ bias,
                                                    float* __restrict__ Y,
                                                    int O, int C) {
    __shared__ unsigned short At[128][72];
    __shared__ unsigned short Bt[128][72];
    int b = blockIdx.z;
    int oB = blockIdx.y * 128, nB = blockIdx.x * 128;
    const unsigned short* Xb = X + (size_t)b * N_ * C;
    int tid = threadIdx.x;
    int lane = tid & 63, w = tid >> 6;
    int wm = w & 1, wn = w >> 1;
    int lr = lane & 15, lg = lane >> 4;

    f32x4 acc[4][4];
#pragma unroll
    for (int m = 0; m < 4; m++)
#pragma unroll
        for (int n = 0; n < 4; n++) acc[m][n] = (f32x4){0.f, 0.f, 0.f, 0.f};

    for (int c0 = 0; c0 < C; c0 += 64) {
#pragma unroll
        for (int r = 0; r < 4; r++) {
            int t = tid + r * 256;
            int row = t >> 3, c8 = (t & 7) * 8;
            float4 va = *reinterpret_cast<const float4*>(&A[(size_t)(oB + row) * C + c0 + c8]);
            *reinterpret_cast<float4*>(&At[row][c8]) = va;
            float4 vb = *reinterpret_cast<const float4*>(&Xb[(size_t)(nB + row) * C + c0 + c8]);
            *reinterpret_cast<float4*>(&Bt[row][c8]) = vb;
        }
        __syncthreads();
#pragma unroll
        for (int kk = 0; kk < 2; kk++) {
            bf16x8 af[4], bfv[4];
#pragma unroll
            for (int m = 0; m < 4; m++)
                af[m] = *reinterpret_cast<const bf16x8*>(&At[wm * 64 + m * 16 + lr][kk * 32 + lg * 8]);
#pragma unroll
            for (int n = 0; n < 4; n++)
                bfv[n] = *reinterpret_cast<const bf16x8*>(&Bt[wn * 64 + n * 16 + lr][kk * 32 + lg * 8]);
#pragma unroll
            for (int m = 0; m < 4; m++)
#pragma unroll
                for (int n = 0; n < 4; n++)
                    acc[m][n] = __builtin_amdgcn_mfma_f32_16x16x32_bf16(af[m], bfv[n], acc[m][n], 0, 0, 0);
        }
        __syncthreads();
    }

#pragma unroll
    for (int m = 0; m < 4; m++) {
#pragma unroll
        for (int r = 0; r < 4; r++) {
            int o = oB + wm * 64 + m * 16 + lg * 4 + r;
            float bv = bias[o];
#pragma unroll
            for (int n = 0; n < 4; n++) {
                int nv = nB + wn * 64 + n * 16 + lr;
                Y[((size_t)b * O + o) * N_ + nv] = acc[m][n][r] + bv;
            }
        }
    }
}

// ---------------------------------------------------------------------------
// Per-channel BN stats over (B,N)
// ---------------------------------------------------------------------------
__global__ __launch_bounds__(256) void bnstats_kernel(const float* __restrict__ y,
                                                      const float* __restrict__ gm,
                                                      const float* __restrict__ bt,
                                                      float* __restrict__ scale,
                                                      float* __restrict__ shift, int O) {
    int o = blockIdx.x;
    float s = 0.f, s2 = 0.f;
    for (int e = threadIdx.x; e < B_ * N_; e += 256) {
        int b = e >> 11, n = e & (N_ - 1);
        float v = y[((size_t)b * O + o) * N_ + n];
        s += v;
        s2 = fmaf(v, v, s2);
    }
#pragma unroll
    for (int off = 32; off; off >>= 1) {
        s += __shfl_down(s, off, 64);
        s2 += __shfl_down(s2, off, 64);
    }
    __shared__ float red[8];
    int lane = threadIdx.x & 63, w = threadIdx.x >> 6;
    if (lane == 0) { red[w] = s; red[4 + w] = s2; }
    __syncthreads();
    if (threadIdx.x == 0) {
        s = red[0] + red[1] + red[2] + red[3];
        s2 = red[4] + red[5] + red[6] + red[7];
        float mu = s * (1.f / (B_ * N_));
        float var = s2 * (1.f / (B_ * N_)) - mu * mu;
        float inv = 1.f / sqrtf(var + 1e-5f);
        float sc = gm[o] * inv;
        scale[o] = sc;
        shift[o] = fmaf(-mu, sc, bt[o]);
    }
}

// ---------------------------------------------------------------------------
// Apply BN + ReLU in place; optional transposed fp32 (B,N,C) copy.
// ---------------------------------------------------------------------------
__global__ __launch_bounds__(256) void bnapply_kernel(float* __restrict__ y,
                                                      const float* __restrict__ scale,
                                                      const float* __restrict__ shift,
                                                      int oLog, int relu,
                                                      float* __restrict__ ft) {
    size_t i = (size_t)blockIdx.x * 256 + threadIdx.x;
    int n = (int)(i & (N_ - 1));
    size_t t = i >> 11;
    int o = (int)(t & ((1u << oLog) - 1));
    int b = (int)(t >> oLog);
    float v = fmaf(y[i], scale[o], shift[o]);
    if (relu) v = fmaxf(v, 0.f);
    y[i] = v;
    if (ft) ft[(((size_t)b << 11) + n) * (1u << oLog) + o] = v;
}

// ---------------------------------------------------------------------------
// BN apply + ReLU + transpose, fp32 (B,O,N) -> bf16 (B,N,O). 64x64 LDS tile.
// ---------------------------------------------------------------------------
__global__ __launch_bounds__(256) void bnt_kernel(const float* __restrict__ y,
                                                  const float* __restrict__ scale,
                                                  const float* __restrict__ shift,
                                                  unsigned short* __restrict__ ft, int O) {
    __shared__ float tile[64][65];
    int b = blockIdx.z;
    int n0 = blockIdx.x * 64, o0 = blockIdx.y * 64;
    int t = threadIdx.x;
#pragma unroll
    for (int rr = 0; rr < 16; rr++) {
        int ol = rr * 4 + (t >> 6), nl = t & 63;
        float v = y[((size_t)b * O + o0 + ol) * N_ + n0 + nl];
        v = fmaf(v, scale[o0 + ol], shift[o0 + ol]);
        tile[ol][nl] = fmaxf(v, 0.f);
    }
    __syncthreads();
#pragma unroll
    for (int rr = 0; rr < 2; rr++) {
        int e = t + rr * 256;
        int n = e >> 3, og = (e & 7) * 8;
        unsigned short u[8];
#pragma unroll
        for (int j = 0; j < 8; j++) u[j] = f2bf(tile[og + j][n]);
        uint4 pk;
        pk.x = (unsigned)u[0] | ((unsigned)u[1] << 16);
        pk.y = (unsigned)u[2] | ((unsigned)u[3] << 16);
        pk.z = (unsigned)u[4] | ((unsigned)u[5] << 16);
        pk.w = (unsigned)u[6] | ((unsigned)u[7] << 16);
        *reinterpret_cast<uint4*>(&ft[((size_t)b * N_ + n0 + n) * O + o0 + og]) = pk;
    }
}

// ---------------------------------------------------------------------------
// Squared norms per point from (B,C,N) fp32 (ascending-c fma == GEMM order).
// ---------------------------------------------------------------------------
__global__ __launch_bounds__(256) void norms_kernel(const float* __restrict__ h,
                                                    float* __restrict__ nrm, int C) {
    int b = blockIdx.y;
    int i = blockIdx.x * 256 + threadIdx.x;
    const float* hp = h + (size_t)b * C * N_;
    float s = 0.f;
    for (int c = 0; c < C; c++) {
        float v = hp[(size_t)c * N_ + i];
        s = fmaf(v, v, s);
    }
    nrm[(b << 11) + i] = s;
}

// ---------------------------------------------------------------------------
// Top-16 per row of a (4*2048) x 2048 distance block — wave per row,
// u64-key register extraction (no LDS).
// ---------------------------------------------------------------------------
__global__ __launch_bounds__(256, 4) void topk_kernel(const float* __restrict__ D,
                                                      int* __restrict__ idx) {
    int wave = threadIdx.x >> 6, lane = threadIdx.x & 63;
    int i = blockIdx.x * 4 + wave;  // global row within 4-batch chunk
    const float* dp = D + (size_t)i * N_;

    unsigned long long k[32];
#pragma unroll
    for (int t = 0; t < 8; t++) {
        float4 v = *reinterpret_cast<const float4*>(&dp[t * 256 + lane * 4]);
        int j0 = t * 256 + lane * 4;
        k[t * 4 + 0] = ((unsigned long long)fflip(v.x) << 11) | (unsigned int)(j0 + 0);
        k[t * 4 + 1] = ((unsigned long long)fflip(v.y) << 11) | (unsigned int)(j0 + 1);
        k[t * 4 + 2] = ((unsigned long long)fflip(v.z) << 11) | (unsigned int)(j0 + 2);
        k[t * 4 + 3] = ((unsigned long long)fflip(v.w) << 11) | (unsigned int)(j0 + 3);
    }

    int* op = idx + (size_t)i * KNN;
    for (int r = 0; r < KNN; r++) {
        unsigned long long mk;
        TREE32K(k, mk);
#pragma unroll
        for (int s = 32; s > 0; s >>= 1) {
            unsigned long long ok = shflx64(mk, s);
            if (ok < mk) mk = ok;
        }
        if (lane == 0) op[r] = (int)(mk & 2047u);
#pragma unroll
        for (int t = 0; t < 32; t++)
            if (k[t] == mk) k[t] = ~0ull;
    }
}

// ---------------------------------------------------------------------------
// Gather 16 neighbor fp32 rows (B,N,C), max over k -> fp32 (B,N,C).
// ---------------------------------------------------------------------------
__global__ __launch_bounds__(256) void gathermax_kernel(const float* __restrict__ ft,
                                                        const int* __restrict__ idx,
                                                        float* __restrict__ out, int cLog) {
    int C = 1 << cLog;
    int b = blockIdx.y;
    int nb = (blockIdx.x << (8 - cLog)) + (threadIdx.x >> cLog);
    int c = threadIdx.x & (C - 1);
    const int* ip = idx + (((size_t)b << 11) + nb) * KNN;
    float m = -3.4e38f;
#pragma unroll
    for (int k = 0; k < KNN; k++) {
        int j = ip[k];
        m = fmaxf(m, ft[(((size_t)b << 11) + j) * C + c]);
    }
    out[(((size_t)b << 11) + nb) * C + c] = m;
}

// ---------------------------------------------------------------------------
// Gather-max: fp32 (B,N,128) in -> bf16 (B,N,128) out (feeds g2 MFMA only).
// ---------------------------------------------------------------------------
__global__ __launch_bounds__(256) void gmaxh2_kernel(const float* __restrict__ ft,
                                                     const int* __restrict__ idx,
                                                     unsigned short* __restrict__ out) {
    const int C = 128;
    int b = blockIdx.y;
    int nb = blockIdx.x * 16 + (threadIdx.x >> 4);
    int cc = (threadIdx.x & 15) * 8;
    const int* ip = idx + (((size_t)b << 11) + nb) * KNN;
    float m[8];
#pragma unroll
    for (int q = 0; q < 8; q++) m[q] = -3.4e38f;
#pragma unroll
    for (int k = 0; k < KNN; k++) {
        int j = ip[k];
        const float* p = &ft[(((size_t)b << 11) + j) * C + cc];
        float4 a = *reinterpret_cast<const float4*>(p);
        float4 c2 = *reinterpret_cast<const float4*>(p + 4);
        m[0] = fmaxf(m[0], a.x); m[1] = fmaxf(m[1], a.y);
        m[2] = fmaxf(m[2], a.z); m[3] = fmaxf(m[3], a.w);
        m[4] = fmaxf(m[4], c2.x); m[5] = fmaxf(m[5], c2.y);
        m[6] = fmaxf(m[6], c2.z); m[7] = fmaxf(m[7], c2.w);
    }
    unsigned short u[8];
#pragma unroll
    for (int q = 0; q < 8; q++) u[q] = f2bf(m[q]);
    uint4 pk;
    pk.x = (unsigned)u[0] | ((unsigned)u[1] << 16);
    pk.y = (unsigned)u[2] | ((unsigned)u[3] << 16);
    pk.z = (unsigned)u[4] | ((unsigned)u[5] << 16);
    pk.w = (unsigned)u[6] | ((unsigned)u[7] << 16);
    *reinterpret_cast<uint4*>(&out[(((size_t)b << 11) + nb) * C + cc]) = pk;
}

// ---------------------------------------------------------------------------
// fp32 -> bf16 weight conversion
// ---------------------------------------------------------------------------
__global__ __launch_bounds__(256) void wcvt_kernel(const float* __restrict__ w,
                                                   unsigned short* __restrict__ wh, int count) {
    int i = blockIdx.x * 256 + threadIdx.x;
    if (i < count) wh[i] = f2bf(w[i]);
}

// ---------------------------------------------------------------------------
// Final: out[b,o] = max_n (y4[b,o,n]*scale[o]+shift[o])
// ---------------------------------------------------------------------------
__global__ __launch_bounds__(256) void finalmax_kernel(const float* __restrict__ y,
                                                       const float* __restrict__ scale,
                                                       const float* __restrict__ shift,
                                                       float* __restrict__ out) {
    int o = blockIdx.x, b = blockIdx.y;
    float s = scale[o], t = shift[o];
    const float* yp = y + ((size_t)b * 512 + o) * N_;
    float m = -3.4e38f;
    for (int n = threadIdx.x; n < N_; n += 256) m = fmaxf(m, fmaf(yp[n], s, t));
#pragma unroll
    for (int off = 32; off; off >>= 1) m = fmaxf(m, __shfl_down(m, off, 64));
    __shared__ float red[4];
    int lane = threadIdx.x & 63, w = threadIdx.x >> 6;
    if (lane == 0) red[w] = m;
    __syncthreads();
    if (threadIdx.x == 0)
        out[b * 512 + o] = fmaxf(fmaxf(red[0], red[1]), fmaxf(red[2], red[3]));
}

// ---------------------------------------------------------------------------
extern "C" void kernel_launch(void* const* d_in, const int* in_sizes, int n_in,
                              void* d_out, int out_size, void* d_ws, size_t ws_size,
                              hipStream_t stream) {
    const float* x = (const float*)d_in[0];
    const float* W1 = (const float*)d_in[1];
    const float* b1 = (const float*)d_in[2];
    const float* gm1 = (const float*)d_in[3];
    const float* bt1 = (const float*)d_in[4];
    const float* W2 = (const float*)d_in[5];
    const float* b2 = (const float*)d_in[6];
    const float* gm2 = (const float*)d_in[7];
    const float* bt2 = (const float*)d_in[8];
    const float* W3 = (const float*)d_in[9];
    const float* b3 = (const float*)d_in[10];
    const float* gm3 = (const float*)d_in[11];
    const float* bt3 = (const float*)d_in[12];
    const float* Wg1 = (const float*)d_in[13];
    const float* bg1 = (const float*)d_in[14];
    const float* gmg1 = (const float*)d_in[15];
    const float* btg1 = (const float*)d_in[16];
    const float* Wg2 = (const float*)d_in[17];
    const float* bg2 = (const float*)d_in[18];
    const float* gmg2 = (const float*)d_in[19];
    const float* btg2 = (const float*)d_in[20];
    const float* W4 = (const float*)d_in[21];
    const float* b4 = (const float*)d_in[22];
    const float* gm4 = (const float*)d_in[23];
    const float* bt4 = (const float*)d_in[24];
    float* out = (float*)d_out;

    // ---- workspace arena (byte offsets), total 154,214,400 bytes ----
    if (ws_size < 154214400ull) return;
    char* base = (char*)d_ws;
    float* scale = (float*)(base + 0);
    float* shift = (float*)(base + 4096);
    float* nrm = (float*)(base + 8192);
    int* idx = (int*)(base + 73728);
    unsigned short* Wg2h = (unsigned short*)(base + 1122304);
    unsigned short* W4h = (unsigned short*)(base + 1384448);
    // bufD4: 4-batch distance chunk (67.1 MB) — aliases bufL region, which is
    // only written (g2 conv) AFTER both KNN loops complete.
    float* bufD4 = (float*)(base + 19210240);
    float* bufL = (float*)(base + 19210240);                    // (8,1024,2048) f32
    unsigned short* bufLh = (unsigned short*)(base + 86319104); // (8,2048,1024) bf16
    char* E = base + 119873536;                                 // early region
    float* h0 = (float*)(E + 0);                                // (8,12,2048)
    float* bufA = (float*)(E + 786432);                         // (8,64,2048)
    float* bufB = (float*)(E + 4980736);                        // (8,64,2048)
    float* bufC = (float*)(E + 9175040);                        // (8,2048,64)
    float* bufM1 = (float*)(E + 13369344);                      // (8,128,2048)
    float* bufM2 = (float*)(E + 21757952);                      // (8,2048,128)
    unsigned short* bufM3h = (unsigned short*)(E + 30146560);   // (8,2048,128) bf16
    float* bufY4 = (float*)(E + 0);                             // (8,512,2048) aliases E

    // weight conversion (value-path weights only)
    wcvt_kernel<<<512, 256, 0, stream>>>(Wg2, Wg2h, 1024 * 128);
    wcvt_kernel<<<2048, 256, 0, stream>>>(W4, W4h, 512 * 1024);

    // Stage 0/1: 3D KNN + covariance features
    knn3_kernel<<<dim3(512, 8), 256, 0, stream>>>(x, idx);
    cov_kernel<<<dim3(8, 8), 256, 0, stream>>>(x, idx, h0);

    // conv1: 12 -> 64 (fp32)
    gemm_kernel<0, 0><<<dim3(16, 1, 8), 256, 0, stream>>>(W1, h0, b1, bufA, 64, 12, nullptr, nullptr);
    bnstats_kernel<<<64, 256, 0, stream>>>(bufA, gm1, bt1, scale, shift, 64);
    bnapply_kernel<<<4096, 256, 0, stream>>>(bufA, scale, shift, 6, 1, nullptr);

    // conv2: 64 -> 64 (fp32)
    gemm_kernel<0, 0><<<dim3(16, 1, 8), 256, 0, stream>>>(W2, bufA, b2, bufB, 64, 64, nullptr, nullptr);
    bnstats_kernel<<<64, 256, 0, stream>>>(bufB, gm2, bt2, scale, shift, 64);
    bnapply_kernel<<<4096, 256, 0, stream>>>(bufB, scale, shift, 6, 1, nullptr);

    // conv3: 64 -> 64 (fp32), dual write bufA (B,64,N) + bufC (B,N,64)
    gemm_kernel<0, 0><<<dim3(16, 1, 8), 256, 0, stream>>>(W3, bufB, b3, bufA, 64, 64, nullptr, nullptr);
    bnstats_kernel<<<64, 256, 0, stream>>>(bufA, gm3, bt3, scale, shift, 64);
    bnapply_kernel<<<4096, 256, 0, stream>>>(bufA, scale, shift, 6, 1, bufC);

    // graph layer 1 KNN (C=64, fp32 distances), 4-batch chunks
    norms_kernel<<<dim3(8, 8), 256, 0, stream>>>(bufA, nrm, 64);
    for (int c = 0; c < 2; c++) {
        gemm_kernel<0, 1><<<dim3(16, 16, 4), 256, 0, stream>>>(
            bufC + (size_t)c * 4 * N_ * 64, bufA + (size_t)c * 4 * 64 * N_, nullptr, bufD4,
            2048, 64, nrm + (size_t)c * 4 * N_, nrm + (size_t)c * 4 * N_);
        topk_kernel<<<2048, 256, 0, stream>>>(bufD4, idx + (size_t)c * 4 * N_ * KNN);
    }
    gathermax_kernel<<<dim3(512, 8), 256, 0, stream>>>(bufC, idx, bufB, 6);

    // conv g1: 64 -> 128 (fp32, input (B,N,64))
    gemm_kernel<1, 0><<<dim3(16, 1, 8), 256, 0, stream>>>(Wg1, bufB, bg1, bufM1, 128, 64, nullptr, nullptr);
    bnstats_kernel<<<128, 256, 0, stream>>>(bufM1, gmg1, btg1, scale, shift, 128);
    bnapply_kernel<<<8192, 256, 0, stream>>>(bufM1, scale, shift, 7, 1, bufM2);

    // graph layer 2 KNN (C=128, fp32 distances), 4-batch chunks
    norms_kernel<<<dim3(8, 8), 256, 0, stream>>>(bufM1, nrm, 128);
    for (int c = 0; c < 2; c++) {
        gemm_kernel<0, 1><<<dim3(16, 16, 4), 256, 0, stream>>>(
            bufM2 + (size_t)c * 4 * N_ * 128, bufM1 + (size_t)c * 4 * 128 * N_, nullptr, bufD4,
            2048, 128, nrm + (size_t)c * 4 * N_, nrm + (size_t)c * 4 * N_);
        topk_kernel<<<2048, 256, 0, stream>>>(bufD4, idx + (size_t)c * 4 * N_ * KNN);
    }
    gmaxh2_kernel<<<dim3(128, 8), 256, 0, stream>>>(bufM2, idx, bufM3h);

    // conv g2: 128 -> 1024 (bf16 MFMA, value path)
    mgemm_kernel<<<dim3(16, 8, 8), 256, 0, stream>>>(Wg2h, bufM3h, bg2, bufL, 1024, 128);
    bnstats_kernel<<<1024, 256, 0, stream>>>(bufL, gmg2, btg2, scale, shift, 1024);
    bnt_kernel<<<dim3(32, 16, 8), 256, 0, stream>>>(bufL, scale, shift, bufLh, 1024);

    // conv4: 1024 -> 512 (bf16 MFMA), BN folded into final max
    mgemm_kernel<<<dim3(16, 4, 8), 256, 0, stream>>>(W4h, bufLh, b4, bufY4, 512, 1024);
    bnstats_kernel<<<512, 256, 0, stream>>>(bufY4, gm4, bt4, scale, shift, 512);
    finalmax_kernel<<<dim3(512, 8), 256, 0, stream>>>(bufY4, scale, shift, out);
}

// Round 7
// 801.670 us; speedup vs baseline: 6.1249x; 1.2624x over previous
//
#include <hip/hip_runtime.h>
#include <math.h>

#define B_ 8
#define N_ 2048
#define KNN 16

typedef __attribute__((ext_vector_type(4))) float f32x4;
typedef __attribute__((ext_vector_type(8))) short bf16x8;

__device__ inline unsigned short f2bf(float f) {
    unsigned int x = __float_as_uint(f);
    unsigned int r = (x + 0x7fffu + ((x >> 16) & 1u)) >> 16;  // RNE
    return (unsigned short)r;
}

// Monotone bijection fp32 -> u32 (handles negatives; order-preserving).
__device__ inline unsigned int fflip(float f) {
    unsigned int u = __float_as_uint(f);
    return u ^ (0x80000000u | (unsigned int)((int)u >> 31));
}

// 64-bit shuffle-xor across the 64-lane wave.
__device__ inline unsigned long long shflx64(unsigned long long v, int m) {
    int lo = __shfl_xor((int)(unsigned int)(v & 0xffffffffull), m, 64);
    int hi = __shfl_xor((int)(unsigned int)(v >> 32), m, 64);
    return ((unsigned long long)(unsigned int)hi << 32) | (unsigned int)lo;
}

// Min-tree over 32 register-resident u64 keys (fully unrolled, static idx).
// Key = (flip(d) << 11) | global_idx  ->  plain u64 '<' is exact (d, idx)
// lexicographic order == lax.top_k tie semantics.
#define TREE32K(kk, MK)                                                     \
    {                                                                       \
        unsigned long long tv[16];                                          \
        _Pragma("unroll") for (int p = 0; p < 16; p++)                      \
            tv[p] = kk[2 * p + 1] < kk[2 * p] ? kk[2 * p + 1] : kk[2 * p];  \
        _Pragma("unroll") for (int p = 0; p < 8; p++)                       \
            if (tv[p + 8] < tv[p]) tv[p] = tv[p + 8];                       \
        _Pragma("unroll") for (int p = 0; p < 4; p++)                       \
            if (tv[p + 4] < tv[p]) tv[p] = tv[p + 4];                       \
        _Pragma("unroll") for (int p = 0; p < 2; p++)                       \
            if (tv[p + 2] < tv[p]) tv[p] = tv[p + 2];                       \
        MK = tv[1] < tv[0] ? tv[1] : tv[0];                                 \
    }

// ---------------------------------------------------------------------------
// KNN on 3D input points — wave-per-query, u64-key register extraction.
// ---------------------------------------------------------------------------
__global__ __launch_bounds__(256, 4) void knn3_kernel(const float* __restrict__ x,
                                                      int* __restrict__ idx) {
    __shared__ float px[N_], py[N_], pz[N_];
    int b = blockIdx.y;
    const float* xb = x + (size_t)b * N_ * 3;
    for (int e = threadIdx.x; e < N_; e += 256) {
        px[e] = xb[e * 3 + 0];
        py[e] = xb[e * 3 + 1];
        pz[e] = xb[e * 3 + 2];
    }
    __syncthreads();

    int wave = threadIdx.x >> 6, lane = threadIdx.x & 63;
    int i = blockIdx.x * 4 + wave;
    float qx = px[i], qy = py[i], qz = pz[i];

    unsigned long long k[32];
#pragma unroll
    for (int t = 0; t < 32; t++) {
        int j = lane + t * 64;
        float dx = px[j] - qx, dy = py[j] - qy, dz = pz[j] - qz;
        float d = dx * dx + dy * dy + dz * dz;
        k[t] = ((unsigned long long)fflip(d) << 11) | (unsigned int)j;
    }

    int* op = idx + ((size_t)b * N_ + i) * KNN;
    for (int r = 0; r < KNN; r++) {
        unsigned long long mk;
        TREE32K(k, mk);
#pragma unroll
        for (int s = 32; s > 0; s >>= 1) {
            unsigned long long ok = shflx64(mk, s);
            if (ok < mk) mk = ok;
        }
        if (lane == 0) op[r] = (int)(mk & 2047u);
#pragma unroll
        for (int t = 0; t < 32; t++)
            if (k[t] == mk) k[t] = ~0ull;  // unique key -> kills exactly one
    }
}

// ---------------------------------------------------------------------------
// Covariance features: h0 (B,12,N).
// ---------------------------------------------------------------------------
__global__ __launch_bounds__(256) void cov_kernel(const float* __restrict__ x,
                                                  const int* __restrict__ idx,
                                                  float* __restrict__ h0) {
    int b = blockIdx.y;
    int n = blockIdx.x * 256 + threadIdx.x;
    const int* ip = idx + ((size_t)b * N_ + n) * KNN;

    float px[KNN], py[KNN], pz[KNN];
    float mx = 0.f, my = 0.f, mz = 0.f;
#pragma unroll
    for (int k = 0; k < KNN; k++) {
        int j = ip[k];
        const float* p = x + ((size_t)b * N_ + j) * 3;
        px[k] = p[0]; py[k] = p[1]; pz[k] = p[2];
        mx += px[k]; my += py[k]; mz += pz[k];
    }
    mx *= (1.f / KNN); my *= (1.f / KNN); mz *= (1.f / KNN);

    float c00 = 0, c01 = 0, c02 = 0, c11 = 0, c12 = 0, c22 = 0;
#pragma unroll
    for (int k = 0; k < KNN; k++) {
        float dx = px[k] - mx, dy = py[k] - my, dz = pz[k] - mz;
        c00 += dx * dx; c01 += dx * dy; c02 += dx * dz;
        c11 += dy * dy; c12 += dy * dz; c22 += dz * dz;
    }
    float* hb = h0 + (size_t)b * 12 * N_;
    const float* xp = x + ((size_t)b * N_ + n) * 3;
    hb[0 * N_ + n] = xp[0];
    hb[1 * N_ + n] = xp[1];
    hb[2 * N_ + n] = xp[2];
    hb[3 * N_ + n] = c00; hb[4 * N_ + n] = c01; hb[5 * N_ + n] = c02;
    hb[6 * N_ + n] = c01; hb[7 * N_ + n] = c11; hb[8 * N_ + n] = c12;
    hb[9 * N_ + n] = c02; hb[10 * N_ + n] = c12; hb[11 * N_ + n] = c22;
}

// ---------------------------------------------------------------------------
// Old fp32 GEMM (kept only for conv1: C=12 needs bounds checks).
// Y[b,o,n] = sum_c A[o,c]*X[b,c,n] + bias[o]
// ---------------------------------------------------------------------------
__global__ __launch_bounds__(256) void gemm_kernel(const float* __restrict__ A,
                                                   const float* __restrict__ X,
                                                   const float* __restrict__ bias,
                                                   float* __restrict__ Y,
                                                   int O, int C) {
    __shared__ float Wt[16][132];
    __shared__ float Xt[16][132];
    const int N = N_;
    int b = blockIdx.z;
    int oB = blockIdx.y * 128, nB = blockIdx.x * 128;
    const float* Xb = X + (size_t)b * C * N;
    int tid = threadIdx.x;
    int tn = tid & 15, to = tid >> 4;

    float acc[8][8];
#pragma unroll
    for (int i = 0; i < 8; i++)
#pragma unroll
        for (int j = 0; j < 8; j++) acc[i][j] = 0.f;

    for (int c0 = 0; c0 < C; c0 += 16) {
#pragma unroll
        for (int r = 0; r < 8; r++) {
            int e = tid + r * 256;
            int k = e & 15, o = e >> 4;
            float v = 0.f;
            if (c0 + k < C && oB + o < O) v = A[(size_t)(oB + o) * C + c0 + k];
            Wt[k][o] = v;
        }
#pragma unroll
        for (int r = 0; r < 8; r++) {
            int e = tid + r * 256;
            int n = e & 127, k = e >> 7;
            float v = 0.f;
            if (c0 + k < C) v = Xb[(size_t)(c0 + k) * N + nB + n];
            Xt[k][n] = v;
        }
        __syncthreads();
#pragma unroll
        for (int k = 0; k < 16; k++) {
            float a[8], xv[8];
#pragma unroll
            for (int i = 0; i < 8; i++) a[i] = Wt[k][to * 8 + i];
#pragma unroll
            for (int m = 0; m < 4; m++) {
                xv[2 * m] = Xt[k][tn * 2 + 32 * m];
                xv[2 * m + 1] = Xt[k][tn * 2 + 32 * m + 1];
            }
#pragma unroll
            for (int i = 0; i < 8; i++)
#pragma unroll
                for (int j = 0; j < 8; j++) acc[i][j] = fmaf(a[i], xv[j], acc[i][j]);
        }
        __syncthreads();
    }

#pragma unroll
    for (int i = 0; i < 8; i++) {
        int o = oB + to * 8 + i;
        if (o >= O) continue;
        float bv = bias[o];
#pragma unroll
        for (int m = 0; m < 4; m++) {
            int n0 = nB + tn * 2 + 32 * m;
            float2 st = make_float2(acc[i][2 * m] + bv, acc[i][2 * m + 1] + bv);
            *reinterpret_cast<float2*>(&Y[((size_t)b * O + o) * N + n0]) = st;
        }
    }
}

// ---------------------------------------------------------------------------
// Symmetric distance GEMM v2. Per batch (z): D[o,n] = nrm[o]+nrm[n]-2*F·F
// computed only for upper-triangle 128x128 tiles; off-diagonal tiles are
// mirrored via LDS transpose (bitwise-identical values since
// fmaf(a,b,s)==fmaf(b,a,s) and accumulation order is ascending c both ways).
// F: (z,N,C) row-major features; X: (z,C,N) same values transposed. C%32==0.
// ---------------------------------------------------------------------------
__global__ __launch_bounds__(256, 4) void dgemm_kernel(const float* __restrict__ F,
                                                       const float* __restrict__ X,
                                                       const float* __restrict__ nrm,
                                                       float* __restrict__ D,
                                                       int C) {
    __shared__ float Wt[32][132];
    __shared__ float Xt[32][132];
    int bz = blockIdx.z;
    int t = blockIdx.x;
    int bx = (int)((sqrtf(8.f * (float)t + 1.f) - 1.f) * 0.5f);
    while ((bx + 1) * (bx + 2) / 2 <= t) bx++;
    while (bx * (bx + 1) / 2 > t) bx--;
    int by = t - bx * (bx + 1) / 2;  // by <= bx
    int oB = by * 128, nB = bx * 128;
    const float* Fb = F + (size_t)bz * N_ * C;
    const float* Xb = X + (size_t)bz * C * N_;
    const float* nb = nrm + (size_t)bz * N_;
    float* Db = D + (size_t)bz * N_ * N_;
    int tid = threadIdx.x;
    int tn = tid & 15, to = tid >> 4;

    float acc[8][8];
#pragma unroll
    for (int i = 0; i < 8; i++)
#pragma unroll
        for (int j = 0; j < 8; j++) acc[i][j] = 0.f;

    for (int c0 = 0; c0 < C; c0 += 32) {
        // stage A rows (oB..oB+127) transposed -> Wt[k][row]
#pragma unroll
        for (int r = 0; r < 4; r++) {
            int e = tid + r * 256;
            int row = e >> 3, c4 = e & 7;
            float4 v = *reinterpret_cast<const float4*>(&Fb[(size_t)(oB + row) * C + c0 + c4 * 4]);
            Wt[c4 * 4 + 0][row] = v.x;
            Wt[c4 * 4 + 1][row] = v.y;
            Wt[c4 * 4 + 2][row] = v.z;
            Wt[c4 * 4 + 3][row] = v.w;
        }
        // stage X cols (nB..nB+127) -> Xt[k][n]
#pragma unroll
        for (int r = 0; r < 4; r++) {
            int e = tid + r * 256;
            int k = e >> 5, n4 = e & 31;
            float4 v = *reinterpret_cast<const float4*>(&Xb[(size_t)(c0 + k) * N_ + nB + n4 * 4]);
            *reinterpret_cast<float4*>(&Xt[k][n4 * 4]) = v;
        }
        __syncthreads();
#pragma unroll
        for (int k = 0; k < 32; k++) {
            float a[8], xv[8];
            *reinterpret_cast<float4*>(&a[0]) = *reinterpret_cast<const float4*>(&Wt[k][to * 8]);
            *reinterpret_cast<float4*>(&a[4]) = *reinterpret_cast<const float4*>(&Wt[k][to * 8 + 4]);
#pragma unroll
            for (int m = 0; m < 4; m++) {
                float2 x2 = *reinterpret_cast<const float2*>(&Xt[k][tn * 2 + 32 * m]);
                xv[2 * m] = x2.x;
                xv[2 * m + 1] = x2.y;
            }
#pragma unroll
            for (int i = 0; i < 8; i++)
#pragma unroll
                for (int j = 0; j < 8; j++) acc[i][j] = fmaf(a[i], xv[j], acc[i][j]);
        }
        __syncthreads();
    }

    // normal write (rows oB.., cols nB..); keep D values in acc for mirror
#pragma unroll
    for (int i = 0; i < 8; i++) {
        int o = oB + to * 8 + i;
        float nr = nb[o];
#pragma unroll
        for (int m = 0; m < 4; m++) {
            int n0 = nB + tn * 2 + 32 * m;
            float v0 = nr + nb[n0] - 2.f * acc[i][2 * m];
            float v1 = nr + nb[n0 + 1] - 2.f * acc[i][2 * m + 1];
            *reinterpret_cast<float2*>(&Db[(size_t)o * N_ + n0]) = make_float2(v0, v1);
            acc[i][2 * m] = v0;
            acc[i][2 * m + 1] = v1;
        }
    }

    // mirror write for off-diagonal tiles: D[nB+j][oB+i] = D[oB+i][nB+j]
    if (bx != by) {
        for (int p = 0; p < 4; p++) {  // 4 chunks of 32 rows
            __syncthreads();
            if ((to >> 2) == p) {
                int rl = (to & 3) * 8;
#pragma unroll
                for (int i = 0; i < 8; i++)
#pragma unroll
                    for (int m = 0; m < 4; m++) {
                        Xt[rl + i][tn * 2 + 32 * m] = acc[i][2 * m];
                        Xt[rl + i][tn * 2 + 32 * m + 1] = acc[i][2 * m + 1];
                    }
            }
            __syncthreads();
#pragma unroll
            for (int r = 0; r < 4; r++) {
                int e = tid + r * 256;
                int j = e >> 3, i4 = e & 7;
                float4 v;
                v.x = Xt[i4 * 4 + 0][j];
                v.y = Xt[i4 * 4 + 1][j];
                v.z = Xt[i4 * 4 + 2][j];
                v.w = Xt[i4 * 4 + 3][j];
                *reinterpret_cast<float4*>(&Db[(size_t)(nB + j) * N_ + oB + p * 32 + i4 * 4]) = v;
            }
        }
    }
}

// ---------------------------------------------------------------------------
// Conv fp32 GEMM v2: 64x64 tile, BK=32, C%32==0, O%64==0.
// Y[b,o,n] = sum_c A[o,c]*X[...] + bias[o]
// XLAYOUT 0: X[(b*C+c)*N+n]   XLAYOUT 1: X[(b*N+n)*C+c]
// ---------------------------------------------------------------------------
template <int XLAYOUT>
__global__ __launch_bounds__(256, 4) void cgemm_kernel(const float* __restrict__ A,
                                                       const float* __restrict__ X,
                                                       const float* __restrict__ bias,
                                                       float* __restrict__ Y,
                                                       int O, int C) {
    __shared__ float Wt[32][68];
    __shared__ float Xt[32][68];
    int b = blockIdx.z;
    int oB = blockIdx.y * 64, nB = blockIdx.x * 64;
    const float* Xb = X + (XLAYOUT == 0 ? (size_t)b * C * N_ : (size_t)b * N_ * C);
    int tid = threadIdx.x;
    int tn = tid & 15, to = tid >> 4;

    float acc[4][4];
#pragma unroll
    for (int i = 0; i < 4; i++)
#pragma unroll
        for (int j = 0; j < 4; j++) acc[i][j] = 0.f;

    for (int c0 = 0; c0 < C; c0 += 32) {
#pragma unroll
        for (int r = 0; r < 2; r++) {
            int e = tid + r * 256;
            int row = e >> 3, c4 = e & 7;
            float4 v = *reinterpret_cast<const float4*>(&A[(size_t)(oB + row) * C + c0 + c4 * 4]);
            Wt[c4 * 4 + 0][row] = v.x;
            Wt[c4 * 4 + 1][row] = v.y;
            Wt[c4 * 4 + 2][row] = v.z;
            Wt[c4 * 4 + 3][row] = v.w;
        }
        if (XLAYOUT == 0) {
#pragma unroll
            for (int r = 0; r < 2; r++) {
                int e = tid + r * 256;
                int k = e >> 4, n4 = e & 15;
                float4 v = *reinterpret_cast<const float4*>(&Xb[(size_t)(c0 + k) * N_ + nB + n4 * 4]);
                *reinterpret_cast<float4*>(&Xt[k][n4 * 4]) = v;
            }
        } else {
#pragma unroll
            for (int r = 0; r < 2; r++) {
                int e = tid + r * 256;
                int n = e >> 3, c4 = e & 7;
                float4 v = *reinterpret_cast<const float4*>(&Xb[(size_t)(nB + n) * C + c0 + c4 * 4]);
                Xt[c4 * 4 + 0][n] = v.x;
                Xt[c4 * 4 + 1][n] = v.y;
                Xt[c4 * 4 + 2][n] = v.z;
                Xt[c4 * 4 + 3][n] = v.w;
            }
        }
        __syncthreads();
#pragma unroll
        for (int k = 0; k < 32; k++) {
            float a[4], xv[4];
            *reinterpret_cast<float4*>(&a[0]) = *reinterpret_cast<const float4*>(&Wt[k][to * 4]);
            float2 x0 = *reinterpret_cast<const float2*>(&Xt[k][tn * 2]);
            float2 x1 = *reinterpret_cast<const float2*>(&Xt[k][tn * 2 + 32]);
            xv[0] = x0.x; xv[1] = x0.y; xv[2] = x1.x; xv[3] = x1.y;
#pragma unroll
            for (int i = 0; i < 4; i++)
#pragma unroll
                for (int j = 0; j < 4; j++) acc[i][j] = fmaf(a[i], xv[j], acc[i][j]);
        }
        __syncthreads();
    }

#pragma unroll
    for (int i = 0; i < 4; i++) {
        int o = oB + to * 4 + i;
        float bv = bias[o];
#pragma unroll
        for (int m = 0; m < 2; m++) {
            int n0 = nB + tn * 2 + 32 * m;
            float2 st = make_float2(acc[i][2 * m] + bv, acc[i][2 * m + 1] + bv);
            *reinterpret_cast<float2*>(&Y[((size_t)b * O + o) * N_ + n0]) = st;
        }
    }
}

// ---------------------------------------------------------------------------
// bf16 MFMA GEMM (value path only: g2 conv, conv4).
// ---------------------------------------------------------------------------
__global__ __launch_bounds__(256) void mgemm_kernel(const unsigned short* __restrict__ A,
                                                    const unsigned short* __restrict__ X,
                                                    const float* __restrict__ bias,
                                                    float* __restrict__ Y,
                                                    int O, int C) {
    __shared__ unsigned short At[128][72];
    __shared__ unsigned short Bt[128][72];
    int b = blockIdx.z;
    int oB = blockIdx.y * 128, nB = blockIdx.x * 128;
    const unsigned short* Xb = X + (size_t)b * N_ * C;
    int tid = threadIdx.x;
    int lane = tid & 63, w = tid >> 6;
    int wm = w & 1, wn = w >> 1;
    int lr = lane & 15, lg = lane >> 4;

    f32x4 acc[4][4];
#pragma unroll
    for (int m = 0; m < 4; m++)
#pragma unroll
        for (int n = 0; n < 4; n++) acc[m][n] = (f32x4){0.f, 0.f, 0.f, 0.f};

    for (int c0 = 0; c0 < C; c0 += 64) {
#pragma unroll
        for (int r = 0; r < 4; r++) {
            int t = tid + r * 256;
            int row = t >> 3, c8 = (t & 7) * 8;
            float4 va = *reinterpret_cast<const float4*>(&A[(size_t)(oB + row) * C + c0 + c8]);
            *reinterpret_cast<float4*>(&At[row][c8]) = va;
            float4 vb = *reinterpret_cast<const float4*>(&Xb[(size_t)(nB + row) * C + c0 + c8]);
            *reinterpret_cast<float4*>(&Bt[row][c8]) = vb;
        }
        __syncthreads();
#pragma unroll
        for (int kk = 0; kk < 2; kk++) {
            bf16x8 af[4], bfv[4];
#pragma unroll
            for (int m = 0; m < 4; m++)
                af[m] = *reinterpret_cast<const bf16x8*>(&At[wm * 64 + m * 16 + lr][kk * 32 + lg * 8]);
#pragma unroll
            for (int n = 0; n < 4; n++)
                bfv[n] = *reinterpret_cast<const bf16x8*>(&Bt[wn * 64 + n * 16 + lr][kk * 32 + lg * 8]);
#pragma unroll
            for (int m = 0; m < 4; m++)
#pragma unroll
                for (int n = 0; n < 4; n++)
                    acc[m][n] = __builtin_amdgcn_mfma_f32_16x16x32_bf16(af[m], bfv[n], acc[m][n], 0, 0, 0);
        }
        __syncthreads();
    }

#pragma unroll
    for (int m = 0; m < 4; m++) {
#pragma unroll
        for (int r = 0; r < 4; r++) {
            int o = oB + wm * 64 + m * 16 + lg * 4 + r;
            float bv = bias[o];
#pragma unroll
            for (int n = 0; n < 4; n++) {
                int nv = nB + wn * 64 + n * 16 + lr;
                Y[((size_t)b * O + o) * N_ + nv] = acc[m][n][r] + bv;
            }
        }
    }
}

// ---------------------------------------------------------------------------
// Per-channel BN stats over (B,N)
// ---------------------------------------------------------------------------
__global__ __launch_bounds__(256) void bnstats_kernel(const float* __restrict__ y,
                                                      const float* __restrict__ gm,
                                                      const float* __restrict__ bt,
                                                      float* __restrict__ scale,
                                                      float* __restrict__ shift, int O) {
    int o = blockIdx.x;
    float s = 0.f, s2 = 0.f;
    for (int e = threadIdx.x; e < B_ * N_; e += 256) {
        int b = e >> 11, n = e & (N_ - 1);
        float v = y[((size_t)b * O + o) * N_ + n];
        s += v;
        s2 = fmaf(v, v, s2);
    }
#pragma unroll
    for (int off = 32; off; off >>= 1) {
        s += __shfl_down(s, off, 64);
        s2 += __shfl_down(s2, off, 64);
    }
    __shared__ float red[8];
    int lane = threadIdx.x & 63, w = threadIdx.x >> 6;
    if (lane == 0) { red[w] = s; red[4 + w] = s2; }
    __syncthreads();
    if (threadIdx.x == 0) {
        s = red[0] + red[1] + red[2] + red[3];
        s2 = red[4] + red[5] + red[6] + red[7];
        float mu = s * (1.f / (B_ * N_));
        float var = s2 * (1.f / (B_ * N_)) - mu * mu;
        float inv = 1.f / sqrtf(var + 1e-5f);
        float sc = gm[o] * inv;
        scale[o] = sc;
        shift[o] = fmaf(-mu, sc, bt[o]);
    }
}

// ---------------------------------------------------------------------------
// Apply BN + ReLU in place; optional transposed fp32 (B,N,C) copy.
// ---------------------------------------------------------------------------
__global__ __launch_bounds__(256) void bnapply_kernel(float* __restrict__ y,
                                                      const float* __restrict__ scale,
                                                      const float* __restrict__ shift,
                                                      int oLog, int relu,
                                                      float* __restrict__ ft) {
    size_t i = (size_t)blockIdx.x * 256 + threadIdx.x;
    int n = (int)(i & (N_ - 1));
    size_t t = i >> 11;
    int o = (int)(t & ((1u << oLog) - 1));
    int b = (int)(t >> oLog);
    float v = fmaf(y[i], scale[o], shift[o]);
    if (relu) v = fmaxf(v, 0.f);
    y[i] = v;
    if (ft) ft[(((size_t)b << 11) + n) * (1u << oLog) + o] = v;
}

// ---------------------------------------------------------------------------
// BN apply + ReLU + transpose, fp32 (B,O,N) -> bf16 (B,N,O). 64x64 LDS tile.
// ---------------------------------------------------------------------------
__global__ __launch_bounds__(256) void bnt_kernel(const float* __restrict__ y,
                                                  const float* __restrict__ scale,
                                                  const float* __restrict__ shift,
                                                  unsigned short* __restrict__ ft, int O) {
    __shared__ float tile[64][65];
    int b = blockIdx.z;
    int n0 = blockIdx.x * 64, o0 = blockIdx.y * 64;
    int t = threadIdx.x;
#pragma unroll
    for (int rr = 0; rr < 16; rr++) {
        int ol = rr * 4 + (t >> 6), nl = t & 63;
        float v = y[((size_t)b * O + o0 + ol) * N_ + n0 + nl];
        v = fmaf(v, scale[o0 + ol], shift[o0 + ol]);
        tile[ol][nl] = fmaxf(v, 0.f);
    }
    __syncthreads();
#pragma unroll
    for (int rr = 0; rr < 2; rr++) {
        int e = t + rr * 256;
        int n = e >> 3, og = (e & 7) * 8;
        unsigned short u[8];
#pragma unroll
        for (int j = 0; j < 8; j++) u[j] = f2bf(tile[og + j][n]);
        uint4 pk;
        pk.x = (unsigned)u[0] | ((unsigned)u[1] << 16);
        pk.y = (unsigned)u[2] | ((unsigned)u[3] << 16);
        pk.z = (unsigned)u[4] | ((unsigned)u[5] << 16);
        pk.w = (unsigned)u[6] | ((unsigned)u[7] << 16);
        *reinterpret_cast<uint4*>(&ft[((size_t)b * N_ + n0 + n) * O + o0 + og]) = pk;
    }
}

// ---------------------------------------------------------------------------
// Squared norms per point from (B,C,N) fp32 (ascending-c fma == GEMM order).
// ---------------------------------------------------------------------------
__global__ __launch_bounds__(256) void norms_kernel(const float* __restrict__ h,
                                                    float* __restrict__ nrm, int C) {
    int b = blockIdx.y;
    int i = blockIdx.x * 256 + threadIdx.x;
    const float* hp = h + (size_t)b * C * N_;
    float s = 0.f;
    for (int c = 0; c < C; c++) {
        float v = hp[(size_t)c * N_ + i];
        s = fmaf(v, v, s);
    }
    nrm[(b << 11) + i] = s;
}

// ---------------------------------------------------------------------------
// Top-16 per row of a (4*2048) x 2048 distance block — wave per row,
// u64-key register extraction (no LDS).
// ---------------------------------------------------------------------------
__global__ __launch_bounds__(256, 4) void topk_kernel(const float* __restrict__ D,
                                                      int* __restrict__ idx) {
    int wave = threadIdx.x >> 6, lane = threadIdx.x & 63;
    int i = blockIdx.x * 4 + wave;  // global row within 4-batch chunk
    const float* dp = D + (size_t)i * N_;

    unsigned long long k[32];
#pragma unroll
    for (int t = 0; t < 8; t++) {
        float4 v = *reinterpret_cast<const float4*>(&dp[t * 256 + lane * 4]);
        int j0 = t * 256 + lane * 4;
        k[t * 4 + 0] = ((unsigned long long)fflip(v.x) << 11) | (unsigned int)(j0 + 0);
        k[t * 4 + 1] = ((unsigned long long)fflip(v.y) << 11) | (unsigned int)(j0 + 1);
        k[t * 4 + 2] = ((unsigned long long)fflip(v.z) << 11) | (unsigned int)(j0 + 2);
        k[t * 4 + 3] = ((unsigned long long)fflip(v.w) << 11) | (unsigned int)(j0 + 3);
    }

    int* op = idx + (size_t)i * KNN;
    for (int r = 0; r < KNN; r++) {
        unsigned long long mk;
        TREE32K(k, mk);
#pragma unroll
        for (int s = 32; s > 0; s >>= 1) {
            unsigned long long ok = shflx64(mk, s);
            if (ok < mk) mk = ok;
        }
        if (lane == 0) op[r] = (int)(mk & 2047u);
#pragma unroll
        for (int t = 0; t < 32; t++)
            if (k[t] == mk) k[t] = ~0ull;
    }
}

// ---------------------------------------------------------------------------
// Gather 16 neighbor fp32 rows (B,N,C), max over k -> fp32 (B,N,C).
// ---------------------------------------------------------------------------
__global__ __launch_bounds__(256) void gathermax_kernel(const float* __restrict__ ft,
                                                        const int* __restrict__ idx,
                                                        float* __restrict__ out, int cLog) {
    int C = 1 << cLog;
    int b = blockIdx.y;
    int nb = (blockIdx.x << (8 - cLog)) + (threadIdx.x >> cLog);
    int c = threadIdx.x & (C - 1);
    const int* ip = idx + (((size_t)b << 11) + nb) * KNN;
    float m = -3.4e38f;
#pragma unroll
    for (int k = 0; k < KNN; k++) {
        int j = ip[k];
        m = fmaxf(m, ft[(((size_t)b << 11) + j) * C + c]);
    }
    out[(((size_t)b << 11) + nb) * C + c] = m;
}

// ---------------------------------------------------------------------------
// Gather-max: fp32 (B,N,128) in -> bf16 (B,N,128) out (feeds g2 MFMA only).
// ---------------------------------------------------------------------------
__global__ __launch_bounds__(256) void gmaxh2_kernel(const float* __restrict__ ft,
                                                     const int* __restrict__ idx,
                                                     unsigned short* __restrict__ out) {
    const int C = 128;
    int b = blockIdx.y;
    int nb = blockIdx.x * 16 + (threadIdx.x >> 4);
    int cc = (threadIdx.x & 15) * 8;
    const int* ip = idx + (((size_t)b << 11) + nb) * KNN;
    float m[8];
#pragma unroll
    for (int q = 0; q < 8; q++) m[q] = -3.4e38f;
#pragma unroll
    for (int k = 0; k < KNN; k++) {
        int j = ip[k];
        const float* p = &ft[(((size_t)b << 11) + j) * C + cc];
        float4 a = *reinterpret_cast<const float4*>(p);
        float4 c2 = *reinterpret_cast<const float4*>(p + 4);
        m[0] = fmaxf(m[0], a.x); m[1] = fmaxf(m[1], a.y);
        m[2] = fmaxf(m[2], a.z); m[3] = fmaxf(m[3], a.w);
        m[4] = fmaxf(m[4], c2.x); m[5] = fmaxf(m[5], c2.y);
        m[6] = fmaxf(m[6], c2.z); m[7] = fmaxf(m[7], c2.w);
    }
    unsigned short u[8];
#pragma unroll
    for (int q = 0; q < 8; q++) u[q] = f2bf(m[q]);
    uint4 pk;
    pk.x = (unsigned)u[0] | ((unsigned)u[1] << 16);
    pk.y = (unsigned)u[2] | ((unsigned)u[3] << 16);
    pk.z = (unsigned)u[4] | ((unsigned)u[5] << 16);
    pk.w = (unsigned)u[6] | ((unsigned)u[7] << 16);
    *reinterpret_cast<uint4*>(&out[(((size_t)b << 11) + nb) * C + cc]) = pk;
}

// ---------------------------------------------------------------------------
// fp32 -> bf16 weight conversion
// ---------------------------------------------------------------------------
__global__ __launch_bounds__(256) void wcvt_kernel(const float* __restrict__ w,
                                                   unsigned short* __restrict__ wh, int count) {
    int i = blockIdx.x * 256 + threadIdx.x;
    if (i < count) wh[i] = f2bf(w[i]);
}

// ---------------------------------------------------------------------------
// Final: out[b,o] = max_n (y4[b,o,n]*scale[o]+shift[o])
// ---------------------------------------------------------------------------
__global__ __launch_bounds__(256) void finalmax_kernel(const float* __restrict__ y,
                                                       const float* __restrict__ scale,
                                                       const float* __restrict__ shift,
                                                       float* __restrict__ out) {
    int o = blockIdx.x, b = blockIdx.y;
    float s = scale[o], t = shift[o];
    const float* yp = y + ((size_t)b * 512 + o) * N_;
    float m = -3.4e38f;
    for (int n = threadIdx.x; n < N_; n += 256) m = fmaxf(m, fmaf(yp[n], s, t));
#pragma unroll
    for (int off = 32; off; off >>= 1) m = fmaxf(m, __shfl_down(m, off, 64));
    __shared__ float red[4];
    int lane = threadIdx.x & 63, w = threadIdx.x >> 6;
    if (lane == 0) red[w] = m;
    __syncthreads();
    if (threadIdx.x == 0)
        out[b * 512 + o] = fmaxf(fmaxf(red[0], red[1]), fmaxf(red[2], red[3]));
}

// ---------------------------------------------------------------------------
extern "C" void kernel_launch(void* const* d_in, const int* in_sizes, int n_in,
                              void* d_out, int out_size, void* d_ws, size_t ws_size,
                              hipStream_t stream) {
    const float* x = (const float*)d_in[0];
    const float* W1 = (const float*)d_in[1];
    const float* b1 = (const float*)d_in[2];
    const float* gm1 = (const float*)d_in[3];
    const float* bt1 = (const float*)d_in[4];
    const float* W2 = (const float*)d_in[5];
    const float* b2 = (const float*)d_in[6];
    const float* gm2 = (const float*)d_in[7];
    const float* bt2 = (const float*)d_in[8];
    const float* W3 = (const float*)d_in[9];
    const float* b3 = (const float*)d_in[10];
    const float* gm3 = (const float*)d_in[11];
    const float* bt3 = (const float*)d_in[12];
    const float* Wg1 = (const float*)d_in[13];
    const float* bg1 = (const float*)d_in[14];
    const float* gmg1 = (const float*)d_in[15];
    const float* btg1 = (const float*)d_in[16];
    const float* Wg2 = (const float*)d_in[17];
    const float* bg2 = (const float*)d_in[18];
    const float* gmg2 = (const float*)d_in[19];
    const float* btg2 = (const float*)d_in[20];
    const float* W4 = (const float*)d_in[21];
    const float* b4 = (const float*)d_in[22];
    const float* gm4 = (const float*)d_in[23];
    const float* bt4 = (const float*)d_in[24];
    float* out = (float*)d_out;

    // ---- workspace arena (byte offsets), total 154,214,400 bytes ----
    if (ws_size < 154214400ull) return;
    char* base = (char*)d_ws;
    float* scale = (float*)(base + 0);
    float* shift = (float*)(base + 4096);
    float* nrm = (float*)(base + 8192);
    int* idx = (int*)(base + 73728);
    unsigned short* Wg2h = (unsigned short*)(base + 1122304);
    unsigned short* W4h = (unsigned short*)(base + 1384448);
    // bufD4: 4-batch distance chunk (67.1 MB) — aliases bufL region, which is
    // only written (g2 conv) AFTER both KNN loops complete.
    float* bufD4 = (float*)(base + 19210240);
    float* bufL = (float*)(base + 19210240);                    // (8,1024,2048) f32
    unsigned short* bufLh = (unsigned short*)(base + 86319104); // (8,2048,1024) bf16
    char* E = base + 119873536;                                 // early region
    float* h0 = (float*)(E + 0);                                // (8,12,2048)
    float* bufA = (float*)(E + 786432);                         // (8,64,2048)
    float* bufB = (float*)(E + 4980736);                        // (8,64,2048)
    float* bufC = (float*)(E + 9175040);                        // (8,2048,64)
    float* bufM1 = (float*)(E + 13369344);                      // (8,128,2048)
    float* bufM2 = (float*)(E + 21757952);                      // (8,2048,128)
    unsigned short* bufM3h = (unsigned short*)(E + 30146560);   // (8,2048,128) bf16
    float* bufY4 = (float*)(E + 0);                             // (8,512,2048) aliases E

    // weight conversion (value-path weights only)
    wcvt_kernel<<<512, 256, 0, stream>>>(Wg2, Wg2h, 1024 * 128);
    wcvt_kernel<<<2048, 256, 0, stream>>>(W4, W4h, 512 * 1024);

    // Stage 0/1: 3D KNN + covariance features
    knn3_kernel<<<dim3(512, 8), 256, 0, stream>>>(x, idx);
    cov_kernel<<<dim3(8, 8), 256, 0, stream>>>(x, idx, h0);

    // conv1: 12 -> 64 (fp32, old path: C=12)
    gemm_kernel<<<dim3(16, 1, 8), 256, 0, stream>>>(W1, h0, b1, bufA, 64, 12);
    bnstats_kernel<<<64, 256, 0, stream>>>(bufA, gm1, bt1, scale, shift, 64);
    bnapply_kernel<<<4096, 256, 0, stream>>>(bufA, scale, shift, 6, 1, nullptr);

    // conv2: 64 -> 64 (fp32 v2)
    cgemm_kernel<0><<<dim3(32, 1, 8), 256, 0, stream>>>(W2, bufA, b2, bufB, 64, 64);
    bnstats_kernel<<<64, 256, 0, stream>>>(bufB, gm2, bt2, scale, shift, 64);
    bnapply_kernel<<<4096, 256, 0, stream>>>(bufB, scale, shift, 6, 1, nullptr);

    // conv3: 64 -> 64 (fp32 v2), dual write bufA (B,64,N) + bufC (B,N,64)
    cgemm_kernel<0><<<dim3(32, 1, 8), 256, 0, stream>>>(W3, bufB, b3, bufA, 64, 64);
    bnstats_kernel<<<64, 256, 0, stream>>>(bufA, gm3, bt3, scale, shift, 64);
    bnapply_kernel<<<4096, 256, 0, stream>>>(bufA, scale, shift, 6, 1, bufC);

    // graph layer 1 KNN (C=64, symmetric fp32 distances), 4-batch chunks
    norms_kernel<<<dim3(8, 8), 256, 0, stream>>>(bufA, nrm, 64);
    for (int c = 0; c < 2; c++) {
        dgemm_kernel<<<dim3(136, 1, 4), 256, 0, stream>>>(
            bufC + (size_t)c * 4 * N_ * 64, bufA + (size_t)c * 4 * 64 * N_,
            nrm + (size_t)c * 4 * N_, bufD4, 64);
        topk_kernel<<<2048, 256, 0, stream>>>(bufD4, idx + (size_t)c * 4 * N_ * KNN);
    }
    gathermax_kernel<<<dim3(512, 8), 256, 0, stream>>>(bufC, idx, bufB, 6);

    // conv g1: 64 -> 128 (fp32 v2, input (B,N,64))
    cgemm_kernel<1><<<dim3(32, 2, 8), 256, 0, stream>>>(Wg1, bufB, bg1, bufM1, 128, 64);
    bnstats_kernel<<<128, 256, 0, stream>>>(bufM1, gmg1, btg1, scale, shift, 128);
    bnapply_kernel<<<8192, 256, 0, stream>>>(bufM1, scale, shift, 7, 1, bufM2);

    // graph layer 2 KNN (C=128, symmetric fp32 distances), 4-batch chunks
    norms_kernel<<<dim3(8, 8), 256, 0, stream>>>(bufM1, nrm, 128);
    for (int c = 0; c < 2; c++) {
        dgemm_kernel<<<dim3(136, 1, 4), 256, 0, stream>>>(
            bufM2 + (size_t)c * 4 * N_ * 128, bufM1 + (size_t)c * 4 * 128 * N_,
            nrm + (size_t)c * 4 * N_, bufD4, 128);
        topk_kernel<<<2048, 256, 0, stream>>>(bufD4, idx + (size_t)c * 4 * N_ * KNN);
    }
    gmaxh2_kernel<<<dim3(128, 8), 256, 0, stream>>>(bufM2, idx, bufM3h);

    // conv g2: 128 -> 1024 (bf16 MFMA, value path)
    mgemm_kernel<<<dim3(16, 8, 8), 256, 0, stream>>>(Wg2h, bufM3h, bg2, bufL, 1024, 128);
    bnstats_kernel<<<1024, 256, 0, stream>>>(bufL, gmg2, btg2, scale, shift, 1024);
    bnt_kernel<<<dim3(32, 16, 8), 256, 0, stream>>>(bufL, scale, shift, bufLh, 1024);

    // conv4: 1024 -> 512 (bf16 MFMA), BN folded into final max
    mgemm_kernel<<<dim3(16, 4, 8), 256, 0, stream>>>(W4h, bufLh, b4, bufY4, 512, 1024);
    bnstats_kernel<<<512, 256, 0, stream>>>(bufY4, gm4, bt4, scale, shift, 512);
    finalmax_kernel<<<dim3(512, 8), 256, 0, stream>>>(bufY4, scale, shift, out);
}

// Round 8
// 667.675 us; speedup vs baseline: 7.3541x; 1.2007x over previous
//
#include <hip/hip_runtime.h>
#include <math.h>

#define B_ 8
#define N_ 2048
#define KNN 16

typedef __attribute__((ext_vector_type(4))) float f32x4;
typedef __attribute__((ext_vector_type(8))) short bf16x8;

__device__ inline unsigned short f2bf(float f) {
    unsigned int x = __float_as_uint(f);
    unsigned int r = (x + 0x7fffu + ((x >> 16) & 1u)) >> 16;  // RNE
    return (unsigned short)r;
}

// Monotone bijection fp32 -> u32 (handles negatives; order-preserving).
__device__ inline unsigned int fflip(float f) {
    unsigned int u = __float_as_uint(f);
    return u ^ (0x80000000u | (unsigned int)((int)u >> 31));
}

// 64-bit shuffle-xor across the 64-lane wave.
__device__ inline unsigned long long shflx64(unsigned long long v, int m) {
    int lo = __shfl_xor((int)(unsigned int)(v & 0xffffffffull), m, 64);
    int hi = __shfl_xor((int)(unsigned int)(v >> 32), m, 64);
    return ((unsigned long long)(unsigned int)hi << 32) | (unsigned int)lo;
}

// Compare-exchange: a=min, b=max (u64 keys are unique -> total order).
__device__ inline void ce(unsigned long long& a, unsigned long long& b) {
    bool c = a < b;
    unsigned long long lo = c ? a : b;
    unsigned long long hi = c ? b : a;
    a = lo;
    b = hi;
}

// Bitonic sort 16 (ascending), fully unrolled, static indices only.
#define SORT16(q)                                                         \
    _Pragma("unroll") for (int kk_ = 2; kk_ <= 16; kk_ <<= 1)             \
    _Pragma("unroll") for (int jj_ = kk_ >> 1; jj_ > 0; jj_ >>= 1)        \
    _Pragma("unroll") for (int ii_ = 0; ii_ < 16; ii_++) {                \
        int ll_ = ii_ ^ jj_;                                              \
        if (ll_ > ii_) {                                                  \
            if ((ii_ & kk_) == 0) ce(q[ii_], q[ll_]);                     \
            else ce(q[ll_], q[ii_]);                                      \
        }                                                                 \
    }

// Bitonic merge 16 (input bitonic -> ascending).
#define MERGE16(q)                                                        \
    _Pragma("unroll") for (int jj_ = 8; jj_ > 0; jj_ >>= 1)               \
    _Pragma("unroll") for (int ii_ = 0; ii_ < 16; ii_++) {                \
        int ll_ = ii_ ^ jj_;                                              \
        if (ll_ > ii_) ce(q[ii_], q[ll_]);                                \
    }

// Reduce 32 keys (kA[16], kB[16]) -> q[16] = sorted ascending local top-16.
// Both halves sorted asc; min(A[i], B[15-i]) is the first stage of a
// 32-bitonic merge -> lower half contains the 16 smallest (bitonic).
#define TOP16OF32(kA, kB, q)                                              \
    SORT16(kA);                                                           \
    SORT16(kB);                                                           \
    _Pragma("unroll") for (int ii_ = 0; ii_ < 16; ii_++) {                \
        unsigned long long b_ = kB[15 - ii_];                             \
        q[ii_] = kA[ii_] < b_ ? kA[ii_] : b_;                             \
    }                                                                     \
    MERGE16(q);

// Extract the wave's 16 smallest keys in ascending order. Each lane holds a
// sorted queue q[16]; per round: butterfly-min of heads, unique-key pop via
// conditional shift (all indices compile-time).
#define EXTRACT16(q, op)                                                  \
    for (int r_ = 0; r_ < KNN; r_++) {                                    \
        unsigned long long mk_ = q[0];                                    \
        _Pragma("unroll") for (int s_ = 32; s_ > 0; s_ >>= 1) {           \
            unsigned long long ok_ = shflx64(mk_, s_);                    \
            if (ok_ < mk_) mk_ = ok_;                                     \
        }                                                                 \
        if (lane == 0) (op)[r_] = (int)(mk_ & 2047u);                     \
        bool pop_ = (q[0] == mk_);                                        \
        _Pragma("unroll") for (int t_ = 0; t_ < 15; t_++)                 \
            q[t_] = pop_ ? q[t_ + 1] : q[t_];                             \
        q[15] = pop_ ? ~0ull : q[15];                                     \
    }

// ---------------------------------------------------------------------------
// KNN on 3D input points — wave-per-query, sorted-queue extraction.
// ---------------------------------------------------------------------------
__global__ __launch_bounds__(256, 4) void knn3_kernel(const float* __restrict__ x,
                                                      int* __restrict__ idx) {
    __shared__ float px[N_], py[N_], pz[N_];
    int b = blockIdx.y;
    const float* xb = x + (size_t)b * N_ * 3;
    for (int e = threadIdx.x; e < N_; e += 256) {
        px[e] = xb[e * 3 + 0];
        py[e] = xb[e * 3 + 1];
        pz[e] = xb[e * 3 + 2];
    }
    __syncthreads();

    int wave = threadIdx.x >> 6, lane = threadIdx.x & 63;
    int i = blockIdx.x * 4 + wave;
    float qx = px[i], qy = py[i], qz = pz[i];

    unsigned long long kA[16], kB[16];
#pragma unroll
    for (int t = 0; t < 16; t++) {
        int j = lane + t * 64;
        float dx = px[j] - qx, dy = py[j] - qy, dz = pz[j] - qz;
        float d = dx * dx + dy * dy + dz * dz;
        kA[t] = ((unsigned long long)fflip(d) << 11) | (unsigned int)j;
    }
#pragma unroll
    for (int t = 0; t < 16; t++) {
        int j = lane + (t + 16) * 64;
        float dx = px[j] - qx, dy = py[j] - qy, dz = pz[j] - qz;
        float d = dx * dx + dy * dy + dz * dz;
        kB[t] = ((unsigned long long)fflip(d) << 11) | (unsigned int)j;
    }

    unsigned long long q[16];
    TOP16OF32(kA, kB, q);

    int* op = idx + ((size_t)b * N_ + i) * KNN;
    EXTRACT16(q, op);
}

// ---------------------------------------------------------------------------
// Covariance features: h0 (B,12,N).
// ---------------------------------------------------------------------------
__global__ __launch_bounds__(256) void cov_kernel(const float* __restrict__ x,
                                                  const int* __restrict__ idx,
                                                  float* __restrict__ h0) {
    int b = blockIdx.y;
    int n = blockIdx.x * 256 + threadIdx.x;
    const int* ip = idx + ((size_t)b * N_ + n) * KNN;

    float px[KNN], py[KNN], pz[KNN];
    float mx = 0.f, my = 0.f, mz = 0.f;
#pragma unroll
    for (int k = 0; k < KNN; k++) {
        int j = ip[k];
        const float* p = x + ((size_t)b * N_ + j) * 3;
        px[k] = p[0]; py[k] = p[1]; pz[k] = p[2];
        mx += px[k]; my += py[k]; mz += pz[k];
    }
    mx *= (1.f / KNN); my *= (1.f / KNN); mz *= (1.f / KNN);

    float c00 = 0, c01 = 0, c02 = 0, c11 = 0, c12 = 0, c22 = 0;
#pragma unroll
    for (int k = 0; k < KNN; k++) {
        float dx = px[k] - mx, dy = py[k] - my, dz = pz[k] - mz;
        c00 += dx * dx; c01 += dx * dy; c02 += dx * dz;
        c11 += dy * dy; c12 += dy * dz; c22 += dz * dz;
    }
    float* hb = h0 + (size_t)b * 12 * N_;
    const float* xp = x + ((size_t)b * N_ + n) * 3;
    hb[0 * N_ + n] = xp[0];
    hb[1 * N_ + n] = xp[1];
    hb[2 * N_ + n] = xp[2];
    hb[3 * N_ + n] = c00; hb[4 * N_ + n] = c01; hb[5 * N_ + n] = c02;
    hb[6 * N_ + n] = c01; hb[7 * N_ + n] = c11; hb[8 * N_ + n] = c12;
    hb[9 * N_ + n] = c02; hb[10 * N_ + n] = c12; hb[11 * N_ + n] = c22;
}

// ---------------------------------------------------------------------------
// Old fp32 GEMM (kept only for conv1: C=12 needs bounds checks).
// ---------------------------------------------------------------------------
__global__ __launch_bounds__(256) void gemm_kernel(const float* __restrict__ A,
                                                   const float* __restrict__ X,
                                                   const float* __restrict__ bias,
                                                   float* __restrict__ Y,
                                                   int O, int C) {
    __shared__ float Wt[16][132];
    __shared__ float Xt[16][132];
    const int N = N_;
    int b = blockIdx.z;
    int oB = blockIdx.y * 128, nB = blockIdx.x * 128;
    const float* Xb = X + (size_t)b * C * N;
    int tid = threadIdx.x;
    int tn = tid & 15, to = tid >> 4;

    float acc[8][8];
#pragma unroll
    for (int i = 0; i < 8; i++)
#pragma unroll
        for (int j = 0; j < 8; j++) acc[i][j] = 0.f;

    for (int c0 = 0; c0 < C; c0 += 16) {
#pragma unroll
        for (int r = 0; r < 8; r++) {
            int e = tid + r * 256;
            int k = e & 15, o = e >> 4;
            float v = 0.f;
            if (c0 + k < C && oB + o < O) v = A[(size_t)(oB + o) * C + c0 + k];
            Wt[k][o] = v;
        }
#pragma unroll
        for (int r = 0; r < 8; r++) {
            int e = tid + r * 256;
            int n = e & 127, k = e >> 7;
            float v = 0.f;
            if (c0 + k < C) v = Xb[(size_t)(c0 + k) * N + nB + n];
            Xt[k][n] = v;
        }
        __syncthreads();
#pragma unroll
        for (int k = 0; k < 16; k++) {
            float a[8], xv[8];
#pragma unroll
            for (int i = 0; i < 8; i++) a[i] = Wt[k][to * 8 + i];
#pragma unroll
            for (int m = 0; m < 4; m++) {
                xv[2 * m] = Xt[k][tn * 2 + 32 * m];
                xv[2 * m + 1] = Xt[k][tn * 2 + 32 * m + 1];
            }
#pragma unroll
            for (int i = 0; i < 8; i++)
#pragma unroll
                for (int j = 0; j < 8; j++) acc[i][j] = fmaf(a[i], xv[j], acc[i][j]);
        }
        __syncthreads();
    }

#pragma unroll
    for (int i = 0; i < 8; i++) {
        int o = oB + to * 8 + i;
        if (o >= O) continue;
        float bv = bias[o];
#pragma unroll
        for (int m = 0; m < 4; m++) {
            int n0 = nB + tn * 2 + 32 * m;
            float2 st = make_float2(acc[i][2 * m] + bv, acc[i][2 * m + 1] + bv);
            *reinterpret_cast<float2*>(&Y[((size_t)b * O + o) * N + n0]) = st;
        }
    }
}

// ---------------------------------------------------------------------------
// Symmetric distance GEMM v2 (upper-triangle tiles + mirrored writes).
// ---------------------------------------------------------------------------
__global__ __launch_bounds__(256, 4) void dgemm_kernel(const float* __restrict__ F,
                                                       const float* __restrict__ X,
                                                       const float* __restrict__ nrm,
                                                       float* __restrict__ D,
                                                       int C) {
    __shared__ float Wt[32][132];
    __shared__ float Xt[32][132];
    int bz = blockIdx.z;
    int t = blockIdx.x;
    int bx = (int)((sqrtf(8.f * (float)t + 1.f) - 1.f) * 0.5f);
    while ((bx + 1) * (bx + 2) / 2 <= t) bx++;
    while (bx * (bx + 1) / 2 > t) bx--;
    int by = t - bx * (bx + 1) / 2;  // by <= bx
    int oB = by * 128, nB = bx * 128;
    const float* Fb = F + (size_t)bz * N_ * C;
    const float* Xb = X + (size_t)bz * C * N_;
    const float* nb = nrm + (size_t)bz * N_;
    float* Db = D + (size_t)bz * N_ * N_;
    int tid = threadIdx.x;
    int tn = tid & 15, to = tid >> 4;

    float acc[8][8];
#pragma unroll
    for (int i = 0; i < 8; i++)
#pragma unroll
        for (int j = 0; j < 8; j++) acc[i][j] = 0.f;

    for (int c0 = 0; c0 < C; c0 += 32) {
#pragma unroll
        for (int r = 0; r < 4; r++) {
            int e = tid + r * 256;
            int row = e >> 3, c4 = e & 7;
            float4 v = *reinterpret_cast<const float4*>(&Fb[(size_t)(oB + row) * C + c0 + c4 * 4]);
            Wt[c4 * 4 + 0][row] = v.x;
            Wt[c4 * 4 + 1][row] = v.y;
            Wt[c4 * 4 + 2][row] = v.z;
            Wt[c4 * 4 + 3][row] = v.w;
        }
#pragma unroll
        for (int r = 0; r < 4; r++) {
            int e = tid + r * 256;
            int k = e >> 5, n4 = e & 31;
            float4 v = *reinterpret_cast<const float4*>(&Xb[(size_t)(c0 + k) * N_ + nB + n4 * 4]);
            *reinterpret_cast<float4*>(&Xt[k][n4 * 4]) = v;
        }
        __syncthreads();
#pragma unroll
        for (int k = 0; k < 32; k++) {
            float a[8], xv[8];
            *reinterpret_cast<float4*>(&a[0]) = *reinterpret_cast<const float4*>(&Wt[k][to * 8]);
            *reinterpret_cast<float4*>(&a[4]) = *reinterpret_cast<const float4*>(&Wt[k][to * 8 + 4]);
#pragma unroll
            for (int m = 0; m < 4; m++) {
                float2 x2 = *reinterpret_cast<const float2*>(&Xt[k][tn * 2 + 32 * m]);
                xv[2 * m] = x2.x;
                xv[2 * m + 1] = x2.y;
            }
#pragma unroll
            for (int i = 0; i < 8; i++)
#pragma unroll
                for (int j = 0; j < 8; j++) acc[i][j] = fmaf(a[i], xv[j], acc[i][j]);
        }
        __syncthreads();
    }

#pragma unroll
    for (int i = 0; i < 8; i++) {
        int o = oB + to * 8 + i;
        float nr = nb[o];
#pragma unroll
        for (int m = 0; m < 4; m++) {
            int n0 = nB + tn * 2 + 32 * m;
            float v0 = nr + nb[n0] - 2.f * acc[i][2 * m];
            float v1 = nr + nb[n0 + 1] - 2.f * acc[i][2 * m + 1];
            *reinterpret_cast<float2*>(&Db[(size_t)o * N_ + n0]) = make_float2(v0, v1);
            acc[i][2 * m] = v0;
            acc[i][2 * m + 1] = v1;
        }
    }

    if (bx != by) {
        for (int p = 0; p < 4; p++) {
            __syncthreads();
            if ((to >> 2) == p) {
                int rl = (to & 3) * 8;
#pragma unroll
                for (int i = 0; i < 8; i++)
#pragma unroll
                    for (int m = 0; m < 4; m++) {
                        Xt[rl + i][tn * 2 + 32 * m] = acc[i][2 * m];
                        Xt[rl + i][tn * 2 + 32 * m + 1] = acc[i][2 * m + 1];
                    }
            }
            __syncthreads();
#pragma unroll
            for (int r = 0; r < 4; r++) {
                int e = tid + r * 256;
                int j = e >> 3, i4 = e & 7;
                float4 v;
                v.x = Xt[i4 * 4 + 0][j];
                v.y = Xt[i4 * 4 + 1][j];
                v.z = Xt[i4 * 4 + 2][j];
                v.w = Xt[i4 * 4 + 3][j];
                *reinterpret_cast<float4*>(&Db[(size_t)(nB + j) * N_ + oB + p * 32 + i4 * 4]) = v;
            }
        }
    }
}

// ---------------------------------------------------------------------------
// Conv fp32 GEMM v2: 64x64 tile, BK=32, C%32==0, O%64==0.
// ---------------------------------------------------------------------------
template <int XLAYOUT>
__global__ __launch_bounds__(256, 4) void cgemm_kernel(const float* __restrict__ A,
                                                       const float* __restrict__ X,
                                                       const float* __restrict__ bias,
                                                       float* __restrict__ Y,
                                                       int O, int C) {
    __shared__ float Wt[32][68];
    __shared__ float Xt[32][68];
    int b = blockIdx.z;
    int oB = blockIdx.y * 64, nB = blockIdx.x * 64;
    const float* Xb = X + (XLAYOUT == 0 ? (size_t)b * C * N_ : (size_t)b * N_ * C);
    int tid = threadIdx.x;
    int tn = tid & 15, to = tid >> 4;

    float acc[4][4];
#pragma unroll
    for (int i = 0; i < 4; i++)
#pragma unroll
        for (int j = 0; j < 4; j++) acc[i][j] = 0.f;

    for (int c0 = 0; c0 < C; c0 += 32) {
#pragma unroll
        for (int r = 0; r < 2; r++) {
            int e = tid + r * 256;
            int row = e >> 3, c4 = e & 7;
            float4 v = *reinterpret_cast<const float4*>(&A[(size_t)(oB + row) * C + c0 + c4 * 4]);
            Wt[c4 * 4 + 0][row] = v.x;
            Wt[c4 * 4 + 1][row] = v.y;
            Wt[c4 * 4 + 2][row] = v.z;
            Wt[c4 * 4 + 3][row] = v.w;
        }
        if (XLAYOUT == 0) {
#pragma unroll
            for (int r = 0; r < 2; r++) {
                int e = tid + r * 256;
                int k = e >> 4, n4 = e & 15;
                float4 v = *reinterpret_cast<const float4*>(&Xb[(size_t)(c0 + k) * N_ + nB + n4 * 4]);
                *reinterpret_cast<float4*>(&Xt[k][n4 * 4]) = v;
            }
        } else {
#pragma unroll
            for (int r = 0; r < 2; r++) {
                int e = tid + r * 256;
                int n = e >> 3, c4 = e & 7;
                float4 v = *reinterpret_cast<const float4*>(&Xb[(size_t)(nB + n) * C + c0 + c4 * 4]);
                Xt[c4 * 4 + 0][n] = v.x;
                Xt[c4 * 4 + 1][n] = v.y;
                Xt[c4 * 4 + 2][n] = v.z;
                Xt[c4 * 4 + 3][n] = v.w;
            }
        }
        __syncthreads();
#pragma unroll
        for (int k = 0; k < 32; k++) {
            float a[4], xv[4];
            *reinterpret_cast<float4*>(&a[0]) = *reinterpret_cast<const float4*>(&Wt[k][to * 4]);
            float2 x0 = *reinterpret_cast<const float2*>(&Xt[k][tn * 2]);
            float2 x1 = *reinterpret_cast<const float2*>(&Xt[k][tn * 2 + 32]);
            xv[0] = x0.x; xv[1] = x0.y; xv[2] = x1.x; xv[3] = x1.y;
#pragma unroll
            for (int i = 0; i < 4; i++)
#pragma unroll
                for (int j = 0; j < 4; j++) acc[i][j] = fmaf(a[i], xv[j], acc[i][j]);
        }
        __syncthreads();
    }

#pragma unroll
    for (int i = 0; i < 4; i++) {
        int o = oB + to * 4 + i;
        float bv = bias[o];
#pragma unroll
        for (int m = 0; m < 2; m++) {
            int n0 = nB + tn * 2 + 32 * m;
            float2 st = make_float2(acc[i][2 * m] + bv, acc[i][2 * m + 1] + bv);
            *reinterpret_cast<float2*>(&Y[((size_t)b * O + o) * N_ + n0]) = st;
        }
    }
}

// ---------------------------------------------------------------------------
// bf16 MFMA GEMM (value path only: g2 conv, conv4).
// ---------------------------------------------------------------------------
__global__ __launch_bounds__(256) void mgemm_kernel(const unsigned short* __restrict__ A,
                                                    const unsigned short* __restrict__ X,
                                                    const float* __restrict__ bias,
                                                    float* __restrict__ Y,
                                                    int O, int C) {
    __shared__ unsigned short At[128][72];
    __shared__ unsigned short Bt[128][72];
    int b = blockIdx.z;
    int oB = blockIdx.y * 128, nB = blockIdx.x * 128;
    const unsigned short* Xb = X + (size_t)b * N_ * C;
    int tid = threadIdx.x;
    int lane = tid & 63, w = tid >> 6;
    int wm = w & 1, wn = w >> 1;
    int lr = lane & 15, lg = lane >> 4;

    f32x4 acc[4][4];
#pragma unroll
    for (int m = 0; m < 4; m++)
#pragma unroll
        for (int n = 0; n < 4; n++) acc[m][n] = (f32x4){0.f, 0.f, 0.f, 0.f};

    for (int c0 = 0; c0 < C; c0 += 64) {
#pragma unroll
        for (int r = 0; r < 4; r++) {
            int t = tid + r * 256;
            int row = t >> 3, c8 = (t & 7) * 8;
            float4 va = *reinterpret_cast<const float4*>(&A[(size_t)(oB + row) * C + c0 + c8]);
            *reinterpret_cast<float4*>(&At[row][c8]) = va;
            float4 vb = *reinterpret_cast<const float4*>(&Xb[(size_t)(nB + row) * C + c0 + c8]);
            *reinterpret_cast<float4*>(&Bt[row][c8]) = vb;
        }
        __syncthreads();
#pragma unroll
        for (int kk = 0; kk < 2; kk++) {
            bf16x8 af[4], bfv[4];
#pragma unroll
            for (int m = 0; m < 4; m++)
                af[m] = *reinterpret_cast<const bf16x8*>(&At[wm * 64 + m * 16 + lr][kk * 32 + lg * 8]);
#pragma unroll
            for (int n = 0; n < 4; n++)
                bfv[n] = *reinterpret_cast<const bf16x8*>(&Bt[wn * 64 + n * 16 + lr][kk * 32 + lg * 8]);
#pragma unroll
            for (int m = 0; m < 4; m++)
#pragma unroll
                for (int n = 0; n < 4; n++)
                    acc[m][n] = __builtin_amdgcn_mfma_f32_16x16x32_bf16(af[m], bfv[n], acc[m][n], 0, 0, 0);
        }
        __syncthreads();
    }

#pragma unroll
    for (int m = 0; m < 4; m++) {
#pragma unroll
        for (int r = 0; r < 4; r++) {
            int o = oB + wm * 64 + m * 16 + lg * 4 + r;
            float bv = bias[o];
#pragma unroll
            for (int n = 0; n < 4; n++) {
                int nv = nB + wn * 64 + n * 16 + lr;
                Y[((size_t)b * O + o) * N_ + nv] = acc[m][n][r] + bv;
            }
        }
    }
}

// ---------------------------------------------------------------------------
// Per-channel BN stats over (B,N)
// ---------------------------------------------------------------------------
__global__ __launch_bounds__(256) void bnstats_kernel(const float* __restrict__ y,
                                                      const float* __restrict__ gm,
                                                      const float* __restrict__ bt,
                                                      float* __restrict__ scale,
                                                      float* __restrict__ shift, int O) {
    int o = blockIdx.x;
    float s = 0.f, s2 = 0.f;
    for (int e = threadIdx.x; e < B_ * N_; e += 256) {
        int b = e >> 11, n = e & (N_ - 1);
        float v = y[((size_t)b * O + o) * N_ + n];
        s += v;
        s2 = fmaf(v, v, s2);
    }
#pragma unroll
    for (int off = 32; off; off >>= 1) {
        s += __shfl_down(s, off, 64);
        s2 += __shfl_down(s2, off, 64);
    }
    __shared__ float red[8];
    int lane = threadIdx.x & 63, w = threadIdx.x >> 6;
    if (lane == 0) { red[w] = s; red[4 + w] = s2; }
    __syncthreads();
    if (threadIdx.x == 0) {
        s = red[0] + red[1] + red[2] + red[3];
        s2 = red[4] + red[5] + red[6] + red[7];
        float mu = s * (1.f / (B_ * N_));
        float var = s2 * (1.f / (B_ * N_)) - mu * mu;
        float inv = 1.f / sqrtf(var + 1e-5f);
        float sc = gm[o] * inv;
        scale[o] = sc;
        shift[o] = fmaf(-mu, sc, bt[o]);
    }
}

// ---------------------------------------------------------------------------
// Apply BN + ReLU in place; optional transposed fp32 (B,N,C) copy.
// ---------------------------------------------------------------------------
__global__ __launch_bounds__(256) void bnapply_kernel(float* __restrict__ y,
                                                      const float* __restrict__ scale,
                                                      const float* __restrict__ shift,
                                                      int oLog, int relu,
                                                      float* __restrict__ ft) {
    size_t i = (size_t)blockIdx.x * 256 + threadIdx.x;
    int n = (int)(i & (N_ - 1));
    size_t t = i >> 11;
    int o = (int)(t & ((1u << oLog) - 1));
    int b = (int)(t >> oLog);
    float v = fmaf(y[i], scale[o], shift[o]);
    if (relu) v = fmaxf(v, 0.f);
    y[i] = v;
    if (ft) ft[(((size_t)b << 11) + n) * (1u << oLog) + o] = v;
}

// ---------------------------------------------------------------------------
// BN apply + ReLU + transpose, fp32 (B,O,N) -> bf16 (B,N,O). 64x64 LDS tile.
// ---------------------------------------------------------------------------
__global__ __launch_bounds__(256) void bnt_kernel(const float* __restrict__ y,
                                                  const float* __restrict__ scale,
                                                  const float* __restrict__ shift,
                                                  unsigned short* __restrict__ ft, int O) {
    __shared__ float tile[64][65];
    int b = blockIdx.z;
    int n0 = blockIdx.x * 64, o0 = blockIdx.y * 64;
    int t = threadIdx.x;
#pragma unroll
    for (int rr = 0; rr < 16; rr++) {
        int ol = rr * 4 + (t >> 6), nl = t & 63;
        float v = y[((size_t)b * O + o0 + ol) * N_ + n0 + nl];
        v = fmaf(v, scale[o0 + ol], shift[o0 + ol]);
        tile[ol][nl] = fmaxf(v, 0.f);
    }
    __syncthreads();
#pragma unroll
    for (int rr = 0; rr < 2; rr++) {
        int e = t + rr * 256;
        int n = e >> 3, og = (e & 7) * 8;
        unsigned short u[8];
#pragma unroll
        for (int j = 0; j < 8; j++) u[j] = f2bf(tile[og + j][n]);
        uint4 pk;
        pk.x = (unsigned)u[0] | ((unsigned)u[1] << 16);
        pk.y = (unsigned)u[2] | ((unsigned)u[3] << 16);
        pk.z = (unsigned)u[4] | ((unsigned)u[5] << 16);
        pk.w = (unsigned)u[6] | ((unsigned)u[7] << 16);
        *reinterpret_cast<uint4*>(&ft[((size_t)b * N_ + n0 + n) * O + o0 + og]) = pk;
    }
}

// ---------------------------------------------------------------------------
// Squared norms per point from (B,C,N) fp32 (ascending-c fma == GEMM order).
// ---------------------------------------------------------------------------
__global__ __launch_bounds__(256) void norms_kernel(const float* __restrict__ h,
                                                    float* __restrict__ nrm, int C) {
    int b = blockIdx.y;
    int i = blockIdx.x * 256 + threadIdx.x;
    const float* hp = h + (size_t)b * C * N_;
    float s = 0.f;
    for (int c = 0; c < C; c++) {
        float v = hp[(size_t)c * N_ + i];
        s = fmaf(v, v, s);
    }
    nrm[(b << 11) + i] = s;
}

// ---------------------------------------------------------------------------
// Top-16 per row of a (4*2048) x 2048 distance block — wave per row,
// sorted-queue extraction (no LDS).
// ---------------------------------------------------------------------------
__global__ __launch_bounds__(256, 4) void topk_kernel(const float* __restrict__ D,
                                                      int* __restrict__ idx) {
    int wave = threadIdx.x >> 6, lane = threadIdx.x & 63;
    int i = blockIdx.x * 4 + wave;  // global row within 4-batch chunk
    const float* dp = D + (size_t)i * N_;

    unsigned long long kA[16], kB[16];
#pragma unroll
    for (int t = 0; t < 4; t++) {
        float4 v = *reinterpret_cast<const float4*>(&dp[t * 256 + lane * 4]);
        int j0 = t * 256 + lane * 4;
        kA[t * 4 + 0] = ((unsigned long long)fflip(v.x) << 11) | (unsigned int)(j0 + 0);
        kA[t * 4 + 1] = ((unsigned long long)fflip(v.y) << 11) | (unsigned int)(j0 + 1);
        kA[t * 4 + 2] = ((unsigned long long)fflip(v.z) << 11) | (unsigned int)(j0 + 2);
        kA[t * 4 + 3] = ((unsigned long long)fflip(v.w) << 11) | (unsigned int)(j0 + 3);
    }
#pragma unroll
    for (int t = 4; t < 8; t++) {
        float4 v = *reinterpret_cast<const float4*>(&dp[t * 256 + lane * 4]);
        int j0 = t * 256 + lane * 4;
        kB[(t - 4) * 4 + 0] = ((unsigned long long)fflip(v.x) << 11) | (unsigned int)(j0 + 0);
        kB[(t - 4) * 4 + 1] = ((unsigned long long)fflip(v.y) << 11) | (unsigned int)(j0 + 1);
        kB[(t - 4) * 4 + 2] = ((unsigned long long)fflip(v.z) << 11) | (unsigned int)(j0 + 2);
        kB[(t - 4) * 4 + 3] = ((unsigned long long)fflip(v.w) << 11) | (unsigned int)(j0 + 3);
    }

    unsigned long long q[16];
    TOP16OF32(kA, kB, q);

    int* op = idx + (size_t)i * KNN;
    EXTRACT16(q, op);
}

// ---------------------------------------------------------------------------
// Gather 16 neighbor fp32 rows (B,N,C), max over k -> fp32 (B,N,C).
// ---------------------------------------------------------------------------
__global__ __launch_bounds__(256) void gathermax_kernel(const float* __restrict__ ft,
                                                        const int* __restrict__ idx,
                                                        float* __restrict__ out, int cLog) {
    int C = 1 << cLog;
    int b = blockIdx.y;
    int nb = (blockIdx.x << (8 - cLog)) + (threadIdx.x >> cLog);
    int c = threadIdx.x & (C - 1);
    const int* ip = idx + (((size_t)b << 11) + nb) * KNN;
    float m = -3.4e38f;
#pragma unroll
    for (int k = 0; k < KNN; k++) {
        int j = ip[k];
        m = fmaxf(m, ft[(((size_t)b << 11) + j) * C + c]);
    }
    out[(((size_t)b << 11) + nb) * C + c] = m;
}

// ---------------------------------------------------------------------------
// Gather-max: fp32 (B,N,128) in -> bf16 (B,N,128) out (feeds g2 MFMA only).
// ---------------------------------------------------------------------------
__global__ __launch_bounds__(256) void gmaxh2_kernel(const float* __restrict__ ft,
                                                     const int* __restrict__ idx,
                                                     unsigned short* __restrict__ out) {
    const int C = 128;
    int b = blockIdx.y;
    int nb = blockIdx.x * 16 + (threadIdx.x >> 4);
    int cc = (threadIdx.x & 15) * 8;
    const int* ip = idx + (((size_t)b << 11) + nb) * KNN;
    float m[8];
#pragma unroll
    for (int q = 0; q < 8; q++) m[q] = -3.4e38f;
#pragma unroll
    for (int k = 0; k < KNN; k++) {
        int j = ip[k];
        const float* p = &ft[(((size_t)b << 11) + j) * C + cc];
        float4 a = *reinterpret_cast<const float4*>(p);
        float4 c2 = *reinterpret_cast<const float4*>(p + 4);
        m[0] = fmaxf(m[0], a.x); m[1] = fmaxf(m[1], a.y);
        m[2] = fmaxf(m[2], a.z); m[3] = fmaxf(m[3], a.w);
        m[4] = fmaxf(m[4], c2.x); m[5] = fmaxf(m[5], c2.y);
        m[6] = fmaxf(m[6], c2.z); m[7] = fmaxf(m[7], c2.w);
    }
    unsigned short u[8];
#pragma unroll
    for (int q = 0; q < 8; q++) u[q] = f2bf(m[q]);
    uint4 pk;
    pk.x = (unsigned)u[0] | ((unsigned)u[1] << 16);
    pk.y = (unsigned)u[2] | ((unsigned)u[3] << 16);
    pk.z = (unsigned)u[4] | ((unsigned)u[5] << 16);
    pk.w = (unsigned)u[6] | ((unsigned)u[7] << 16);
    *reinterpret_cast<uint4*>(&out[(((size_t)b << 11) + nb) * C + cc]) = pk;
}

// ---------------------------------------------------------------------------
// fp32 -> bf16 weight conversion
// ---------------------------------------------------------------------------
__global__ __launch_bounds__(256) void wcvt_kernel(const float* __restrict__ w,
                                                   unsigned short* __restrict__ wh, int count) {
    int i = blockIdx.x * 256 + threadIdx.x;
    if (i < count) wh[i] = f2bf(w[i]);
}

// ---------------------------------------------------------------------------
// Final: out[b,o] = max_n (y4[b,o,n]*scale[o]+shift[o])
// ---------------------------------------------------------------------------
__global__ __launch_bounds__(256) void finalmax_kernel(const float* __restrict__ y,
                                                       const float* __restrict__ scale,
                                                       const float* __restrict__ shift,
                                                       float* __restrict__ out) {
    int o = blockIdx.x, b = blockIdx.y;
    float s = scale[o], t = shift[o];
    const float* yp = y + ((size_t)b * 512 + o) * N_;
    float m = -3.4e38f;
    for (int n = threadIdx.x; n < N_; n += 256) m = fmaxf(m, fmaf(yp[n], s, t));
#pragma unroll
    for (int off = 32; off; off >>= 1) m = fmaxf(m, __shfl_down(m, off, 64));
    __shared__ float red[4];
    int lane = threadIdx.x & 63, w = threadIdx.x >> 6;
    if (lane == 0) red[w] = m;
    __syncthreads();
    if (threadIdx.x == 0)
        out[b * 512 + o] = fmaxf(fmaxf(red[0], red[1]), fmaxf(red[2], red[3]));
}

// ---------------------------------------------------------------------------
extern "C" void kernel_launch(void* const* d_in, const int* in_sizes, int n_in,
                              void* d_out, int out_size, void* d_ws, size_t ws_size,
                              hipStream_t stream) {
    const float* x = (const float*)d_in[0];
    const float* W1 = (const float*)d_in[1];
    const float* b1 = (const float*)d_in[2];
    const float* gm1 = (const float*)d_in[3];
    const float* bt1 = (const float*)d_in[4];
    const float* W2 = (const float*)d_in[5];
    const float* b2 = (const float*)d_in[6];
    const float* gm2 = (const float*)d_in[7];
    const float* bt2 = (const float*)d_in[8];
    const float* W3 = (const float*)d_in[9];
    const float* b3 = (const float*)d_in[10];
    const float* gm3 = (const float*)d_in[11];
    const float* bt3 = (const float*)d_in[12];
    const float* Wg1 = (const float*)d_in[13];
    const float* bg1 = (const float*)d_in[14];
    const float* gmg1 = (const float*)d_in[15];
    const float* btg1 = (const float*)d_in[16];
    const float* Wg2 = (const float*)d_in[17];
    const float* bg2 = (const float*)d_in[18];
    const float* gmg2 = (const float*)d_in[19];
    const float* btg2 = (const float*)d_in[20];
    const float* W4 = (const float*)d_in[21];
    const float* b4 = (const float*)d_in[22];
    const float* gm4 = (const float*)d_in[23];
    const float* bt4 = (const float*)d_in[24];
    float* out = (float*)d_out;

    // ---- workspace arena (byte offsets), total 154,214,400 bytes ----
    if (ws_size < 154214400ull) return;
    char* base = (char*)d_ws;
    float* scale = (float*)(base + 0);
    float* shift = (float*)(base + 4096);
    float* nrm = (float*)(base + 8192);
    int* idx = (int*)(base + 73728);
    unsigned short* Wg2h = (unsigned short*)(base + 1122304);
    unsigned short* W4h = (unsigned short*)(base + 1384448);
    // bufD4: 4-batch distance chunk (67.1 MB) — aliases bufL region, which is
    // only written (g2 conv) AFTER both KNN loops complete.
    float* bufD4 = (float*)(base + 19210240);
    float* bufL = (float*)(base + 19210240);                    // (8,1024,2048) f32
    unsigned short* bufLh = (unsigned short*)(base + 86319104); // (8,2048,1024) bf16
    char* E = base + 119873536;                                 // early region
    float* h0 = (float*)(E + 0);                                // (8,12,2048)
    float* bufA = (float*)(E + 786432);                         // (8,64,2048)
    float* bufB = (float*)(E + 4980736);                        // (8,64,2048)
    float* bufC = (float*)(E + 9175040);                        // (8,2048,64)
    float* bufM1 = (float*)(E + 13369344);                      // (8,128,2048)
    float* bufM2 = (float*)(E + 21757952);                      // (8,2048,128)
    unsigned short* bufM3h = (unsigned short*)(E + 30146560);   // (8,2048,128) bf16
    float* bufY4 = (float*)(E + 0);                             // (8,512,2048) aliases E

    // weight conversion (value-path weights only)
    wcvt_kernel<<<512, 256, 0, stream>>>(Wg2, Wg2h, 1024 * 128);
    wcvt_kernel<<<2048, 256, 0, stream>>>(W4, W4h, 512 * 1024);

    // Stage 0/1: 3D KNN + covariance features
    knn3_kernel<<<dim3(512, 8), 256, 0, stream>>>(x, idx);
    cov_kernel<<<dim3(8, 8), 256, 0, stream>>>(x, idx, h0);

    // conv1: 12 -> 64 (fp32, old path: C=12)
    gemm_kernel<<<dim3(16, 1, 8), 256, 0, stream>>>(W1, h0, b1, bufA, 64, 12);
    bnstats_kernel<<<64, 256, 0, stream>>>(bufA, gm1, bt1, scale, shift, 64);
    bnapply_kernel<<<4096, 256, 0, stream>>>(bufA, scale, shift, 6, 1, nullptr);

    // conv2: 64 -> 64 (fp32 v2)
    cgemm_kernel<0><<<dim3(32, 1, 8), 256, 0, stream>>>(W2, bufA, b2, bufB, 64, 64);
    bnstats_kernel<<<64, 256, 0, stream>>>(bufB, gm2, bt2, scale, shift, 64);
    bnapply_kernel<<<4096, 256, 0, stream>>>(bufB, scale, shift, 6, 1, nullptr);

    // conv3: 64 -> 64 (fp32 v2), dual write bufA (B,64,N) + bufC (B,N,64)
    cgemm_kernel<0><<<dim3(32, 1, 8), 256, 0, stream>>>(W3, bufB, b3, bufA, 64, 64);
    bnstats_kernel<<<64, 256, 0, stream>>>(bufA, gm3, bt3, scale, shift, 64);
    bnapply_kernel<<<4096, 256, 0, stream>>>(bufA, scale, shift, 6, 1, bufC);

    // graph layer 1 KNN (C=64, symmetric fp32 distances), 4-batch chunks
    norms_kernel<<<dim3(8, 8), 256, 0, stream>>>(bufA, nrm, 64);
    for (int c = 0; c < 2; c++) {
        dgemm_kernel<<<dim3(136, 1, 4), 256, 0, stream>>>(
            bufC + (size_t)c * 4 * N_ * 64, bufA + (size_t)c * 4 * 64 * N_,
            nrm + (size_t)c * 4 * N_, bufD4, 64);
        topk_kernel<<<2048, 256, 0, stream>>>(bufD4, idx + (size_t)c * 4 * N_ * KNN);
    }
    gathermax_kernel<<<dim3(512, 8), 256, 0, stream>>>(bufC, idx, bufB, 6);

    // conv g1: 64 -> 128 (fp32 v2, input (B,N,64))
    cgemm_kernel<1><<<dim3(32, 2, 8), 256, 0, stream>>>(Wg1, bufB, bg1, bufM1, 128, 64);
    bnstats_kernel<<<128, 256, 0, stream>>>(bufM1, gmg1, btg1, scale, shift, 128);
    bnapply_kernel<<<8192, 256, 0, stream>>>(bufM1, scale, shift, 7, 1, bufM2);

    // graph layer 2 KNN (C=128, symmetric fp32 distances), 4-batch chunks
    norms_kernel<<<dim3(8, 8), 256, 0, stream>>>(bufM1, nrm, 128);
    for (int c = 0; c < 2; c++) {
        dgemm_kernel<<<dim3(136, 1, 4), 256, 0, stream>>>(
            bufM2 + (size_t)c * 4 * N_ * 128, bufM1 + (size_t)c * 4 * 128 * N_,
            nrm + (size_t)c * 4 * N_, bufD4, 128);
        topk_kernel<<<2048, 256, 0, stream>>>(bufD4, idx + (size_t)c * 4 * N_ * KNN);
    }
    gmaxh2_kernel<<<dim3(128, 8), 256, 0, stream>>>(bufM2, idx, bufM3h);

    // conv g2: 128 -> 1024 (bf16 MFMA, value path)
    mgemm_kernel<<<dim3(16, 8, 8), 256, 0, stream>>>(Wg2h, bufM3h, bg2, bufL, 1024, 128);
    bnstats_kernel<<<1024, 256, 0, stream>>>(bufL, gmg2, btg2, scale, shift, 1024);
    bnt_kernel<<<dim3(32, 16, 8), 256, 0, stream>>>(bufL, scale, shift, bufLh, 1024);

    // conv4: 1024 -> 512 (bf16 MFMA), BN folded into final max
    mgemm_kernel<<<dim3(16, 4, 8), 256, 0, stream>>>(W4h, bufLh, b4, bufY4, 512, 1024);
    bnstats_kernel<<<512, 256, 0, stream>>>(bufY4, gm4, bt4, scale, shift, 512);
    finalmax_kernel<<<dim3(512, 8), 256, 0, stream>>>(bufY4, scale, shift, out);
}

// Round 9
// 658.908 us; speedup vs baseline: 7.4519x; 1.0133x over previous
//
#include <hip/hip_runtime.h>
#include <math.h>

#define B_ 8
#define N_ 2048
#define KNN 16

typedef __attribute__((ext_vector_type(4))) float f32x4;
typedef __attribute__((ext_vector_type(8))) short bf16x8;
typedef __attribute__((address_space(3))) unsigned int lds_u32_t;
typedef __attribute__((address_space(1))) const unsigned int glb_u32_t;

__device__ inline unsigned short f2bf(float f) {
    unsigned int x = __float_as_uint(f);
    unsigned int r = (x + 0x7fffu + ((x >> 16) & 1u)) >> 16;  // RNE
    return (unsigned short)r;
}

// Monotone bijection fp32 -> u32 (handles negatives; order-preserving).
__device__ inline unsigned int fflip(float f) {
    unsigned int u = __float_as_uint(f);
    return u ^ (0x80000000u | (unsigned int)((int)u >> 31));
}

// 64-bit shuffle-xor across the 64-lane wave.
__device__ inline unsigned long long shflx64(unsigned long long v, int m) {
    int lo = __shfl_xor((int)(unsigned int)(v & 0xffffffffull), m, 64);
    int hi = __shfl_xor((int)(unsigned int)(v >> 32), m, 64);
    return ((unsigned long long)(unsigned int)hi << 32) | (unsigned int)lo;
}

// Compare-exchange: a=min, b=max (u64 keys are unique -> total order).
__device__ inline void ce(unsigned long long& a, unsigned long long& b) {
    bool c = a < b;
    unsigned long long lo = c ? a : b;
    unsigned long long hi = c ? b : a;
    a = lo;
    b = hi;
}

// Bitonic sort 16 (ascending), fully unrolled, static indices only.
#define SORT16(q)                                                         \
    _Pragma("unroll") for (int kk_ = 2; kk_ <= 16; kk_ <<= 1)             \
    _Pragma("unroll") for (int jj_ = kk_ >> 1; jj_ > 0; jj_ >>= 1)        \
    _Pragma("unroll") for (int ii_ = 0; ii_ < 16; ii_++) {                \
        int ll_ = ii_ ^ jj_;                                              \
        if (ll_ > ii_) {                                                  \
            if ((ii_ & kk_) == 0) ce(q[ii_], q[ll_]);                     \
            else ce(q[ll_], q[ii_]);                                      \
        }                                                                 \
    }

// Bitonic merge 16 (input bitonic -> ascending).
#define MERGE16(q)                                                        \
    _Pragma("unroll") for (int jj_ = 8; jj_ > 0; jj_ >>= 1)               \
    _Pragma("unroll") for (int ii_ = 0; ii_ < 16; ii_++) {                \
        int ll_ = ii_ ^ jj_;                                              \
        if (ll_ > ii_) ce(q[ii_], q[ll_]);                                \
    }

// Reduce 32 keys (kA[16], kB[16]) -> q[16] = sorted ascending local top-16.
#define TOP16OF32(kA, kB, q)                                              \
    SORT16(kA);                                                           \
    SORT16(kB);                                                           \
    _Pragma("unroll") for (int ii_ = 0; ii_ < 16; ii_++) {                \
        unsigned long long b_ = kB[15 - ii_];                             \
        q[ii_] = kA[ii_] < b_ ? kA[ii_] : b_;                             \
    }                                                                     \
    MERGE16(q);

// Extract the wave's 16 smallest keys in ascending order.
#define EXTRACT16(q, op)                                                  \
    for (int r_ = 0; r_ < KNN; r_++) {                                    \
        unsigned long long mk_ = q[0];                                    \
        _Pragma("unroll") for (int s_ = 32; s_ > 0; s_ >>= 1) {           \
            unsigned long long ok_ = shflx64(mk_, s_);                    \
            if (ok_ < mk_) mk_ = ok_;                                     \
        }                                                                 \
        if (lane == 0) (op)[r_] = (int)(mk_ & 2047u);                     \
        bool pop_ = (q[0] == mk_);                                        \
        _Pragma("unroll") for (int t_ = 0; t_ < 15; t_++)                 \
            q[t_] = pop_ ? q[t_ + 1] : q[t_];                             \
        q[15] = pop_ ? ~0ull : q[15];                                     \
    }

// ---------------------------------------------------------------------------
// KNN on 3D input points — wave-per-query, sorted-queue extraction.
// ---------------------------------------------------------------------------
__global__ __launch_bounds__(256, 4) void knn3_kernel(const float* __restrict__ x,
                                                      int* __restrict__ idx) {
    __shared__ float px[N_], py[N_], pz[N_];
    int b = blockIdx.y;
    const float* xb = x + (size_t)b * N_ * 3;
    for (int e = threadIdx.x; e < N_; e += 256) {
        px[e] = xb[e * 3 + 0];
        py[e] = xb[e * 3 + 1];
        pz[e] = xb[e * 3 + 2];
    }
    __syncthreads();

    int wave = threadIdx.x >> 6, lane = threadIdx.x & 63;
    int i = blockIdx.x * 4 + wave;
    float qx = px[i], qy = py[i], qz = pz[i];

    unsigned long long kA[16], kB[16];
#pragma unroll
    for (int t = 0; t < 16; t++) {
        int j = lane + t * 64;
        float dx = px[j] - qx, dy = py[j] - qy, dz = pz[j] - qz;
        float d = dx * dx + dy * dy + dz * dz;
        kA[t] = ((unsigned long long)fflip(d) << 11) | (unsigned int)j;
    }
#pragma unroll
    for (int t = 0; t < 16; t++) {
        int j = lane + (t + 16) * 64;
        float dx = px[j] - qx, dy = py[j] - qy, dz = pz[j] - qz;
        float d = dx * dx + dy * dy + dz * dz;
        kB[t] = ((unsigned long long)fflip(d) << 11) | (unsigned int)j;
    }

    unsigned long long q[16];
    TOP16OF32(kA, kB, q);

    int* op = idx + ((size_t)b * N_ + i) * KNN;
    EXTRACT16(q, op);
}

// ---------------------------------------------------------------------------
// Covariance features: h0 (B,12,N).
// ---------------------------------------------------------------------------
__global__ __launch_bounds__(256) void cov_kernel(const float* __restrict__ x,
                                                  const int* __restrict__ idx,
                                                  float* __restrict__ h0) {
    int b = blockIdx.y;
    int n = blockIdx.x * 256 + threadIdx.x;
    const int* ip = idx + ((size_t)b * N_ + n) * KNN;

    float px[KNN], py[KNN], pz[KNN];
    float mx = 0.f, my = 0.f, mz = 0.f;
#pragma unroll
    for (int k = 0; k < KNN; k++) {
        int j = ip[k];
        const float* p = x + ((size_t)b * N_ + j) * 3;
        px[k] = p[0]; py[k] = p[1]; pz[k] = p[2];
        mx += px[k]; my += py[k]; mz += pz[k];
    }
    mx *= (1.f / KNN); my *= (1.f / KNN); mz *= (1.f / KNN);

    float c00 = 0, c01 = 0, c02 = 0, c11 = 0, c12 = 0, c22 = 0;
#pragma unroll
    for (int k = 0; k < KNN; k++) {
        float dx = px[k] - mx, dy = py[k] - my, dz = pz[k] - mz;
        c00 += dx * dx; c01 += dx * dy; c02 += dx * dz;
        c11 += dy * dy; c12 += dy * dz; c22 += dz * dz;
    }
    float* hb = h0 + (size_t)b * 12 * N_;
    const float* xp = x + ((size_t)b * N_ + n) * 3;
    hb[0 * N_ + n] = xp[0];
    hb[1 * N_ + n] = xp[1];
    hb[2 * N_ + n] = xp[2];
    hb[3 * N_ + n] = c00; hb[4 * N_ + n] = c01; hb[5 * N_ + n] = c02;
    hb[6 * N_ + n] = c01; hb[7 * N_ + n] = c11; hb[8 * N_ + n] = c12;
    hb[9 * N_ + n] = c02; hb[10 * N_ + n] = c12; hb[11 * N_ + n] = c22;
}

// ---------------------------------------------------------------------------
// Old fp32 GEMM (kept only for conv1: C=12 needs bounds checks).
// ---------------------------------------------------------------------------
__global__ __launch_bounds__(256) void gemm_kernel(const float* __restrict__ A,
                                                   const float* __restrict__ X,
                                                   const float* __restrict__ bias,
                                                   float* __restrict__ Y,
                                                   int O, int C) {
    __shared__ float Wt[16][132];
    __shared__ float Xt[16][132];
    const int N = N_;
    int b = blockIdx.z;
    int oB = blockIdx.y * 128, nB = blockIdx.x * 128;
    const float* Xb = X + (size_t)b * C * N;
    int tid = threadIdx.x;
    int tn = tid & 15, to = tid >> 4;

    float acc[8][8];
#pragma unroll
    for (int i = 0; i < 8; i++)
#pragma unroll
        for (int j = 0; j < 8; j++) acc[i][j] = 0.f;

    for (int c0 = 0; c0 < C; c0 += 16) {
#pragma unroll
        for (int r = 0; r < 8; r++) {
            int e = tid + r * 256;
            int k = e & 15, o = e >> 4;
            float v = 0.f;
            if (c0 + k < C && oB + o < O) v = A[(size_t)(oB + o) * C + c0 + k];
            Wt[k][o] = v;
        }
#pragma unroll
        for (int r = 0; r < 8; r++) {
            int e = tid + r * 256;
            int n = e & 127, k = e >> 7;
            float v = 0.f;
            if (c0 + k < C) v = Xb[(size_t)(c0 + k) * N + nB + n];
            Xt[k][n] = v;
        }
        __syncthreads();
#pragma unroll
        for (int k = 0; k < 16; k++) {
            float a[8], xv[8];
#pragma unroll
            for (int i = 0; i < 8; i++) a[i] = Wt[k][to * 8 + i];
#pragma unroll
            for (int m = 0; m < 4; m++) {
                xv[2 * m] = Xt[k][tn * 2 + 32 * m];
                xv[2 * m + 1] = Xt[k][tn * 2 + 32 * m + 1];
            }
#pragma unroll
            for (int i = 0; i < 8; i++)
#pragma unroll
                for (int j = 0; j < 8; j++) acc[i][j] = fmaf(a[i], xv[j], acc[i][j]);
        }
        __syncthreads();
    }

#pragma unroll
    for (int i = 0; i < 8; i++) {
        int o = oB + to * 8 + i;
        if (o >= O) continue;
        float bv = bias[o];
#pragma unroll
        for (int m = 0; m < 4; m++) {
            int n0 = nB + tn * 2 + 32 * m;
            float2 st = make_float2(acc[i][2 * m] + bv, acc[i][2 * m + 1] + bv);
            *reinterpret_cast<float2*>(&Y[((size_t)b * O + o) * N + n0]) = st;
        }
    }
}

// ---------------------------------------------------------------------------
// Symmetric distance GEMM v3: BOTH operands staged from the (z,C,N) array
// (A rows of F == columns of X), coalesced float4 loads, no transpose scatter.
// Upper-triangle tiles + mirrored writes. C%32==0.
// ---------------------------------------------------------------------------
__global__ __launch_bounds__(256, 4) void dgemm_kernel(const float* __restrict__ X,
                                                       const float* __restrict__ nrm,
                                                       float* __restrict__ D,
                                                       int C) {
    __shared__ float Wt[32][132];
    __shared__ float Xt[32][132];
    int bz = blockIdx.z;
    int t = blockIdx.x;
    int bx = (int)((sqrtf(8.f * (float)t + 1.f) - 1.f) * 0.5f);
    while ((bx + 1) * (bx + 2) / 2 <= t) bx++;
    while (bx * (bx + 1) / 2 > t) bx--;
    int by = t - bx * (bx + 1) / 2;  // by <= bx
    int oB = by * 128, nB = bx * 128;
    const float* Xb = X + (size_t)bz * C * N_;
    const float* nb = nrm + (size_t)bz * N_;
    float* Db = D + (size_t)bz * N_ * N_;
    int tid = threadIdx.x;
    int tn = tid & 15, to = tid >> 4;

    float acc[8][8];
#pragma unroll
    for (int i = 0; i < 8; i++)
#pragma unroll
        for (int j = 0; j < 8; j++) acc[i][j] = 0.f;

    for (int c0 = 0; c0 < C; c0 += 32) {
#pragma unroll
        for (int r = 0; r < 4; r++) {
            int e = tid + r * 256;
            int k = e >> 5, n4 = e & 31;
            float4 v = *reinterpret_cast<const float4*>(&Xb[(size_t)(c0 + k) * N_ + oB + n4 * 4]);
            *reinterpret_cast<float4*>(&Wt[k][n4 * 4]) = v;
        }
#pragma unroll
        for (int r = 0; r < 4; r++) {
            int e = tid + r * 256;
            int k = e >> 5, n4 = e & 31;
            float4 v = *reinterpret_cast<const float4*>(&Xb[(size_t)(c0 + k) * N_ + nB + n4 * 4]);
            *reinterpret_cast<float4*>(&Xt[k][n4 * 4]) = v;
        }
        __syncthreads();
#pragma unroll
        for (int k = 0; k < 32; k++) {
            float a[8], xv[8];
            *reinterpret_cast<float4*>(&a[0]) = *reinterpret_cast<const float4*>(&Wt[k][to * 8]);
            *reinterpret_cast<float4*>(&a[4]) = *reinterpret_cast<const float4*>(&Wt[k][to * 8 + 4]);
#pragma unroll
            for (int m = 0; m < 4; m++) {
                float2 x2 = *reinterpret_cast<const float2*>(&Xt[k][tn * 2 + 32 * m]);
                xv[2 * m] = x2.x;
                xv[2 * m + 1] = x2.y;
            }
#pragma unroll
            for (int i = 0; i < 8; i++)
#pragma unroll
                for (int j = 0; j < 8; j++) acc[i][j] = fmaf(a[i], xv[j], acc[i][j]);
        }
        __syncthreads();
    }

#pragma unroll
    for (int i = 0; i < 8; i++) {
        int o = oB + to * 8 + i;
        float nr = nb[o];
#pragma unroll
        for (int m = 0; m < 4; m++) {
            int n0 = nB + tn * 2 + 32 * m;
            float v0 = nr + nb[n0] - 2.f * acc[i][2 * m];
            float v1 = nr + nb[n0 + 1] - 2.f * acc[i][2 * m + 1];
            *reinterpret_cast<float2*>(&Db[(size_t)o * N_ + n0]) = make_float2(v0, v1);
            acc[i][2 * m] = v0;
            acc[i][2 * m + 1] = v1;
        }
    }

    if (bx != by) {
        for (int p = 0; p < 4; p++) {
            __syncthreads();
            if ((to >> 2) == p) {
                int rl = (to & 3) * 8;
#pragma unroll
                for (int i = 0; i < 8; i++)
#pragma unroll
                    for (int m = 0; m < 4; m++) {
                        Xt[rl + i][tn * 2 + 32 * m] = acc[i][2 * m];
                        Xt[rl + i][tn * 2 + 32 * m + 1] = acc[i][2 * m + 1];
                    }
            }
            __syncthreads();
#pragma unroll
            for (int r = 0; r < 4; r++) {
                int e = tid + r * 256;
                int j = e >> 3, i4 = e & 7;
                float4 v;
                v.x = Xt[i4 * 4 + 0][j];
                v.y = Xt[i4 * 4 + 1][j];
                v.z = Xt[i4 * 4 + 2][j];
                v.w = Xt[i4 * 4 + 3][j];
                *reinterpret_cast<float4*>(&Db[(size_t)(nB + j) * N_ + oB + p * 32 + i4 * 4]) = v;
            }
        }
    }
}

// ---------------------------------------------------------------------------
// Conv fp32 GEMM v2: 64x64 tile, BK=32, C%32==0, O%64==0.
// FUSE=1 (XLAYOUT 0 only): X-load applies y=relu(fmaf(x,xs[c],xh[c])) on the
// fly — bitwise identical to a prior separate bnapply pass.
// ---------------------------------------------------------------------------
template <int XLAYOUT, int FUSE>
__global__ __launch_bounds__(256, 4) void cgemm_kernel(const float* __restrict__ A,
                                                       const float* __restrict__ X,
                                                       const float* __restrict__ bias,
                                                       float* __restrict__ Y,
                                                       int O, int C,
                                                       const float* __restrict__ xs,
                                                       const float* __restrict__ xh) {
    __shared__ float Wt[32][68];
    __shared__ float Xt[32][68];
    int b = blockIdx.z;
    int oB = blockIdx.y * 64, nB = blockIdx.x * 64;
    const float* Xb = X + (XLAYOUT == 0 ? (size_t)b * C * N_ : (size_t)b * N_ * C);
    int tid = threadIdx.x;
    int tn = tid & 15, to = tid >> 4;

    float acc[4][4];
#pragma unroll
    for (int i = 0; i < 4; i++)
#pragma unroll
        for (int j = 0; j < 4; j++) acc[i][j] = 0.f;

    for (int c0 = 0; c0 < C; c0 += 32) {
#pragma unroll
        for (int r = 0; r < 2; r++) {
            int e = tid + r * 256;
            int row = e >> 3, c4 = e & 7;
            float4 v = *reinterpret_cast<const float4*>(&A[(size_t)(oB + row) * C + c0 + c4 * 4]);
            Wt[c4 * 4 + 0][row] = v.x;
            Wt[c4 * 4 + 1][row] = v.y;
            Wt[c4 * 4 + 2][row] = v.z;
            Wt[c4 * 4 + 3][row] = v.w;
        }
        if (XLAYOUT == 0) {
#pragma unroll
            for (int r = 0; r < 2; r++) {
                int e = tid + r * 256;
                int k = e >> 4, n4 = e & 15;
                float4 v = *reinterpret_cast<const float4*>(&Xb[(size_t)(c0 + k) * N_ + nB + n4 * 4]);
                if (FUSE) {
                    float sc = xs[c0 + k], sh = xh[c0 + k];
                    v.x = fmaxf(fmaf(v.x, sc, sh), 0.f);
                    v.y = fmaxf(fmaf(v.y, sc, sh), 0.f);
                    v.z = fmaxf(fmaf(v.z, sc, sh), 0.f);
                    v.w = fmaxf(fmaf(v.w, sc, sh), 0.f);
                }
                *reinterpret_cast<float4*>(&Xt[k][n4 * 4]) = v;
            }
        } else {
#pragma unroll
            for (int r = 0; r < 2; r++) {
                int e = tid + r * 256;
                int n = e >> 3, c4 = e & 7;
                float4 v = *reinterpret_cast<const float4*>(&Xb[(size_t)(nB + n) * C + c0 + c4 * 4]);
                Xt[c4 * 4 + 0][n] = v.x;
                Xt[c4 * 4 + 1][n] = v.y;
                Xt[c4 * 4 + 2][n] = v.z;
                Xt[c4 * 4 + 3][n] = v.w;
            }
        }
        __syncthreads();
#pragma unroll
        for (int k = 0; k < 32; k++) {
            float a[4], xv[4];
            *reinterpret_cast<float4*>(&a[0]) = *reinterpret_cast<const float4*>(&Wt[k][to * 4]);
            float2 x0 = *reinterpret_cast<const float2*>(&Xt[k][tn * 2]);
            float2 x1 = *reinterpret_cast<const float2*>(&Xt[k][tn * 2 + 32]);
            xv[0] = x0.x; xv[1] = x0.y; xv[2] = x1.x; xv[3] = x1.y;
#pragma unroll
            for (int i = 0; i < 4; i++)
#pragma unroll
                for (int j = 0; j < 4; j++) acc[i][j] = fmaf(a[i], xv[j], acc[i][j]);
        }
        __syncthreads();
    }

#pragma unroll
    for (int i = 0; i < 4; i++) {
        int o = oB + to * 4 + i;
        float bv = bias[o];
#pragma unroll
        for (int m = 0; m < 2; m++) {
            int n0 = nB + tn * 2 + 32 * m;
            float2 st = make_float2(acc[i][2 * m] + bv, acc[i][2 * m + 1] + bv);
            *reinterpret_cast<float2*>(&Y[((size_t)b * O + o) * N_ + n0]) = st;
        }
    }
}

// ---------------------------------------------------------------------------
// bf16 MFMA GEMM (value path: g2 conv, conv4) — global_load_lds (16B) with
// XOR-swizzled per-lane SOURCE addresses + matching swizzled LDS reads
// (linear LDS dest required by gload_lds; same involution both sides).
// ---------------------------------------------------------------------------
__global__ __launch_bounds__(256) void mgemm_kernel(const unsigned short* __restrict__ A,
                                                    const unsigned short* __restrict__ X,
                                                    const float* __restrict__ bias,
                                                    float* __restrict__ Y,
                                                    int O, int C) {
    __shared__ unsigned short At[128 * 64];
    __shared__ unsigned short Bt[128 * 64];
    int b = blockIdx.z;
    int oB = blockIdx.y * 128, nB = blockIdx.x * 128;
    const unsigned short* Xb = X + (size_t)b * N_ * C;
    int tid = threadIdx.x;
    int lane = tid & 63, w = tid >> 6;
    int wm = w & 1, wn = w >> 1;
    int lr = lane & 15, lg = lane >> 4;
    int lrow = lane >> 3;                   // row within 8-row segment (== row&7)
    int lcol = ((lane & 7) ^ lrow) * 8;     // swizzled source elem offset

    f32x4 acc[4][4];
#pragma unroll
    for (int m = 0; m < 4; m++)
#pragma unroll
        for (int n = 0; n < 4; n++) acc[m][n] = (f32x4){0.f, 0.f, 0.f, 0.f};

    for (int c0 = 0; c0 < C; c0 += 64) {
#pragma unroll
        for (int r = 0; r < 4; r++) {
            int seg = r * 4 + w;            // wave-uniform
            int row = seg * 8 + lrow;
            const unsigned short* ga = &A[(size_t)(oB + row) * C + c0 + lcol];
            const unsigned short* gb = &Xb[(size_t)(nB + row) * C + c0 + lcol];
            __builtin_amdgcn_global_load_lds((glb_u32_t*)ga, (lds_u32_t*)&At[seg * 512], 16, 0, 0);
            __builtin_amdgcn_global_load_lds((glb_u32_t*)gb, (lds_u32_t*)&Bt[seg * 512], 16, 0, 0);
        }
        __syncthreads();
#pragma unroll
        for (int kk = 0; kk < 2; kk++) {
            bf16x8 af[4], bfv[4];
#pragma unroll
            for (int m = 0; m < 4; m++) {
                int row = wm * 64 + m * 16 + lr;
                int slot = (kk * 4 + lg) ^ (lr & 7);
                af[m] = *reinterpret_cast<const bf16x8*>(&At[row * 64 + slot * 8]);
            }
#pragma unroll
            for (int n = 0; n < 4; n++) {
                int row = wn * 64 + n * 16 + lr;
                int slot = (kk * 4 + lg) ^ (lr & 7);
                bfv[n] = *reinterpret_cast<const bf16x8*>(&Bt[row * 64 + slot * 8]);
            }
#pragma unroll
            for (int m = 0; m < 4; m++)
#pragma unroll
                for (int n = 0; n < 4; n++)
                    acc[m][n] = __builtin_amdgcn_mfma_f32_16x16x32_bf16(af[m], bfv[n], acc[m][n], 0, 0, 0);
        }
        __syncthreads();
    }

#pragma unroll
    for (int m = 0; m < 4; m++) {
#pragma unroll
        for (int r = 0; r < 4; r++) {
            int o = oB + wm * 64 + m * 16 + lg * 4 + r;
            float bv = bias[o];
#pragma unroll
            for (int n = 0; n < 4; n++) {
                int nv = nB + wn * 64 + n * 16 + lr;
                Y[((size_t)b * O + o) * N_ + nv] = acc[m][n][r] + bv;
            }
        }
    }
}

// ---------------------------------------------------------------------------
// Per-channel BN stats over (B,N)
// ---------------------------------------------------------------------------
__global__ __launch_bounds__(256) void bnstats_kernel(const float* __restrict__ y,
                                                      const float* __restrict__ gm,
                                                      const float* __restrict__ bt,
                                                      float* __restrict__ scale,
                                                      float* __restrict__ shift, int O) {
    int o = blockIdx.x;
    float s = 0.f, s2 = 0.f;
    for (int e = threadIdx.x; e < B_ * N_; e += 256) {
        int b = e >> 11, n = e & (N_ - 1);
        float v = y[((size_t)b * O + o) * N_ + n];
        s += v;
        s2 = fmaf(v, v, s2);
    }
#pragma unroll
    for (int off = 32; off; off >>= 1) {
        s += __shfl_down(s, off, 64);
        s2 += __shfl_down(s2, off, 64);
    }
    __shared__ float red[8];
    int lane = threadIdx.x & 63, w = threadIdx.x >> 6;
    if (lane == 0) { red[w] = s; red[4 + w] = s2; }
    __syncthreads();
    if (threadIdx.x == 0) {
        s = red[0] + red[1] + red[2] + red[3];
        s2 = red[4] + red[5] + red[6] + red[7];
        float mu = s * (1.f / (B_ * N_));
        float var = s2 * (1.f / (B_ * N_)) - mu * mu;
        float inv = 1.f / sqrtf(var + 1e-5f);
        float sc = gm[o] * inv;
        scale[o] = sc;
        shift[o] = fmaf(-mu, sc, bt[o]);
    }
}

// ---------------------------------------------------------------------------
// Apply BN + ReLU in place; optional transposed fp32 (B,N,C) copy.
// ---------------------------------------------------------------------------
__global__ __launch_bounds__(256) void bnapply_kernel(float* __restrict__ y,
                                                      const float* __restrict__ scale,
                                                      const float* __restrict__ shift,
                                                      int oLog, int relu,
                                                      float* __restrict__ ft) {
    size_t i = (size_t)blockIdx.x * 256 + threadIdx.x;
    int n = (int)(i & (N_ - 1));
    size_t t = i >> 11;
    int o = (int)(t & ((1u << oLog) - 1));
    int b = (int)(t >> oLog);
    float v = fmaf(y[i], scale[o], shift[o]);
    if (relu) v = fmaxf(v, 0.f);
    y[i] = v;
    if (ft) ft[(((size_t)b << 11) + n) * (1u << oLog) + o] = v;
}

// ---------------------------------------------------------------------------
// BN apply + ReLU + transpose, fp32 (B,O,N) -> bf16 (B,N,O). 64x64 LDS tile.
// ---------------------------------------------------------------------------
__global__ __launch_bounds__(256) void bnt_kernel(const float* __restrict__ y,
                                                  const float* __restrict__ scale,
                                                  const float* __restrict__ shift,
                                                  unsigned short* __restrict__ ft, int O) {
    __shared__ float tile[64][65];
    int b = blockIdx.z;
    int n0 = blockIdx.x * 64, o0 = blockIdx.y * 64;
    int t = threadIdx.x;
#pragma unroll
    for (int rr = 0; rr < 16; rr++) {
        int ol = rr * 4 + (t >> 6), nl = t & 63;
        float v = y[((size_t)b * O + o0 + ol) * N_ + n0 + nl];
        v = fmaf(v, scale[o0 + ol], shift[o0 + ol]);
        tile[ol][nl] = fmaxf(v, 0.f);
    }
    __syncthreads();
#pragma unroll
    for (int rr = 0; rr < 2; rr++) {
        int e = t + rr * 256;
        int n = e >> 3, og = (e & 7) * 8;
        unsigned short u[8];
#pragma unroll
        for (int j = 0; j < 8; j++) u[j] = f2bf(tile[og + j][n]);
        uint4 pk;
        pk.x = (unsigned)u[0] | ((unsigned)u[1] << 16);
        pk.y = (unsigned)u[2] | ((unsigned)u[3] << 16);
        pk.z = (unsigned)u[4] | ((unsigned)u[5] << 16);
        pk.w = (unsigned)u[6] | ((unsigned)u[7] << 16);
        *reinterpret_cast<uint4*>(&ft[((size_t)b * N_ + n0 + n) * O + o0 + og]) = pk;
    }
}

// ---------------------------------------------------------------------------
// Squared norms per point from (B,C,N) fp32 (ascending-c fma == GEMM order).
// ---------------------------------------------------------------------------
__global__ __launch_bounds__(256) void norms_kernel(const float* __restrict__ h,
                                                    float* __restrict__ nrm, int C) {
    int b = blockIdx.y;
    int i = blockIdx.x * 256 + threadIdx.x;
    const float* hp = h + (size_t)b * C * N_;
    float s = 0.f;
    for (int c = 0; c < C; c++) {
        float v = hp[(size_t)c * N_ + i];
        s = fmaf(v, v, s);
    }
    nrm[(b << 11) + i] = s;
}

// ---------------------------------------------------------------------------
// Top-16 per row of a (4*2048) x 2048 distance block — wave per row,
// sorted-queue extraction (no LDS).
// ---------------------------------------------------------------------------
__global__ __launch_bounds__(256, 4) void topk_kernel(const float* __restrict__ D,
                                                      int* __restrict__ idx) {
    int wave = threadIdx.x >> 6, lane = threadIdx.x & 63;
    int i = blockIdx.x * 4 + wave;
    const float* dp = D + (size_t)i * N_;

    unsigned long long kA[16], kB[16];
#pragma unroll
    for (int t = 0; t < 4; t++) {
        float4 v = *reinterpret_cast<const float4*>(&dp[t * 256 + lane * 4]);
        int j0 = t * 256 + lane * 4;
        kA[t * 4 + 0] = ((unsigned long long)fflip(v.x) << 11) | (unsigned int)(j0 + 0);
        kA[t * 4 + 1] = ((unsigned long long)fflip(v.y) << 11) | (unsigned int)(j0 + 1);
        kA[t * 4 + 2] = ((unsigned long long)fflip(v.z) << 11) | (unsigned int)(j0 + 2);
        kA[t * 4 + 3] = ((unsigned long long)fflip(v.w) << 11) | (unsigned int)(j0 + 3);
    }
#pragma unroll
    for (int t = 4; t < 8; t++) {
        float4 v = *reinterpret_cast<const float4*>(&dp[t * 256 + lane * 4]);
        int j0 = t * 256 + lane * 4;
        kB[(t - 4) * 4 + 0] = ((unsigned long long)fflip(v.x) << 11) | (unsigned int)(j0 + 0);
        kB[(t - 4) * 4 + 1] = ((unsigned long long)fflip(v.y) << 11) | (unsigned int)(j0 + 1);
        kB[(t - 4) * 4 + 2] = ((unsigned long long)fflip(v.z) << 11) | (unsigned int)(j0 + 2);
        kB[(t - 4) * 4 + 3] = ((unsigned long long)fflip(v.w) << 11) | (unsigned int)(j0 + 3);
    }

    unsigned long long q[16];
    TOP16OF32(kA, kB, q);

    int* op = idx + (size_t)i * KNN;
    EXTRACT16(q, op);
}

// ---------------------------------------------------------------------------
// Gather 16 neighbor fp32 rows (B,N,C), max over k -> fp32 (B,N,C).
// ---------------------------------------------------------------------------
__global__ __launch_bounds__(256) void gathermax_kernel(const float* __restrict__ ft,
                                                        const int* __restrict__ idx,
                                                        float* __restrict__ out, int cLog) {
    int C = 1 << cLog;
    int b = blockIdx.y;
    int nb = (blockIdx.x << (8 - cLog)) + (threadIdx.x >> cLog);
    int c = threadIdx.x & (C - 1);
    const int* ip = idx + (((size_t)b << 11) + nb) * KNN;
    float m = -3.4e38f;
#pragma unroll
    for (int k = 0; k < KNN; k++) {
        int j = ip[k];
        m = fmaxf(m, ft[(((size_t)b << 11) + j) * C + c]);
    }
    out[(((size_t)b << 11) + nb) * C + c] = m;
}

// ---------------------------------------------------------------------------
// Gather-max: fp32 (B,N,128) in -> bf16 (B,N,128) out (feeds g2 MFMA only).
// ---------------------------------------------------------------------------
__global__ __launch_bounds__(256) void gmaxh2_kernel(const float* __restrict__ ft,
                                                     const int* __restrict__ idx,
                                                     unsigned short* __restrict__ out) {
    const int C = 128;
    int b = blockIdx.y;
    int nb = blockIdx.x * 16 + (threadIdx.x >> 4);
    int cc = (threadIdx.x & 15) * 8;
    const int* ip = idx + (((size_t)b << 11) + nb) * KNN;
    float m[8];
#pragma unroll
    for (int q = 0; q < 8; q++) m[q] = -3.4e38f;
#pragma unroll
    for (int k = 0; k < KNN; k++) {
        int j = ip[k];
        const float* p = &ft[(((size_t)b << 11) + j) * C + cc];
        float4 a = *reinterpret_cast<const float4*>(p);
        float4 c2 = *reinterpret_cast<const float4*>(p + 4);
        m[0] = fmaxf(m[0], a.x); m[1] = fmaxf(m[1], a.y);
        m[2] = fmaxf(m[2], a.z); m[3] = fmaxf(m[3], a.w);
        m[4] = fmaxf(m[4], c2.x); m[5] = fmaxf(m[5], c2.y);
        m[6] = fmaxf(m[6], c2.z); m[7] = fmaxf(m[7], c2.w);
    }
    unsigned short u[8];
#pragma unroll
    for (int q = 0; q < 8; q++) u[q] = f2bf(m[q]);
    uint4 pk;
    pk.x = (unsigned)u[0] | ((unsigned)u[1] << 16);
    pk.y = (unsigned)u[2] | ((unsigned)u[3] << 16);
    pk.z = (unsigned)u[4] | ((unsigned)u[5] << 16);
    pk.w = (unsigned)u[6] | ((unsigned)u[7] << 16);
    *reinterpret_cast<uint4*>(&out[(((size_t)b << 11) + nb) * C + cc]) = pk;
}

// ---------------------------------------------------------------------------
// fp32 -> bf16 weight conversion
// ---------------------------------------------------------------------------
__global__ __launch_bounds__(256) void wcvt_kernel(const float* __restrict__ w,
                                                   unsigned short* __restrict__ wh, int count) {
    int i = blockIdx.x * 256 + threadIdx.x;
    if (i < count) wh[i] = f2bf(w[i]);
}

// ---------------------------------------------------------------------------
// Final: out[b,o] = max_n (y4[b,o,n]*scale[o]+shift[o])
// ---------------------------------------------------------------------------
__global__ __launch_bounds__(256) void finalmax_kernel(const float* __restrict__ y,
                                                       const float* __restrict__ scale,
                                                       const float* __restrict__ shift,
                                                       float* __restrict__ out) {
    int o = blockIdx.x, b = blockIdx.y;
    float s = scale[o], t = shift[o];
    const float* yp = y + ((size_t)b * 512 + o) * N_;
    float m = -3.4e38f;
    for (int n = threadIdx.x; n < N_; n += 256) m = fmaxf(m, fmaf(yp[n], s, t));
#pragma unroll
    for (int off = 32; off; off >>= 1) m = fmaxf(m, __shfl_down(m, off, 64));
    __shared__ float red[4];
    int lane = threadIdx.x & 63, w = threadIdx.x >> 6;
    if (lane == 0) red[w] = m;
    __syncthreads();
    if (threadIdx.x == 0)
        out[b * 512 + o] = fmaxf(fmaxf(red[0], red[1]), fmaxf(red[2], red[3]));
}

// ---------------------------------------------------------------------------
extern "C" void kernel_launch(void* const* d_in, const int* in_sizes, int n_in,
                              void* d_out, int out_size, void* d_ws, size_t ws_size,
                              hipStream_t stream) {
    const float* x = (const float*)d_in[0];
    const float* W1 = (const float*)d_in[1];
    const float* b1 = (const float*)d_in[2];
    const float* gm1 = (const float*)d_in[3];
    const float* bt1 = (const float*)d_in[4];
    const float* W2 = (const float*)d_in[5];
    const float* b2 = (const float*)d_in[6];
    const float* gm2 = (const float*)d_in[7];
    const float* bt2 = (const float*)d_in[8];
    const float* W3 = (const float*)d_in[9];
    const float* b3 = (const float*)d_in[10];
    const float* gm3 = (const float*)d_in[11];
    const float* bt3 = (const float*)d_in[12];
    const float* Wg1 = (const float*)d_in[13];
    const float* bg1 = (const float*)d_in[14];
    const float* gmg1 = (const float*)d_in[15];
    const float* btg1 = (const float*)d_in[16];
    const float* Wg2 = (const float*)d_in[17];
    const float* bg2 = (const float*)d_in[18];
    const float* gmg2 = (const float*)d_in[19];
    const float* btg2 = (const float*)d_in[20];
    const float* W4 = (const float*)d_in[21];
    const float* b4 = (const float*)d_in[22];
    const float* gm4 = (const float*)d_in[23];
    const float* bt4 = (const float*)d_in[24];
    float* out = (float*)d_out;

    // ---- workspace arena (byte offsets), total 154,214,400 bytes ----
    if (ws_size < 154214400ull) return;
    char* base = (char*)d_ws;
    float* scale = (float*)(base + 0);
    float* shift = (float*)(base + 4096);
    float* nrm = (float*)(base + 8192);
    int* idx = (int*)(base + 73728);
    unsigned short* Wg2h = (unsigned short*)(base + 1122304);
    unsigned short* W4h = (unsigned short*)(base + 1384448);
    // bufD4: 4-batch distance chunk (67.1 MB) — aliases bufL region, written
    // (g2 conv) only AFTER both KNN loops complete.
    float* bufD4 = (float*)(base + 19210240);
    float* bufL = (float*)(base + 19210240);                    // (8,1024,2048) f32
    unsigned short* bufLh = (unsigned short*)(base + 86319104); // (8,2048,1024) bf16
    char* E = base + 119873536;                                 // early region
    float* h0 = (float*)(E + 0);                                // (8,12,2048)
    float* bufA = (float*)(E + 786432);                         // (8,64,2048)
    float* bufB = (float*)(E + 4980736);                        // (8,64,2048)
    float* bufC = (float*)(E + 9175040);                        // (8,2048,64)
    float* bufM1 = (float*)(E + 13369344);                      // (8,128,2048)
    float* bufM2 = (float*)(E + 21757952);                      // (8,2048,128)
    unsigned short* bufM3h = (unsigned short*)(E + 30146560);   // (8,2048,128) bf16
    float* bufY4 = (float*)(E + 0);                             // (8,512,2048) aliases E

    // weight conversion (value-path weights only)
    wcvt_kernel<<<512, 256, 0, stream>>>(Wg2, Wg2h, 1024 * 128);
    wcvt_kernel<<<2048, 256, 0, stream>>>(W4, W4h, 512 * 1024);

    // Stage 0/1: 3D KNN + covariance features
    knn3_kernel<<<dim3(512, 8), 256, 0, stream>>>(x, idx);
    cov_kernel<<<dim3(8, 8), 256, 0, stream>>>(x, idx, h0);

    // conv1: 12 -> 64 (fp32, old path: C=12); raw output, BN1 fused into conv2
    gemm_kernel<<<dim3(16, 1, 8), 256, 0, stream>>>(W1, h0, b1, bufA, 64, 12);
    bnstats_kernel<<<64, 256, 0, stream>>>(bufA, gm1, bt1, scale, shift, 64);

    // conv2: 64 -> 64 (fp32 v2, BN1+ReLU fused on load); raw out, BN2 fused next
    cgemm_kernel<0, 1><<<dim3(32, 1, 8), 256, 0, stream>>>(W2, bufA, b2, bufB, 64, 64, scale, shift);
    bnstats_kernel<<<64, 256, 0, stream>>>(bufB, gm2, bt2, scale, shift, 64);

    // conv3: 64 -> 64 (fp32 v2, BN2+ReLU fused on load) -> raw bufA
    cgemm_kernel<0, 1><<<dim3(32, 1, 8), 256, 0, stream>>>(W3, bufB, b3, bufA, 64, 64, scale, shift);
    bnstats_kernel<<<64, 256, 0, stream>>>(bufA, gm3, bt3, scale, shift, 64);
    bnapply_kernel<<<4096, 256, 0, stream>>>(bufA, scale, shift, 6, 1, bufC);

    // graph layer 1 KNN (C=64, symmetric fp32 distances), 4-batch chunks
    norms_kernel<<<dim3(8, 8), 256, 0, stream>>>(bufA, nrm, 64);
    for (int c = 0; c < 2; c++) {
        dgemm_kernel<<<dim3(136, 1, 4), 256, 0, stream>>>(
            bufA + (size_t)c * 4 * 64 * N_, nrm + (size_t)c * 4 * N_, bufD4, 64);
        topk_kernel<<<2048, 256, 0, stream>>>(bufD4, idx + (size_t)c * 4 * N_ * KNN);
    }
    gathermax_kernel<<<dim3(512, 8), 256, 0, stream>>>(bufC, idx, bufB, 6);

    // conv g1: 64 -> 128 (fp32 v2, input (B,N,64))
    cgemm_kernel<1, 0><<<dim3(32, 2, 8), 256, 0, stream>>>(Wg1, bufB, bg1, bufM1, 128, 64, nullptr, nullptr);
    bnstats_kernel<<<128, 256, 0, stream>>>(bufM1, gmg1, btg1, scale, shift, 128);
    bnapply_kernel<<<8192, 256, 0, stream>>>(bufM1, scale, shift, 7, 1, bufM2);

    // graph layer 2 KNN (C=128, symmetric fp32 distances), 4-batch chunks
    norms_kernel<<<dim3(8, 8), 256, 0, stream>>>(bufM1, nrm, 128);
    for (int c = 0; c < 2; c++) {
        dgemm_kernel<<<dim3(136, 1, 4), 256, 0, stream>>>(
            bufM1 + (size_t)c * 4 * 128 * N_, nrm + (size_t)c * 4 * N_, bufD4, 128);
        topk_kernel<<<2048, 256, 0, stream>>>(bufD4, idx + (size_t)c * 4 * N_ * KNN);
    }
    gmaxh2_kernel<<<dim3(128, 8), 256, 0, stream>>>(bufM2, idx, bufM3h);

    // conv g2: 128 -> 1024 (bf16 MFMA, gload_lds)
    mgemm_kernel<<<dim3(16, 8, 8), 256, 0, stream>>>(Wg2h, bufM3h, bg2, bufL, 1024, 128);
    bnstats_kernel<<<1024, 256, 0, stream>>>(bufL, gmg2, btg2, scale, shift, 1024);
    bnt_kernel<<<dim3(32, 16, 8), 256, 0, stream>>>(bufL, scale, shift, bufLh, 1024);

    // conv4: 1024 -> 512 (bf16 MFMA, gload_lds), BN folded into final max
    mgemm_kernel<<<dim3(16, 4, 8), 256, 0, stream>>>(W4h, bufLh, b4, bufY4, 512, 1024);
    bnstats_kernel<<<512, 256, 0, stream>>>(bufY4, gm4, bt4, scale, shift, 512);
    finalmax_kernel<<<dim3(512, 8), 256, 0, stream>>>(bufY4, scale, shift, out);
}

// Round 10
// 621.131 us; speedup vs baseline: 7.9051x; 1.0608x over previous
//
#include <hip/hip_runtime.h>
#include <math.h>

#define B_ 8
#define N_ 2048
#define KNN 16

typedef __attribute__((ext_vector_type(4))) float f32x4;
typedef __attribute__((ext_vector_type(8))) short bf16x8;
typedef __attribute__((address_space(3))) unsigned int lds_u32_t;
typedef __attribute__((address_space(1))) const unsigned int glb_u32_t;

__device__ inline unsigned short f2bf(float f) {
    unsigned int x = __float_as_uint(f);
    unsigned int r = (x + 0x7fffu + ((x >> 16) & 1u)) >> 16;  // RNE
    return (unsigned short)r;
}

// Monotone bijection fp32 -> u32 (handles negatives; order-preserving).
__device__ inline unsigned int fflip(float f) {
    unsigned int u = __float_as_uint(f);
    return u ^ (0x80000000u | (unsigned int)((int)u >> 31));
}

// 64-bit shuffle-xor across the 64-lane wave.
__device__ inline unsigned long long shflx64(unsigned long long v, int m) {
    int lo = __shfl_xor((int)(unsigned int)(v & 0xffffffffull), m, 64);
    int hi = __shfl_xor((int)(unsigned int)(v >> 32), m, 64);
    return ((unsigned long long)(unsigned int)hi << 32) | (unsigned int)lo;
}

// Compare-exchange: a=min, b=max (u64 keys are unique -> total order).
__device__ inline void ce(unsigned long long& a, unsigned long long& b) {
    bool c = a < b;
    unsigned long long lo = c ? a : b;
    unsigned long long hi = c ? b : a;
    a = lo;
    b = hi;
}

// Bitonic sort 16 (ascending), fully unrolled, static indices only.
#define SORT16(q)                                                         \
    _Pragma("unroll") for (int kk_ = 2; kk_ <= 16; kk_ <<= 1)             \
    _Pragma("unroll") for (int jj_ = kk_ >> 1; jj_ > 0; jj_ >>= 1)        \
    _Pragma("unroll") for (int ii_ = 0; ii_ < 16; ii_++) {                \
        int ll_ = ii_ ^ jj_;                                              \
        if (ll_ > ii_) {                                                  \
            if ((ii_ & kk_) == 0) ce(q[ii_], q[ll_]);                     \
            else ce(q[ll_], q[ii_]);                                      \
        }                                                                 \
    }

// Bitonic merge 16 (input bitonic -> ascending).
#define MERGE16(q)                                                        \
    _Pragma("unroll") for (int jj_ = 8; jj_ > 0; jj_ >>= 1)               \
    _Pragma("unroll") for (int ii_ = 0; ii_ < 16; ii_++) {                \
        int ll_ = ii_ ^ jj_;                                              \
        if (ll_ > ii_) ce(q[ii_], q[ll_]);                                \
    }

// Reduce 32 keys (kA[16], kB[16]) -> q[16] = sorted ascending local top-16.
#define TOP16OF32(kA, kB, q)                                              \
    SORT16(kA);                                                           \
    SORT16(kB);                                                           \
    _Pragma("unroll") for (int ii_ = 0; ii_ < 16; ii_++) {                \
        unsigned long long b_ = kB[15 - ii_];                             \
        q[ii_] = kA[ii_] < b_ ? kA[ii_] : b_;                             \
    }                                                                     \
    MERGE16(q);

// Extract the wave's 16 smallest keys in ascending order.
#define EXTRACT16(q, op)                                                  \
    for (int r_ = 0; r_ < KNN; r_++) {                                    \
        unsigned long long mk_ = q[0];                                    \
        _Pragma("unroll") for (int s_ = 32; s_ > 0; s_ >>= 1) {           \
            unsigned long long ok_ = shflx64(mk_, s_);                    \
            if (ok_ < mk_) mk_ = ok_;                                     \
        }                                                                 \
        if (lane == 0) (op)[r_] = (int)(mk_ & 2047u);                     \
        bool pop_ = (q[0] == mk_);                                        \
        _Pragma("unroll") for (int t_ = 0; t_ < 15; t_++)                 \
            q[t_] = pop_ ? q[t_ + 1] : q[t_];                             \
        q[15] = pop_ ? ~0ull : q[15];                                     \
    }

// ---------------------------------------------------------------------------
// KNN on 3D input points + fused covariance features (h0 (B,12,N)).
// Wave-per-query, sorted-queue extraction; winners are wave-uniform so the
// covariance is computed from LDS-resident coords in identical order to the
// old cov_kernel (bitwise-identical h0).
// ---------------------------------------------------------------------------
__global__ __launch_bounds__(256, 4) void knn3_kernel(const float* __restrict__ x,
                                                      int* __restrict__ idx,
                                                      float* __restrict__ h0) {
    __shared__ float px[N_], py[N_], pz[N_];
    int b = blockIdx.y;
    const float* xb = x + (size_t)b * N_ * 3;
    for (int e = threadIdx.x; e < N_; e += 256) {
        px[e] = xb[e * 3 + 0];
        py[e] = xb[e * 3 + 1];
        pz[e] = xb[e * 3 + 2];
    }
    __syncthreads();

    int wave = threadIdx.x >> 6, lane = threadIdx.x & 63;
    int i = blockIdx.x * 4 + wave;
    float qx = px[i], qy = py[i], qz = pz[i];

    unsigned long long kA[16], kB[16];
#pragma unroll
    for (int t = 0; t < 16; t++) {
        int j = lane + t * 64;
        float dx = px[j] - qx, dy = py[j] - qy, dz = pz[j] - qz;
        float d = dx * dx + dy * dy + dz * dz;
        kA[t] = ((unsigned long long)fflip(d) << 11) | (unsigned int)j;
    }
#pragma unroll
    for (int t = 0; t < 16; t++) {
        int j = lane + (t + 16) * 64;
        float dx = px[j] - qx, dy = py[j] - qy, dz = pz[j] - qz;
        float d = dx * dx + dy * dy + dz * dz;
        kB[t] = ((unsigned long long)fflip(d) << 11) | (unsigned int)j;
    }

    unsigned long long q[16];
    TOP16OF32(kA, kB, q);

    int* op = idx + ((size_t)b * N_ + i) * KNN;
    unsigned int jr[16];
#pragma unroll
    for (int r_ = 0; r_ < KNN; r_++) {
        unsigned long long mk_ = q[0];
#pragma unroll
        for (int s_ = 32; s_ > 0; s_ >>= 1) {
            unsigned long long ok_ = shflx64(mk_, s_);
            if (ok_ < mk_) mk_ = ok_;
        }
        jr[r_] = (unsigned int)(mk_ & 2047u);
        if (lane == 0) op[r_] = (int)jr[r_];
        bool pop_ = (q[0] == mk_);
#pragma unroll
        for (int t_ = 0; t_ < 15; t_++) q[t_] = pop_ ? q[t_ + 1] : q[t_];
        q[15] = pop_ ? ~0ull : q[15];
    }

    // fused covariance (same accumulation order as old cov_kernel)
    float nx[16], ny[16], nz[16];
    float mx = 0.f, my = 0.f, mz = 0.f;
#pragma unroll
    for (int r_ = 0; r_ < 16; r_++) {
        int j = (int)jr[r_];
        nx[r_] = px[j]; ny[r_] = py[j]; nz[r_] = pz[j];
        mx += nx[r_]; my += ny[r_]; mz += nz[r_];
    }
    mx *= (1.f / KNN); my *= (1.f / KNN); mz *= (1.f / KNN);
    float c00 = 0, c01 = 0, c02 = 0, c11 = 0, c12 = 0, c22 = 0;
#pragma unroll
    for (int r_ = 0; r_ < 16; r_++) {
        float dx = nx[r_] - mx, dy = ny[r_] - my, dz = nz[r_] - mz;
        c00 += dx * dx; c01 += dx * dy; c02 += dx * dz;
        c11 += dy * dy; c12 += dy * dz; c22 += dz * dz;
    }
    if (lane == 0) {
        float* hb = h0 + (size_t)b * 12 * N_;
        hb[0 * N_ + i] = qx;
        hb[1 * N_ + i] = qy;
        hb[2 * N_ + i] = qz;
        hb[3 * N_ + i] = c00; hb[4 * N_ + i] = c01; hb[5 * N_ + i] = c02;
        hb[6 * N_ + i] = c01; hb[7 * N_ + i] = c11; hb[8 * N_ + i] = c12;
        hb[9 * N_ + i] = c02; hb[10 * N_ + i] = c12; hb[11 * N_ + i] = c22;
    }
}

// ---------------------------------------------------------------------------
// Old fp32 GEMM (kept only for conv1: C=12 needs bounds checks).
// ---------------------------------------------------------------------------
__global__ __launch_bounds__(256) void gemm_kernel(const float* __restrict__ A,
                                                   const float* __restrict__ X,
                                                   const float* __restrict__ bias,
                                                   float* __restrict__ Y,
                                                   int O, int C) {
    __shared__ float Wt[16][132];
    __shared__ float Xt[16][132];
    const int N = N_;
    int b = blockIdx.z;
    int oB = blockIdx.y * 128, nB = blockIdx.x * 128;
    const float* Xb = X + (size_t)b * C * N;
    int tid = threadIdx.x;
    int tn = tid & 15, to = tid >> 4;

    float acc[8][8];
#pragma unroll
    for (int i = 0; i < 8; i++)
#pragma unroll
        for (int j = 0; j < 8; j++) acc[i][j] = 0.f;

    for (int c0 = 0; c0 < C; c0 += 16) {
#pragma unroll
        for (int r = 0; r < 8; r++) {
            int e = tid + r * 256;
            int k = e & 15, o = e >> 4;
            float v = 0.f;
            if (c0 + k < C && oB + o < O) v = A[(size_t)(oB + o) * C + c0 + k];
            Wt[k][o] = v;
        }
#pragma unroll
        for (int r = 0; r < 8; r++) {
            int e = tid + r * 256;
            int n = e & 127, k = e >> 7;
            float v = 0.f;
            if (c0 + k < C) v = Xb[(size_t)(c0 + k) * N + nB + n];
            Xt[k][n] = v;
        }
        __syncthreads();
#pragma unroll
        for (int k = 0; k < 16; k++) {
            float a[8], xv[8];
#pragma unroll
            for (int i = 0; i < 8; i++) a[i] = Wt[k][to * 8 + i];
#pragma unroll
            for (int m = 0; m < 4; m++) {
                xv[2 * m] = Xt[k][tn * 2 + 32 * m];
                xv[2 * m + 1] = Xt[k][tn * 2 + 32 * m + 1];
            }
#pragma unroll
            for (int i = 0; i < 8; i++)
#pragma unroll
                for (int j = 0; j < 8; j++) acc[i][j] = fmaf(a[i], xv[j], acc[i][j]);
        }
        __syncthreads();
    }

#pragma unroll
    for (int i = 0; i < 8; i++) {
        int o = oB + to * 8 + i;
        if (o >= O) continue;
        float bv = bias[o];
#pragma unroll
        for (int m = 0; m < 4; m++) {
            int n0 = nB + tn * 2 + 32 * m;
            float2 st = make_float2(acc[i][2 * m] + bv, acc[i][2 * m + 1] + bv);
            *reinterpret_cast<float2*>(&Y[((size_t)b * O + o) * N + n0]) = st;
        }
    }
}

// ---------------------------------------------------------------------------
// Symmetric distance GEMM v4: both operands from (z,C,N); float4 micro-tile
// columns (cols tn*4 and 64+tn*4); upper-triangle tiles + mirrored writes.
// Per-element FMA chains identical to v3 -> bitwise-identical D. C%32==0.
// ---------------------------------------------------------------------------
__global__ __launch_bounds__(256, 4) void dgemm_kernel(const float* __restrict__ X,
                                                       const float* __restrict__ nrm,
                                                       float* __restrict__ D,
                                                       int C) {
    __shared__ float Wt[32][132];
    __shared__ float Xt[32][132];
    int bz = blockIdx.z;
    int t = blockIdx.x;
    int bx = (int)((sqrtf(8.f * (float)t + 1.f) - 1.f) * 0.5f);
    while ((bx + 1) * (bx + 2) / 2 <= t) bx++;
    while (bx * (bx + 1) / 2 > t) bx--;
    int by = t - bx * (bx + 1) / 2;  // by <= bx
    int oB = by * 128, nB = bx * 128;
    const float* Xb = X + (size_t)bz * C * N_;
    const float* nb = nrm + (size_t)bz * N_;
    float* Db = D + (size_t)bz * N_ * N_;
    int tid = threadIdx.x;
    int tn = tid & 15, to = tid >> 4;

    float acc[8][8];
#pragma unroll
    for (int i = 0; i < 8; i++)
#pragma unroll
        for (int j = 0; j < 8; j++) acc[i][j] = 0.f;

    for (int c0 = 0; c0 < C; c0 += 32) {
#pragma unroll
        for (int r = 0; r < 4; r++) {
            int e = tid + r * 256;
            int k = e >> 5, n4 = e & 31;
            float4 v = *reinterpret_cast<const float4*>(&Xb[(size_t)(c0 + k) * N_ + oB + n4 * 4]);
            *reinterpret_cast<float4*>(&Wt[k][n4 * 4]) = v;
        }
#pragma unroll
        for (int r = 0; r < 4; r++) {
            int e = tid + r * 256;
            int k = e >> 5, n4 = e & 31;
            float4 v = *reinterpret_cast<const float4*>(&Xb[(size_t)(c0 + k) * N_ + nB + n4 * 4]);
            *reinterpret_cast<float4*>(&Xt[k][n4 * 4]) = v;
        }
        __syncthreads();
#pragma unroll
        for (int k = 0; k < 32; k++) {
            float a[8], xv[8];
            *reinterpret_cast<float4*>(&a[0]) = *reinterpret_cast<const float4*>(&Wt[k][to * 8]);
            *reinterpret_cast<float4*>(&a[4]) = *reinterpret_cast<const float4*>(&Wt[k][to * 8 + 4]);
            *reinterpret_cast<float4*>(&xv[0]) = *reinterpret_cast<const float4*>(&Xt[k][tn * 4]);
            *reinterpret_cast<float4*>(&xv[4]) = *reinterpret_cast<const float4*>(&Xt[k][64 + tn * 4]);
#pragma unroll
            for (int i = 0; i < 8; i++)
#pragma unroll
                for (int j = 0; j < 8; j++) acc[i][j] = fmaf(a[i], xv[j], acc[i][j]);
        }
        __syncthreads();
    }

#pragma unroll
    for (int i = 0; i < 8; i++) {
        int o = oB + to * 8 + i;
        float nr = nb[o];
        int n0 = nB + tn * 4;
        float4 w0, w1;
        w0.x = nr + nb[n0 + 0] - 2.f * acc[i][0];
        w0.y = nr + nb[n0 + 1] - 2.f * acc[i][1];
        w0.z = nr + nb[n0 + 2] - 2.f * acc[i][2];
        w0.w = nr + nb[n0 + 3] - 2.f * acc[i][3];
        w1.x = nr + nb[n0 + 64] - 2.f * acc[i][4];
        w1.y = nr + nb[n0 + 65] - 2.f * acc[i][5];
        w1.z = nr + nb[n0 + 66] - 2.f * acc[i][6];
        w1.w = nr + nb[n0 + 67] - 2.f * acc[i][7];
        *reinterpret_cast<float4*>(&Db[(size_t)o * N_ + n0]) = w0;
        *reinterpret_cast<float4*>(&Db[(size_t)o * N_ + n0 + 64]) = w1;
        acc[i][0] = w0.x; acc[i][1] = w0.y; acc[i][2] = w0.z; acc[i][3] = w0.w;
        acc[i][4] = w1.x; acc[i][5] = w1.y; acc[i][6] = w1.z; acc[i][7] = w1.w;
    }

    if (bx != by) {
        for (int p = 0; p < 4; p++) {
            __syncthreads();
            if ((to >> 2) == p) {
                int rl = (to & 3) * 8;
#pragma unroll
                for (int i = 0; i < 8; i++)
#pragma unroll
                    for (int qj = 0; qj < 4; qj++) {
                        Xt[rl + i][tn * 4 + qj] = acc[i][qj];
                        Xt[rl + i][64 + tn * 4 + qj] = acc[i][4 + qj];
                    }
            }
            __syncthreads();
#pragma unroll
            for (int r = 0; r < 4; r++) {
                int e = tid + r * 256;
                int j = e >> 3, i4 = e & 7;
                float4 v;
                v.x = Xt[i4 * 4 + 0][j];
                v.y = Xt[i4 * 4 + 1][j];
                v.z = Xt[i4 * 4 + 2][j];
                v.w = Xt[i4 * 4 + 3][j];
                *reinterpret_cast<float4*>(&Db[(size_t)(nB + j) * N_ + oB + p * 32 + i4 * 4]) = v;
            }
        }
    }
}

// ---------------------------------------------------------------------------
// Conv fp32 GEMM v3: 64x64 tile, BK=32, float4 micro-tile cols (tn*4).
// FUSE=1 (XLAYOUT 0 only): X-load applies y=relu(fmaf(x,xs[c],xh[c])).
// ---------------------------------------------------------------------------
template <int XLAYOUT, int FUSE>
__global__ __launch_bounds__(256, 4) void cgemm_kernel(const float* __restrict__ A,
                                                       const float* __restrict__ X,
                                                       const float* __restrict__ bias,
                                                       float* __restrict__ Y,
                                                       int O, int C,
                                                       const float* __restrict__ xs,
                                                       const float* __restrict__ xh) {
    __shared__ float Wt[32][68];
    __shared__ float Xt[32][68];
    int b = blockIdx.z;
    int oB = blockIdx.y * 64, nB = blockIdx.x * 64;
    const float* Xb = X + (XLAYOUT == 0 ? (size_t)b * C * N_ : (size_t)b * N_ * C);
    int tid = threadIdx.x;
    int tn = tid & 15, to = tid >> 4;

    float acc[4][4];
#pragma unroll
    for (int i = 0; i < 4; i++)
#pragma unroll
        for (int j = 0; j < 4; j++) acc[i][j] = 0.f;

    for (int c0 = 0; c0 < C; c0 += 32) {
#pragma unroll
        for (int r = 0; r < 2; r++) {
            int e = tid + r * 256;
            int row = e >> 3, c4 = e & 7;
            float4 v = *reinterpret_cast<const float4*>(&A[(size_t)(oB + row) * C + c0 + c4 * 4]);
            Wt[c4 * 4 + 0][row] = v.x;
            Wt[c4 * 4 + 1][row] = v.y;
            Wt[c4 * 4 + 2][row] = v.z;
            Wt[c4 * 4 + 3][row] = v.w;
        }
        if (XLAYOUT == 0) {
#pragma unroll
            for (int r = 0; r < 2; r++) {
                int e = tid + r * 256;
                int k = e >> 4, n4 = e & 15;
                float4 v = *reinterpret_cast<const float4*>(&Xb[(size_t)(c0 + k) * N_ + nB + n4 * 4]);
                if (FUSE) {
                    float sc = xs[c0 + k], sh = xh[c0 + k];
                    v.x = fmaxf(fmaf(v.x, sc, sh), 0.f);
                    v.y = fmaxf(fmaf(v.y, sc, sh), 0.f);
                    v.z = fmaxf(fmaf(v.z, sc, sh), 0.f);
                    v.w = fmaxf(fmaf(v.w, sc, sh), 0.f);
                }
                *reinterpret_cast<float4*>(&Xt[k][n4 * 4]) = v;
            }
        } else {
#pragma unroll
            for (int r = 0; r < 2; r++) {
                int e = tid + r * 256;
                int n = e >> 3, c4 = e & 7;
                float4 v = *reinterpret_cast<const float4*>(&Xb[(size_t)(nB + n) * C + c0 + c4 * 4]);
                Xt[c4 * 4 + 0][n] = v.x;
                Xt[c4 * 4 + 1][n] = v.y;
                Xt[c4 * 4 + 2][n] = v.z;
                Xt[c4 * 4 + 3][n] = v.w;
            }
        }
        __syncthreads();
#pragma unroll
        for (int k = 0; k < 32; k++) {
            float a[4], xv[4];
            *reinterpret_cast<float4*>(&a[0]) = *reinterpret_cast<const float4*>(&Wt[k][to * 4]);
            *reinterpret_cast<float4*>(&xv[0]) = *reinterpret_cast<const float4*>(&Xt[k][tn * 4]);
#pragma unroll
            for (int i = 0; i < 4; i++)
#pragma unroll
                for (int j = 0; j < 4; j++) acc[i][j] = fmaf(a[i], xv[j], acc[i][j]);
        }
        __syncthreads();
    }

#pragma unroll
    for (int i = 0; i < 4; i++) {
        int o = oB + to * 4 + i;
        float bv = bias[o];
        int n0 = nB + tn * 4;
        float4 st;
        st.x = acc[i][0] + bv; st.y = acc[i][1] + bv;
        st.z = acc[i][2] + bv; st.w = acc[i][3] + bv;
        *reinterpret_cast<float4*>(&Y[((size_t)b * O + o) * N_ + n0]) = st;
    }
}

// ---------------------------------------------------------------------------
// bf16 MFMA GEMM (value path). EPI=0: Y = A·X + bias (g2 conv).
// EPI=1 (conv4): no bias (BN absorbs it), no Y write — emits per-block
// (max,min,sum,sumsq) partials over its 128-n slice for each of its 128 o's.
// ---------------------------------------------------------------------------
template <int EPI>
__global__ __launch_bounds__(256) void mgemm_kernel(const unsigned short* __restrict__ A,
                                                    const unsigned short* __restrict__ X,
                                                    const float* __restrict__ bias,
                                                    float* __restrict__ Y,
                                                    int O, int C,
                                                    float* __restrict__ part) {
    __shared__ unsigned short At[128 * 64];
    __shared__ unsigned short Bt[128 * 64];
    int b = blockIdx.z;
    int oB = blockIdx.y * 128, nB = blockIdx.x * 128;
    const unsigned short* Xb = X + (size_t)b * N_ * C;
    int tid = threadIdx.x;
    int lane = tid & 63, w = tid >> 6;
    int wm = w & 1, wn = w >> 1;
    int lr = lane & 15, lg = lane >> 4;
    int lrow = lane >> 3;
    int lcol = ((lane & 7) ^ lrow) * 8;

    f32x4 acc[4][4];
#pragma unroll
    for (int m = 0; m < 4; m++)
#pragma unroll
        for (int n = 0; n < 4; n++) acc[m][n] = (f32x4){0.f, 0.f, 0.f, 0.f};

    for (int c0 = 0; c0 < C; c0 += 64) {
#pragma unroll
        for (int r = 0; r < 4; r++) {
            int seg = r * 4 + w;
            int row = seg * 8 + lrow;
            const unsigned short* ga = &A[(size_t)(oB + row) * C + c0 + lcol];
            const unsigned short* gb = &Xb[(size_t)(nB + row) * C + c0 + lcol];
            __builtin_amdgcn_global_load_lds((glb_u32_t*)ga, (lds_u32_t*)&At[seg * 512], 16, 0, 0);
            __builtin_amdgcn_global_load_lds((glb_u32_t*)gb, (lds_u32_t*)&Bt[seg * 512], 16, 0, 0);
        }
        __syncthreads();
#pragma unroll
        for (int kk = 0; kk < 2; kk++) {
            bf16x8 af[4], bfv[4];
#pragma unroll
            for (int m = 0; m < 4; m++) {
                int row = wm * 64 + m * 16 + lr;
                int slot = (kk * 4 + lg) ^ (lr & 7);
                af[m] = *reinterpret_cast<const bf16x8*>(&At[row * 64 + slot * 8]);
            }
#pragma unroll
            for (int n = 0; n < 4; n++) {
                int row = wn * 64 + n * 16 + lr;
                int slot = (kk * 4 + lg) ^ (lr & 7);
                bfv[n] = *reinterpret_cast<const bf16x8*>(&Bt[row * 64 + slot * 8]);
            }
#pragma unroll
            for (int m = 0; m < 4; m++)
#pragma unroll
                for (int n = 0; n < 4; n++)
                    acc[m][n] = __builtin_amdgcn_mfma_f32_16x16x32_bf16(af[m], bfv[n], acc[m][n], 0, 0, 0);
        }
        __syncthreads();
    }

    if (EPI == 0) {
#pragma unroll
        for (int m = 0; m < 4; m++) {
#pragma unroll
            for (int r = 0; r < 4; r++) {
                int o = oB + wm * 64 + m * 16 + lg * 4 + r;
                float bv = bias[o];
#pragma unroll
                for (int n = 0; n < 4; n++) {
                    int nv = nB + wn * 64 + n * 16 + lr;
                    Y[((size_t)b * O + o) * N_ + nv] = acc[m][n][r] + bv;
                }
            }
        }
    } else {
        __shared__ float sred[2][2][64][4];
#pragma unroll
        for (int m = 0; m < 4; m++) {
#pragma unroll
            for (int r = 0; r < 4; r++) {
                float v0 = acc[m][0][r], v1 = acc[m][1][r];
                float v2 = acc[m][2][r], v3 = acc[m][3][r];
                float mx = fmaxf(fmaxf(v0, v1), fmaxf(v2, v3));
                float mn = fminf(fminf(v0, v1), fminf(v2, v3));
                float s = (v0 + v1) + (v2 + v3);
                float s2 = fmaf(v0, v0, fmaf(v1, v1, fmaf(v2, v2, v3 * v3)));
#pragma unroll
                for (int msk = 1; msk <= 8; msk <<= 1) {
                    mx = fmaxf(mx, __shfl_xor(mx, msk, 64));
                    mn = fminf(mn, __shfl_xor(mn, msk, 64));
                    s += __shfl_xor(s, msk, 64);
                    s2 += __shfl_xor(s2, msk, 64);
                }
                if (lr == 0) {
                    int ol = m * 16 + lg * 4 + r;
                    sred[wm][wn][ol][0] = mx;
                    sred[wm][wn][ol][1] = mn;
                    sred[wm][wn][ol][2] = s;
                    sred[wm][wn][ol][3] = s2;
                }
            }
        }
        __syncthreads();
        if (tid < 128) {
            int wmv = tid >> 6, ol = tid & 63;
            float mx = fmaxf(sred[wmv][0][ol][0], sred[wmv][1][ol][0]);
            float mn = fminf(sred[wmv][0][ol][1], sred[wmv][1][ol][1]);
            float s = sred[wmv][0][ol][2] + sred[wmv][1][ol][2];
            float s2 = sred[wmv][0][ol][3] + sred[wmv][1][ol][3];
            int o = oB + wmv * 64 + ol;
            float* pp = &part[((size_t)(o * 8 + b) * 16 + blockIdx.x) * 4];
            pp[0] = mx; pp[1] = mn; pp[2] = s; pp[3] = s2;
        }
    }
}

// ---------------------------------------------------------------------------
// conv4 finish: per channel o, reduce 8b x 16nb partials -> BN stats; then
// out[b,o] = scale*max + shift (or min if scale<0) — exact (monotone linear).
// ---------------------------------------------------------------------------
__global__ __launch_bounds__(128) void bnmax_kernel(const float* __restrict__ part,
                                                    const float* __restrict__ gm,
                                                    const float* __restrict__ bt,
                                                    float* __restrict__ out) {
    int o = blockIdx.x;
    int t = threadIdx.x;          // 128 = 8 b x 16 nb
    int b = t >> 4, nb = t & 15;
    const float* p = &part[((size_t)(o * 8 + b) * 16 + nb) * 4];
    float mx = p[0], mn = p[1], s = p[2], s2 = p[3];

    float ss = s, ss2 = s2;
#pragma unroll
    for (int msk = 1; msk <= 32; msk <<= 1) {
        ss += __shfl_xor(ss, msk, 64);
        ss2 += __shfl_xor(ss2, msk, 64);
    }
    __shared__ float red[4];
    int wv = t >> 6, lane = t & 63;
    if (lane == 0) { red[wv] = ss; red[2 + wv] = ss2; }
    __syncthreads();
    float S = red[0] + red[1], S2 = red[2] + red[3];
    float mu = S * (1.f / (B_ * N_));
    float var = S2 * (1.f / (B_ * N_)) - mu * mu;
    float inv = 1.f / sqrtf(var + 1e-5f);
    float sc = gm[o] * inv;
    float sh = fmaf(-mu, sc, bt[o]);

#pragma unroll
    for (int msk = 1; msk <= 8; msk <<= 1) {
        mx = fmaxf(mx, __shfl_xor(mx, msk, 64));
        mn = fminf(mn, __shfl_xor(mn, msk, 64));
    }
    if (nb == 0) out[b * 512 + o] = fmaf(sc, sc >= 0.f ? mx : mn, sh);
}

// ---------------------------------------------------------------------------
// Per-channel BN stats over (B,N)
// ---------------------------------------------------------------------------
__global__ __launch_bounds__(256) void bnstats_kernel(const float* __restrict__ y,
                                                      const float* __restrict__ gm,
                                                      const float* __restrict__ bt,
                                                      float* __restrict__ scale,
                                                      float* __restrict__ shift, int O) {
    int o = blockIdx.x;
    float s = 0.f, s2 = 0.f;
    for (int e = threadIdx.x; e < B_ * N_; e += 256) {
        int b = e >> 11, n = e & (N_ - 1);
        float v = y[((size_t)b * O + o) * N_ + n];
        s += v;
        s2 = fmaf(v, v, s2);
    }
#pragma unroll
    for (int off = 32; off; off >>= 1) {
        s += __shfl_down(s, off, 64);
        s2 += __shfl_down(s2, off, 64);
    }
    __shared__ float red[8];
    int lane = threadIdx.x & 63, w = threadIdx.x >> 6;
    if (lane == 0) { red[w] = s; red[4 + w] = s2; }
    __syncthreads();
    if (threadIdx.x == 0) {
        s = red[0] + red[1] + red[2] + red[3];
        s2 = red[4] + red[5] + red[6] + red[7];
        float mu = s * (1.f / (B_ * N_));
        float var = s2 * (1.f / (B_ * N_)) - mu * mu;
        float inv = 1.f / sqrtf(var + 1e-5f);
        float sc = gm[o] * inv;
        scale[o] = sc;
        shift[o] = fmaf(-mu, sc, bt[o]);
    }
}

// ---------------------------------------------------------------------------
// Apply BN + ReLU in place; optional transposed fp32 (B,N,C) copy.
// ---------------------------------------------------------------------------
__global__ __launch_bounds__(256) void bnapply_kernel(float* __restrict__ y,
                                                      const float* __restrict__ scale,
                                                      const float* __restrict__ shift,
                                                      int oLog, int relu,
                                                      float* __restrict__ ft) {
    size_t i = (size_t)blockIdx.x * 256 + threadIdx.x;
    int n = (int)(i & (N_ - 1));
    size_t t = i >> 11;
    int o = (int)(t & ((1u << oLog) - 1));
    int b = (int)(t >> oLog);
    float v = fmaf(y[i], scale[o], shift[o]);
    if (relu) v = fmaxf(v, 0.f);
    y[i] = v;
    if (ft) ft[(((size_t)b << 11) + n) * (1u << oLog) + o] = v;
}

// ---------------------------------------------------------------------------
// BN apply + ReLU + transpose, fp32 (B,O,N) -> bf16 (B,N,O). 64x64 LDS tile.
// ---------------------------------------------------------------------------
__global__ __launch_bounds__(256) void bnt_kernel(const float* __restrict__ y,
                                                  const float* __restrict__ scale,
                                                  const float* __restrict__ shift,
                                                  unsigned short* __restrict__ ft, int O) {
    __shared__ float tile[64][65];
    int b = blockIdx.z;
    int n0 = blockIdx.x * 64, o0 = blockIdx.y * 64;
    int t = threadIdx.x;
#pragma unroll
    for (int rr = 0; rr < 16; rr++) {
        int ol = rr * 4 + (t >> 6), nl = t & 63;
        float v = y[((size_t)b * O + o0 + ol) * N_ + n0 + nl];
        v = fmaf(v, scale[o0 + ol], shift[o0 + ol]);
        tile[ol][nl] = fmaxf(v, 0.f);
    }
    __syncthreads();
#pragma unroll
    for (int rr = 0; rr < 2; rr++) {
        int e = t + rr * 256;
        int n = e >> 3, og = (e & 7) * 8;
        unsigned short u[8];
#pragma unroll
        for (int j = 0; j < 8; j++) u[j] = f2bf(tile[og + j][n]);
        uint4 pk;
        pk.x = (unsigned)u[0] | ((unsigned)u[1] << 16);
        pk.y = (unsigned)u[2] | ((unsigned)u[3] << 16);
        pk.z = (unsigned)u[4] | ((unsigned)u[5] << 16);
        pk.w = (unsigned)u[6] | ((unsigned)u[7] << 16);
        *reinterpret_cast<uint4*>(&ft[((size_t)b * N_ + n0 + n) * O + o0 + og]) = pk;
    }
}

// ---------------------------------------------------------------------------
// Squared norms per point from (B,C,N) fp32 (ascending-c fma == GEMM order).
// ---------------------------------------------------------------------------
__global__ __launch_bounds__(256) void norms_kernel(const float* __restrict__ h,
                                                    float* __restrict__ nrm, int C) {
    int b = blockIdx.y;
    int i = blockIdx.x * 256 + threadIdx.x;
    const float* hp = h + (size_t)b * C * N_;
    float s = 0.f;
    for (int c = 0; c < C; c++) {
        float v = hp[(size_t)c * N_ + i];
        s = fmaf(v, v, s);
    }
    nrm[(b << 11) + i] = s;
}

// ---------------------------------------------------------------------------
// Top-16 per row of a (4*2048) x 2048 distance block — wave per row,
// sorted-queue extraction (no LDS).
// ---------------------------------------------------------------------------
__global__ __launch_bounds__(256, 4) void topk_kernel(const float* __restrict__ D,
                                                      int* __restrict__ idx) {
    int wave = threadIdx.x >> 6, lane = threadIdx.x & 63;
    int i = blockIdx.x * 4 + wave;
    const float* dp = D + (size_t)i * N_;

    unsigned long long kA[16], kB[16];
#pragma unroll
    for (int t = 0; t < 4; t++) {
        float4 v = *reinterpret_cast<const float4*>(&dp[t * 256 + lane * 4]);
        int j0 = t * 256 + lane * 4;
        kA[t * 4 + 0] = ((unsigned long long)fflip(v.x) << 11) | (unsigned int)(j0 + 0);
        kA[t * 4 + 1] = ((unsigned long long)fflip(v.y) << 11) | (unsigned int)(j0 + 1);
        kA[t * 4 + 2] = ((unsigned long long)fflip(v.z) << 11) | (unsigned int)(j0 + 2);
        kA[t * 4 + 3] = ((unsigned long long)fflip(v.w) << 11) | (unsigned int)(j0 + 3);
    }
#pragma unroll
    for (int t = 4; t < 8; t++) {
        float4 v = *reinterpret_cast<const float4*>(&dp[t * 256 + lane * 4]);
        int j0 = t * 256 + lane * 4;
        kB[(t - 4) * 4 + 0] = ((unsigned long long)fflip(v.x) << 11) | (unsigned int)(j0 + 0);
        kB[(t - 4) * 4 + 1] = ((unsigned long long)fflip(v.y) << 11) | (unsigned int)(j0 + 1);
        kB[(t - 4) * 4 + 2] = ((unsigned long long)fflip(v.z) << 11) | (unsigned int)(j0 + 2);
        kB[(t - 4) * 4 + 3] = ((unsigned long long)fflip(v.w) << 11) | (unsigned int)(j0 + 3);
    }

    unsigned long long q[16];
    TOP16OF32(kA, kB, q);

    int* op = idx + (size_t)i * KNN;
    EXTRACT16(q, op);
}

// ---------------------------------------------------------------------------
// Gather 16 neighbor fp32 rows (B,N,C), max over k -> fp32 (B,N,C).
// ---------------------------------------------------------------------------
__global__ __launch_bounds__(256) void gathermax_kernel(const float* __restrict__ ft,
                                                        const int* __restrict__ idx,
                                                        float* __restrict__ out, int cLog) {
    int C = 1 << cLog;
    int b = blockIdx.y;
    int nb = (blockIdx.x << (8 - cLog)) + (threadIdx.x >> cLog);
    int c = threadIdx.x & (C - 1);
    const int* ip = idx + (((size_t)b << 11) + nb) * KNN;
    float m = -3.4e38f;
#pragma unroll
    for (int k = 0; k < KNN; k++) {
        int j = ip[k];
        m = fmaxf(m, ft[(((size_t)b << 11) + j) * C + c]);
    }
    out[(((size_t)b << 11) + nb) * C + c] = m;
}

// ---------------------------------------------------------------------------
// Gather-max: fp32 (B,N,128) in -> bf16 (B,N,128) out (feeds g2 MFMA only).
// ---------------------------------------------------------------------------
__global__ __launch_bounds__(256) void gmaxh2_kernel(const float* __restrict__ ft,
                                                     const int* __restrict__ idx,
                                                     unsigned short* __restrict__ out) {
    const int C = 128;
    int b = blockIdx.y;
    int nb = blockIdx.x * 16 + (threadIdx.x >> 4);
    int cc = (threadIdx.x & 15) * 8;
    const int* ip = idx + (((size_t)b << 11) + nb) * KNN;
    float m[8];
#pragma unroll
    for (int q = 0; q < 8; q++) m[q] = -3.4e38f;
#pragma unroll
    for (int k = 0; k < KNN; k++) {
        int j = ip[k];
        const float* p = &ft[(((size_t)b << 11) + j) * C + cc];
        float4 a = *reinterpret_cast<const float4*>(p);
        float4 c2 = *reinterpret_cast<const float4*>(p + 4);
        m[0] = fmaxf(m[0], a.x); m[1] = fmaxf(m[1], a.y);
        m[2] = fmaxf(m[2], a.z); m[3] = fmaxf(m[3], a.w);
        m[4] = fmaxf(m[4], c2.x); m[5] = fmaxf(m[5], c2.y);
        m[6] = fmaxf(m[6], c2.z); m[7] = fmaxf(m[7], c2.w);
    }
    unsigned short u[8];
#pragma unroll
    for (int q = 0; q < 8; q++) u[q] = f2bf(m[q]);
    uint4 pk;
    pk.x = (unsigned)u[0] | ((unsigned)u[1] << 16);
    pk.y = (unsigned)u[2] | ((unsigned)u[3] << 16);
    pk.z = (unsigned)u[4] | ((unsigned)u[5] << 16);
    pk.w = (unsigned)u[6] | ((unsigned)u[7] << 16);
    *reinterpret_cast<uint4*>(&out[(((size_t)b << 11) + nb) * C + cc]) = pk;
}

// ---------------------------------------------------------------------------
// fp32 -> bf16 weight conversion
// ---------------------------------------------------------------------------
__global__ __launch_bounds__(256) void wcvt_kernel(const float* __restrict__ w,
                                                   unsigned short* __restrict__ wh, int count) {
    int i = blockIdx.x * 256 + threadIdx.x;
    if (i < count) wh[i] = f2bf(w[i]);
}

// ---------------------------------------------------------------------------
extern "C" void kernel_launch(void* const* d_in, const int* in_sizes, int n_in,
                              void* d_out, int out_size, void* d_ws, size_t ws_size,
                              hipStream_t stream) {
    const float* x = (const float*)d_in[0];
    const float* W1 = (const float*)d_in[1];
    const float* b1 = (const float*)d_in[2];
    const float* gm1 = (const float*)d_in[3];
    const float* bt1 = (const float*)d_in[4];
    const float* W2 = (const float*)d_in[5];
    const float* b2 = (const float*)d_in[6];
    const float* gm2 = (const float*)d_in[7];
    const float* bt2 = (const float*)d_in[8];
    const float* W3 = (const float*)d_in[9];
    const float* b3 = (const float*)d_in[10];
    const float* gm3 = (const float*)d_in[11];
    const float* bt3 = (const float*)d_in[12];
    const float* Wg1 = (const float*)d_in[13];
    const float* bg1 = (const float*)d_in[14];
    const float* gmg1 = (const float*)d_in[15];
    const float* btg1 = (const float*)d_in[16];
    const float* Wg2 = (const float*)d_in[17];
    const float* bg2 = (const float*)d_in[18];
    const float* gmg2 = (const float*)d_in[19];
    const float* btg2 = (const float*)d_in[20];
    const float* W4 = (const float*)d_in[21];
    const float* b4 = (const float*)d_in[22];
    const float* gm4 = (const float*)d_in[23];
    const float* bt4 = (const float*)d_in[24];
    float* out = (float*)d_out;
    (void)b4;

    // ---- workspace arena (byte offsets), total 154,214,400 bytes ----
    if (ws_size < 154214400ull) return;
    char* base = (char*)d_ws;
    float* scale = (float*)(base + 0);
    float* shift = (float*)(base + 4096);
    float* nrm = (float*)(base + 8192);
    int* idx = (int*)(base + 73728);
    unsigned short* Wg2h = (unsigned short*)(base + 1122304);
    unsigned short* W4h = (unsigned short*)(base + 1384448);
    // bufD4: 4-batch distance chunk (67.1 MB) — aliases bufL region, written
    // (g2 conv) only AFTER both KNN loops complete.
    float* bufD4 = (float*)(base + 19210240);
    float* bufL = (float*)(base + 19210240);                    // (8,1024,2048) f32
    unsigned short* bufLh = (unsigned short*)(base + 86319104); // (8,2048,1024) bf16
    char* E = base + 119873536;                                 // early region
    float* h0 = (float*)(E + 0);                                // (8,12,2048)
    float* bufA = (float*)(E + 786432);                         // (8,64,2048)
    float* bufB = (float*)(E + 4980736);                        // (8,64,2048)
    float* bufC = (float*)(E + 9175040);                        // (8,2048,64)
    float* bufM1 = (float*)(E + 13369344);                      // (8,128,2048)
    float* bufM2 = (float*)(E + 21757952);                      // (8,2048,128)
    unsigned short* bufM3h = (unsigned short*)(E + 30146560);   // (8,2048,128) bf16
    float* part = (float*)(E + 0);   // conv4 partials (1 MB), E early bufs dead

    // weight conversion (value-path weights only)
    wcvt_kernel<<<512, 256, 0, stream>>>(Wg2, Wg2h, 1024 * 128);
    wcvt_kernel<<<2048, 256, 0, stream>>>(W4, W4h, 512 * 1024);

    // Stage 0/1: 3D KNN + fused covariance features
    knn3_kernel<<<dim3(512, 8), 256, 0, stream>>>(x, idx, h0);

    // conv1: 12 -> 64 (fp32, old path: C=12); raw output, BN1 fused into conv2
    gemm_kernel<<<dim3(16, 1, 8), 256, 0, stream>>>(W1, h0, b1, bufA, 64, 12);
    bnstats_kernel<<<64, 256, 0, stream>>>(bufA, gm1, bt1, scale, shift, 64);

    // conv2: 64 -> 64 (fp32 v3, BN1+ReLU fused on load); raw out, BN2 fused next
    cgemm_kernel<0, 1><<<dim3(32, 1, 8), 256, 0, stream>>>(W2, bufA, b2, bufB, 64, 64, scale, shift);
    bnstats_kernel<<<64, 256, 0, stream>>>(bufB, gm2, bt2, scale, shift, 64);

    // conv3: 64 -> 64 (fp32 v3, BN2+ReLU fused on load) -> raw bufA
    cgemm_kernel<0, 1><<<dim3(32, 1, 8), 256, 0, stream>>>(W3, bufB, b3, bufA, 64, 64, scale, shift);
    bnstats_kernel<<<64, 256, 0, stream>>>(bufA, gm3, bt3, scale, shift, 64);
    bnapply_kernel<<<4096, 256, 0, stream>>>(bufA, scale, shift, 6, 1, bufC);

    // graph layer 1 KNN (C=64, symmetric fp32 distances), 4-batch chunks
    norms_kernel<<<dim3(8, 8), 256, 0, stream>>>(bufA, nrm, 64);
    for (int c = 0; c < 2; c++) {
        dgemm_kernel<<<dim3(136, 1, 4), 256, 0, stream>>>(
            bufA + (size_t)c * 4 * 64 * N_, nrm + (size_t)c * 4 * N_, bufD4, 64);
        topk_kernel<<<2048, 256, 0, stream>>>(bufD4, idx + (size_t)c * 4 * N_ * KNN);
    }
    gathermax_kernel<<<dim3(512, 8), 256, 0, stream>>>(bufC, idx, bufB, 6);

    // conv g1: 64 -> 128 (fp32 v3, input (B,N,64))
    cgemm_kernel<1, 0><<<dim3(32, 2, 8), 256, 0, stream>>>(Wg1, bufB, bg1, bufM1, 128, 64, nullptr, nullptr);
    bnstats_kernel<<<128, 256, 0, stream>>>(bufM1, gmg1, btg1, scale, shift, 128);
    bnapply_kernel<<<8192, 256, 0, stream>>>(bufM1, scale, shift, 7, 1, bufM2);

    // graph layer 2 KNN (C=128, symmetric fp32 distances), 4-batch chunks
    norms_kernel<<<dim3(8, 8), 256, 0, stream>>>(bufM1, nrm, 128);
    for (int c = 0; c < 2; c++) {
        dgemm_kernel<<<dim3(136, 1, 4), 256, 0, stream>>>(
            bufM1 + (size_t)c * 4 * 128 * N_, nrm + (size_t)c * 4 * N_, bufD4, 128);
        topk_kernel<<<2048, 256, 0, stream>>>(bufD4, idx + (size_t)c * 4 * N_ * KNN);
    }
    gmaxh2_kernel<<<dim3(128, 8), 256, 0, stream>>>(bufM2, idx, bufM3h);

    // conv g2: 128 -> 1024 (bf16 MFMA)
    mgemm_kernel<0><<<dim3(16, 8, 8), 256, 0, stream>>>(Wg2h, bufM3h, bg2, bufL, 1024, 128, nullptr);
    bnstats_kernel<<<1024, 256, 0, stream>>>(bufL, gmg2, btg2, scale, shift, 1024);
    bnt_kernel<<<dim3(32, 16, 8), 256, 0, stream>>>(bufL, scale, shift, bufLh, 1024);

    // conv4: 1024 -> 512 (bf16 MFMA, fused BN-stats+max epilogue; bias dropped
    // — BN absorbs it exactly). bnmax finishes stats + writes out.
    mgemm_kernel<1><<<dim3(16, 4, 8), 256, 0, stream>>>(W4h, bufLh, nullptr, nullptr, 512, 1024, part);
    bnmax_kernel<<<512, 128, 0, stream>>>(part, gm4, bt4, out);
}

// Round 11
// 596.269 us; speedup vs baseline: 8.2347x; 1.0417x over previous
//
#include <hip/hip_runtime.h>
#include <math.h>

#define B_ 8
#define N_ 2048
#define KNN 16

typedef __attribute__((ext_vector_type(4))) float f32x4;
typedef __attribute__((ext_vector_type(8))) short bf16x8;
typedef __attribute__((address_space(3))) unsigned int lds_u32_t;
typedef __attribute__((address_space(1))) const unsigned int glb_u32_t;

__device__ inline unsigned short f2bf(float f) {
    unsigned int x = __float_as_uint(f);
    unsigned int r = (x + 0x7fffu + ((x >> 16) & 1u)) >> 16;  // RNE
    return (unsigned short)r;
}

// Monotone bijection fp32 -> u32 (handles negatives; order-preserving).
__device__ inline unsigned int fflip(float f) {
    unsigned int u = __float_as_uint(f);
    return u ^ (0x80000000u | (unsigned int)((int)u >> 31));
}

// 64-bit shuffle-xor across the 64-lane wave.
__device__ inline unsigned long long shflx64(unsigned long long v, int m) {
    int lo = __shfl_xor((int)(unsigned int)(v & 0xffffffffull), m, 64);
    int hi = __shfl_xor((int)(unsigned int)(v >> 32), m, 64);
    return ((unsigned long long)(unsigned int)hi << 32) | (unsigned int)lo;
}

// Compare-exchange: a=min, b=max (u64 keys are unique -> total order).
__device__ inline void ce(unsigned long long& a, unsigned long long& b) {
    bool c = a < b;
    unsigned long long lo = c ? a : b;
    unsigned long long hi = c ? b : a;
    a = lo;
    b = hi;
}

// Bitonic sort 16 (ascending), fully unrolled, static indices only.
#define SORT16(q)                                                         \
    _Pragma("unroll") for (int kk_ = 2; kk_ <= 16; kk_ <<= 1)             \
    _Pragma("unroll") for (int jj_ = kk_ >> 1; jj_ > 0; jj_ >>= 1)        \
    _Pragma("unroll") for (int ii_ = 0; ii_ < 16; ii_++) {                \
        int ll_ = ii_ ^ jj_;                                              \
        if (ll_ > ii_) {                                                  \
            if ((ii_ & kk_) == 0) ce(q[ii_], q[ll_]);                     \
            else ce(q[ll_], q[ii_]);                                      \
        }                                                                 \
    }

// Bitonic merge 16 (input bitonic -> ascending).
#define MERGE16(q)                                                        \
    _Pragma("unroll") for (int jj_ = 8; jj_ > 0; jj_ >>= 1)               \
    _Pragma("unroll") for (int ii_ = 0; ii_ < 16; ii_++) {                \
        int ll_ = ii_ ^ jj_;                                              \
        if (ll_ > ii_) ce(q[ii_], q[ll_]);                                \
    }

// Reduce 32 keys (kA[16], kB[16]) -> q[16] = sorted ascending local top-16.
#define TOP16OF32(kA, kB, q)                                              \
    SORT16(kA);                                                           \
    SORT16(kB);                                                           \
    _Pragma("unroll") for (int ii_ = 0; ii_ < 16; ii_++) {                \
        unsigned long long b_ = kB[15 - ii_];                             \
        q[ii_] = kA[ii_] < b_ ? kA[ii_] : b_;                             \
    }                                                                     \
    MERGE16(q);

// Extract the wave's 16 smallest keys in ascending order.
#define EXTRACT16(q, op)                                                  \
    for (int r_ = 0; r_ < KNN; r_++) {                                    \
        unsigned long long mk_ = q[0];                                    \
        _Pragma("unroll") for (int s_ = 32; s_ > 0; s_ >>= 1) {           \
            unsigned long long ok_ = shflx64(mk_, s_);                    \
            if (ok_ < mk_) mk_ = ok_;                                     \
        }                                                                 \
        if (lane == 0) (op)[r_] = (int)(mk_ & 2047u);                     \
        bool pop_ = (q[0] == mk_);                                        \
        _Pragma("unroll") for (int t_ = 0; t_ < 15; t_++)                 \
            q[t_] = pop_ ? q[t_ + 1] : q[t_];                             \
        q[15] = pop_ ? ~0ull : q[15];                                     \
    }

// ---------------------------------------------------------------------------
// KNN on 3D input points + fused covariance features (h0 (B,12,N)).
// ---------------------------------------------------------------------------
__global__ __launch_bounds__(256, 4) void knn3_kernel(const float* __restrict__ x,
                                                      int* __restrict__ idx,
                                                      float* __restrict__ h0) {
    __shared__ float px[N_], py[N_], pz[N_];
    int b = blockIdx.y;
    const float* xb = x + (size_t)b * N_ * 3;
    for (int e = threadIdx.x; e < N_; e += 256) {
        px[e] = xb[e * 3 + 0];
        py[e] = xb[e * 3 + 1];
        pz[e] = xb[e * 3 + 2];
    }
    __syncthreads();

    int wave = threadIdx.x >> 6, lane = threadIdx.x & 63;
    int i = blockIdx.x * 4 + wave;
    float qx = px[i], qy = py[i], qz = pz[i];

    unsigned long long kA[16], kB[16];
#pragma unroll
    for (int t = 0; t < 16; t++) {
        int j = lane + t * 64;
        float dx = px[j] - qx, dy = py[j] - qy, dz = pz[j] - qz;
        float d = dx * dx + dy * dy + dz * dz;
        kA[t] = ((unsigned long long)fflip(d) << 11) | (unsigned int)j;
    }
#pragma unroll
    for (int t = 0; t < 16; t++) {
        int j = lane + (t + 16) * 64;
        float dx = px[j] - qx, dy = py[j] - qy, dz = pz[j] - qz;
        float d = dx * dx + dy * dy + dz * dz;
        kB[t] = ((unsigned long long)fflip(d) << 11) | (unsigned int)j;
    }

    unsigned long long q[16];
    TOP16OF32(kA, kB, q);

    int* op = idx + ((size_t)b * N_ + i) * KNN;
    unsigned int jr[16];
#pragma unroll
    for (int r_ = 0; r_ < KNN; r_++) {
        unsigned long long mk_ = q[0];
#pragma unroll
        for (int s_ = 32; s_ > 0; s_ >>= 1) {
            unsigned long long ok_ = shflx64(mk_, s_);
            if (ok_ < mk_) mk_ = ok_;
        }
        jr[r_] = (unsigned int)(mk_ & 2047u);
        if (lane == 0) op[r_] = (int)jr[r_];
        bool pop_ = (q[0] == mk_);
#pragma unroll
        for (int t_ = 0; t_ < 15; t_++) q[t_] = pop_ ? q[t_ + 1] : q[t_];
        q[15] = pop_ ? ~0ull : q[15];
    }

    // fused covariance (same accumulation order as the old cov_kernel)
    float nx[16], ny[16], nz[16];
    float mx = 0.f, my = 0.f, mz = 0.f;
#pragma unroll
    for (int r_ = 0; r_ < 16; r_++) {
        int j = (int)jr[r_];
        nx[r_] = px[j]; ny[r_] = py[j]; nz[r_] = pz[j];
        mx += nx[r_]; my += ny[r_]; mz += nz[r_];
    }
    mx *= (1.f / KNN); my *= (1.f / KNN); mz *= (1.f / KNN);
    float c00 = 0, c01 = 0, c02 = 0, c11 = 0, c12 = 0, c22 = 0;
#pragma unroll
    for (int r_ = 0; r_ < 16; r_++) {
        float dx = nx[r_] - mx, dy = ny[r_] - my, dz = nz[r_] - mz;
        c00 += dx * dx; c01 += dx * dy; c02 += dx * dz;
        c11 += dy * dy; c12 += dy * dz; c22 += dz * dz;
    }
    if (lane == 0) {
        float* hb = h0 + (size_t)b * 12 * N_;
        hb[0 * N_ + i] = qx;
        hb[1 * N_ + i] = qy;
        hb[2 * N_ + i] = qz;
        hb[3 * N_ + i] = c00; hb[4 * N_ + i] = c01; hb[5 * N_ + i] = c02;
        hb[6 * N_ + i] = c01; hb[7 * N_ + i] = c11; hb[8 * N_ + i] = c12;
        hb[9 * N_ + i] = c02; hb[10 * N_ + i] = c12; hb[11 * N_ + i] = c22;
    }
}

// ---------------------------------------------------------------------------
// Old fp32 GEMM (kept only for conv1: C=12 needs bounds checks).
// ---------------------------------------------------------------------------
__global__ __launch_bounds__(256) void gemm_kernel(const float* __restrict__ A,
                                                   const float* __restrict__ X,
                                                   const float* __restrict__ bias,
                                                   float* __restrict__ Y,
                                                   int O, int C) {
    __shared__ float Wt[16][132];
    __shared__ float Xt[16][132];
    const int N = N_;
    int b = blockIdx.z;
    int oB = blockIdx.y * 128, nB = blockIdx.x * 128;
    const float* Xb = X + (size_t)b * C * N;
    int tid = threadIdx.x;
    int tn = tid & 15, to = tid >> 4;

    float acc[8][8];
#pragma unroll
    for (int i = 0; i < 8; i++)
#pragma unroll
        for (int j = 0; j < 8; j++) acc[i][j] = 0.f;

    for (int c0 = 0; c0 < C; c0 += 16) {
#pragma unroll
        for (int r = 0; r < 8; r++) {
            int e = tid + r * 256;
            int k = e & 15, o = e >> 4;
            float v = 0.f;
            if (c0 + k < C && oB + o < O) v = A[(size_t)(oB + o) * C + c0 + k];
            Wt[k][o] = v;
        }
#pragma unroll
        for (int r = 0; r < 8; r++) {
            int e = tid + r * 256;
            int n = e & 127, k = e >> 7;
            float v = 0.f;
            if (c0 + k < C) v = Xb[(size_t)(c0 + k) * N + nB + n];
            Xt[k][n] = v;
        }
        __syncthreads();
#pragma unroll
        for (int k = 0; k < 16; k++) {
            float a[8], xv[8];
#pragma unroll
            for (int i = 0; i < 8; i++) a[i] = Wt[k][to * 8 + i];
#pragma unroll
            for (int m = 0; m < 4; m++) {
                xv[2 * m] = Xt[k][tn * 2 + 32 * m];
                xv[2 * m + 1] = Xt[k][tn * 2 + 32 * m + 1];
            }
#pragma unroll
            for (int i = 0; i < 8; i++)
#pragma unroll
                for (int j = 0; j < 8; j++) acc[i][j] = fmaf(a[i], xv[j], acc[i][j]);
        }
        __syncthreads();
    }

#pragma unroll
    for (int i = 0; i < 8; i++) {
        int o = oB + to * 8 + i;
        if (o >= O) continue;
        float bv = bias[o];
#pragma unroll
        for (int m = 0; m < 4; m++) {
            int n0 = nB + tn * 2 + 32 * m;
            float2 st = make_float2(acc[i][2 * m] + bv, acc[i][2 * m + 1] + bv);
            *reinterpret_cast<float2*>(&Y[((size_t)b * O + o) * N + n0]) = st;
        }
    }
}

// ---------------------------------------------------------------------------
// Symmetric distance GEMM v5: both operands from (z,C,N); float4 micro-tile
// cols; upper-triangle tiles + mirrored writes. D stored as PRE-FLIPPED u32
// keys (monotone fp32->u32 bijection) so topk consumes bits directly.
// Mirror path copies bits verbatim. C%32==0.
// ---------------------------------------------------------------------------
__global__ __launch_bounds__(256, 4) void dgemm_kernel(const float* __restrict__ X,
                                                       const float* __restrict__ nrm,
                                                       float* __restrict__ D,
                                                       int C) {
    __shared__ float Wt[32][132];
    __shared__ float Xt[32][132];
    int bz = blockIdx.z;
    int t = blockIdx.x;
    int bx = (int)((sqrtf(8.f * (float)t + 1.f) - 1.f) * 0.5f);
    while ((bx + 1) * (bx + 2) / 2 <= t) bx++;
    while (bx * (bx + 1) / 2 > t) bx--;
    int by = t - bx * (bx + 1) / 2;  // by <= bx
    int oB = by * 128, nB = bx * 128;
    const float* Xb = X + (size_t)bz * C * N_;
    const float* nb = nrm + (size_t)bz * N_;
    float* Db = D + (size_t)bz * N_ * N_;
    int tid = threadIdx.x;
    int tn = tid & 15, to = tid >> 4;

    float acc[8][8];
#pragma unroll
    for (int i = 0; i < 8; i++)
#pragma unroll
        for (int j = 0; j < 8; j++) acc[i][j] = 0.f;

    for (int c0 = 0; c0 < C; c0 += 32) {
#pragma unroll
        for (int r = 0; r < 4; r++) {
            int e = tid + r * 256;
            int k = e >> 5, n4 = e & 31;
            float4 v = *reinterpret_cast<const float4*>(&Xb[(size_t)(c0 + k) * N_ + oB + n4 * 4]);
            *reinterpret_cast<float4*>(&Wt[k][n4 * 4]) = v;
        }
#pragma unroll
        for (int r = 0; r < 4; r++) {
            int e = tid + r * 256;
            int k = e >> 5, n4 = e & 31;
            float4 v = *reinterpret_cast<const float4*>(&Xb[(size_t)(c0 + k) * N_ + nB + n4 * 4]);
            *reinterpret_cast<float4*>(&Xt[k][n4 * 4]) = v;
        }
        __syncthreads();
#pragma unroll
        for (int k = 0; k < 32; k++) {
            float a[8], xv[8];
            *reinterpret_cast<float4*>(&a[0]) = *reinterpret_cast<const float4*>(&Wt[k][to * 8]);
            *reinterpret_cast<float4*>(&a[4]) = *reinterpret_cast<const float4*>(&Wt[k][to * 8 + 4]);
            *reinterpret_cast<float4*>(&xv[0]) = *reinterpret_cast<const float4*>(&Xt[k][tn * 4]);
            *reinterpret_cast<float4*>(&xv[4]) = *reinterpret_cast<const float4*>(&Xt[k][64 + tn * 4]);
#pragma unroll
            for (int i = 0; i < 8; i++)
#pragma unroll
                for (int j = 0; j < 8; j++) acc[i][j] = fmaf(a[i], xv[j], acc[i][j]);
        }
        __syncthreads();
    }

#pragma unroll
    for (int i = 0; i < 8; i++) {
        int o = oB + to * 8 + i;
        float nr = nb[o];
        int n0 = nB + tn * 4;
        float4 w0, w1;
        w0.x = __uint_as_float(fflip(nr + nb[n0 + 0] - 2.f * acc[i][0]));
        w0.y = __uint_as_float(fflip(nr + nb[n0 + 1] - 2.f * acc[i][1]));
        w0.z = __uint_as_float(fflip(nr + nb[n0 + 2] - 2.f * acc[i][2]));
        w0.w = __uint_as_float(fflip(nr + nb[n0 + 3] - 2.f * acc[i][3]));
        w1.x = __uint_as_float(fflip(nr + nb[n0 + 64] - 2.f * acc[i][4]));
        w1.y = __uint_as_float(fflip(nr + nb[n0 + 65] - 2.f * acc[i][5]));
        w1.z = __uint_as_float(fflip(nr + nb[n0 + 66] - 2.f * acc[i][6]));
        w1.w = __uint_as_float(fflip(nr + nb[n0 + 67] - 2.f * acc[i][7]));
        *reinterpret_cast<float4*>(&Db[(size_t)o * N_ + n0]) = w0;
        *reinterpret_cast<float4*>(&Db[(size_t)o * N_ + n0 + 64]) = w1;
        acc[i][0] = w0.x; acc[i][1] = w0.y; acc[i][2] = w0.z; acc[i][3] = w0.w;
        acc[i][4] = w1.x; acc[i][5] = w1.y; acc[i][6] = w1.z; acc[i][7] = w1.w;
    }

    if (bx != by) {
        for (int p = 0; p < 4; p++) {
            __syncthreads();
            if ((to >> 2) == p) {
                int rl = (to & 3) * 8;
#pragma unroll
                for (int i = 0; i < 8; i++)
#pragma unroll
                    for (int qj = 0; qj < 4; qj++) {
                        Xt[rl + i][tn * 4 + qj] = acc[i][qj];
                        Xt[rl + i][64 + tn * 4 + qj] = acc[i][4 + qj];
                    }
            }
            __syncthreads();
#pragma unroll
            for (int r = 0; r < 4; r++) {
                int e = tid + r * 256;
                int j = e >> 3, i4 = e & 7;
                float4 v;
                v.x = Xt[i4 * 4 + 0][j];
                v.y = Xt[i4 * 4 + 1][j];
                v.z = Xt[i4 * 4 + 2][j];
                v.w = Xt[i4 * 4 + 3][j];
                *reinterpret_cast<float4*>(&Db[(size_t)(nB + j) * N_ + oB + p * 32 + i4 * 4]) = v;
            }
        }
    }
}

// ---------------------------------------------------------------------------
// Conv fp32 GEMM v3: 64x64 tile, BK=32, float4 micro-tile cols.
// FUSE=1 (XLAYOUT 0 only): X-load applies y=relu(fmaf(x,xs[c],xh[c])).
// ---------------------------------------------------------------------------
template <int XLAYOUT, int FUSE>
__global__ __launch_bounds__(256, 4) void cgemm_kernel(const float* __restrict__ A,
                                                       const float* __restrict__ X,
                                                       const float* __restrict__ bias,
                                                       float* __restrict__ Y,
                                                       int O, int C,
                                                       const float* __restrict__ xs,
                                                       const float* __restrict__ xh) {
    __shared__ float Wt[32][68];
    __shared__ float Xt[32][68];
    int b = blockIdx.z;
    int oB = blockIdx.y * 64, nB = blockIdx.x * 64;
    const float* Xb = X + (XLAYOUT == 0 ? (size_t)b * C * N_ : (size_t)b * N_ * C);
    int tid = threadIdx.x;
    int tn = tid & 15, to = tid >> 4;

    float acc[4][4];
#pragma unroll
    for (int i = 0; i < 4; i++)
#pragma unroll
        for (int j = 0; j < 4; j++) acc[i][j] = 0.f;

    for (int c0 = 0; c0 < C; c0 += 32) {
#pragma unroll
        for (int r = 0; r < 2; r++) {
            int e = tid + r * 256;
            int row = e >> 3, c4 = e & 7;
            float4 v = *reinterpret_cast<const float4*>(&A[(size_t)(oB + row) * C + c0 + c4 * 4]);
            Wt[c4 * 4 + 0][row] = v.x;
            Wt[c4 * 4 + 1][row] = v.y;
            Wt[c4 * 4 + 2][row] = v.z;
            Wt[c4 * 4 + 3][row] = v.w;
        }
        if (XLAYOUT == 0) {
#pragma unroll
            for (int r = 0; r < 2; r++) {
                int e = tid + r * 256;
                int k = e >> 4, n4 = e & 15;
                float4 v = *reinterpret_cast<const float4*>(&Xb[(size_t)(c0 + k) * N_ + nB + n4 * 4]);
                if (FUSE) {
                    float sc = xs[c0 + k], sh = xh[c0 + k];
                    v.x = fmaxf(fmaf(v.x, sc, sh), 0.f);
                    v.y = fmaxf(fmaf(v.y, sc, sh), 0.f);
                    v.z = fmaxf(fmaf(v.z, sc, sh), 0.f);
                    v.w = fmaxf(fmaf(v.w, sc, sh), 0.f);
                }
                *reinterpret_cast<float4*>(&Xt[k][n4 * 4]) = v;
            }
        } else {
#pragma unroll
            for (int r = 0; r < 2; r++) {
                int e = tid + r * 256;
                int n = e >> 3, c4 = e & 7;
                float4 v = *reinterpret_cast<const float4*>(&Xb[(size_t)(nB + n) * C + c0 + c4 * 4]);
                Xt[c4 * 4 + 0][n] = v.x;
                Xt[c4 * 4 + 1][n] = v.y;
                Xt[c4 * 4 + 2][n] = v.z;
                Xt[c4 * 4 + 3][n] = v.w;
            }
        }
        __syncthreads();
#pragma unroll
        for (int k = 0; k < 32; k++) {
            float a[4], xv[4];
            *reinterpret_cast<float4*>(&a[0]) = *reinterpret_cast<const float4*>(&Wt[k][to * 4]);
            *reinterpret_cast<float4*>(&xv[0]) = *reinterpret_cast<const float4*>(&Xt[k][tn * 4]);
#pragma unroll
            for (int i = 0; i < 4; i++)
#pragma unroll
                for (int j = 0; j < 4; j++) acc[i][j] = fmaf(a[i], xv[j], acc[i][j]);
        }
        __syncthreads();
    }

#pragma unroll
    for (int i = 0; i < 4; i++) {
        int o = oB + to * 4 + i;
        float bv = bias[o];
        int n0 = nB + tn * 4;
        float4 st;
        st.x = acc[i][0] + bv; st.y = acc[i][1] + bv;
        st.z = acc[i][2] + bv; st.w = acc[i][3] + bv;
        *reinterpret_cast<float4*>(&Y[((size_t)b * O + o) * N_ + n0]) = st;
    }
}

// ---------------------------------------------------------------------------
// bf16 MFMA GEMM (value path).
// EPI=1 (conv4): no bias/Y — per-block (max,min,sum,sumsq) partials.
// EPI=2 (g2): Y = transposed fp32 (B,N,O) with bias; per-block (sum,sumsq)
//             partials for the downstream BN.
// ---------------------------------------------------------------------------
template <int EPI>
__global__ __launch_bounds__(256) void mgemm_kernel(const unsigned short* __restrict__ A,
                                                    const unsigned short* __restrict__ X,
                                                    const float* __restrict__ bias,
                                                    float* __restrict__ Y,
                                                    int O, int C,
                                                    float* __restrict__ part) {
    __shared__ unsigned short At[128 * 64];
    __shared__ unsigned short Bt[128 * 64];
    __shared__ float sred[2][2][64][4];
    int b = blockIdx.z;
    int oB = blockIdx.y * 128, nB = blockIdx.x * 128;
    const unsigned short* Xb = X + (size_t)b * N_ * C;
    int tid = threadIdx.x;
    int lane = tid & 63, w = tid >> 6;
    int wm = w & 1, wn = w >> 1;
    int lr = lane & 15, lg = lane >> 4;
    int lrow = lane >> 3;
    int lcol = ((lane & 7) ^ lrow) * 8;

    f32x4 acc[4][4];
#pragma unroll
    for (int m = 0; m < 4; m++)
#pragma unroll
        for (int n = 0; n < 4; n++) acc[m][n] = (f32x4){0.f, 0.f, 0.f, 0.f};

    for (int c0 = 0; c0 < C; c0 += 64) {
#pragma unroll
        for (int r = 0; r < 4; r++) {
            int seg = r * 4 + w;
            int row = seg * 8 + lrow;
            const unsigned short* ga = &A[(size_t)(oB + row) * C + c0 + lcol];
            const unsigned short* gb = &Xb[(size_t)(nB + row) * C + c0 + lcol];
            __builtin_amdgcn_global_load_lds((glb_u32_t*)ga, (lds_u32_t*)&At[seg * 512], 16, 0, 0);
            __builtin_amdgcn_global_load_lds((glb_u32_t*)gb, (lds_u32_t*)&Bt[seg * 512], 16, 0, 0);
        }
        __syncthreads();
#pragma unroll
        for (int kk = 0; kk < 2; kk++) {
            bf16x8 af[4], bfv[4];
#pragma unroll
            for (int m = 0; m < 4; m++) {
                int row = wm * 64 + m * 16 + lr;
                int slot = (kk * 4 + lg) ^ (lr & 7);
                af[m] = *reinterpret_cast<const bf16x8*>(&At[row * 64 + slot * 8]);
            }
#pragma unroll
            for (int n = 0; n < 4; n++) {
                int row = wn * 64 + n * 16 + lr;
                int slot = (kk * 4 + lg) ^ (lr & 7);
                bfv[n] = *reinterpret_cast<const bf16x8*>(&Bt[row * 64 + slot * 8]);
            }
#pragma unroll
            for (int m = 0; m < 4; m++)
#pragma unroll
                for (int n = 0; n < 4; n++)
                    acc[m][n] = __builtin_amdgcn_mfma_f32_16x16x32_bf16(af[m], bfv[n], acc[m][n], 0, 0, 0);
        }
        __syncthreads();
    }

    if (EPI == 1) {
#pragma unroll
        for (int m = 0; m < 4; m++) {
#pragma unroll
            for (int r = 0; r < 4; r++) {
                float v0 = acc[m][0][r], v1 = acc[m][1][r];
                float v2 = acc[m][2][r], v3 = acc[m][3][r];
                float mx = fmaxf(fmaxf(v0, v1), fmaxf(v2, v3));
                float mn = fminf(fminf(v0, v1), fminf(v2, v3));
                float s = (v0 + v1) + (v2 + v3);
                float s2 = fmaf(v0, v0, fmaf(v1, v1, fmaf(v2, v2, v3 * v3)));
#pragma unroll
                for (int msk = 1; msk <= 8; msk <<= 1) {
                    mx = fmaxf(mx, __shfl_xor(mx, msk, 64));
                    mn = fminf(mn, __shfl_xor(mn, msk, 64));
                    s += __shfl_xor(s, msk, 64);
                    s2 += __shfl_xor(s2, msk, 64);
                }
                if (lr == 0) {
                    int ol = m * 16 + lg * 4 + r;
                    sred[wm][wn][ol][0] = mx;
                    sred[wm][wn][ol][1] = mn;
                    sred[wm][wn][ol][2] = s;
                    sred[wm][wn][ol][3] = s2;
                }
            }
        }
        __syncthreads();
        if (tid < 128) {
            int wmv = tid >> 6, ol = tid & 63;
            float mx = fmaxf(sred[wmv][0][ol][0], sred[wmv][1][ol][0]);
            float mn = fminf(sred[wmv][0][ol][1], sred[wmv][1][ol][1]);
            float s = sred[wmv][0][ol][2] + sred[wmv][1][ol][2];
            float s2 = sred[wmv][0][ol][3] + sred[wmv][1][ol][3];
            int o = oB + wmv * 64 + ol;
            float* pp = &part[((size_t)(o * 8 + b) * 16 + blockIdx.x) * 4];
            pp[0] = mx; pp[1] = mn; pp[2] = s; pp[3] = s2;
        }
    } else {
        // EPI == 2: transposed write + (sum,sumsq) partials
#pragma unroll
        for (int m = 0; m < 4; m++) {
            int o0 = oB + wm * 64 + m * 16 + lg * 4;
            float4 bv = *reinterpret_cast<const float4*>(&bias[o0]);
            float s[4] = {0.f, 0.f, 0.f, 0.f};
            float s2[4] = {0.f, 0.f, 0.f, 0.f};
#pragma unroll
            for (int n = 0; n < 4; n++) {
                int nv = nB + wn * 64 + n * 16 + lr;
                float4 st;
                st.x = acc[m][n][0] + bv.x;
                st.y = acc[m][n][1] + bv.y;
                st.z = acc[m][n][2] + bv.z;
                st.w = acc[m][n][3] + bv.w;
                *reinterpret_cast<float4*>(&Y[((size_t)b * N_ + nv) * (size_t)O + o0]) = st;
                s[0] += st.x; s2[0] = fmaf(st.x, st.x, s2[0]);
                s[1] += st.y; s2[1] = fmaf(st.y, st.y, s2[1]);
                s[2] += st.z; s2[2] = fmaf(st.z, st.z, s2[2]);
                s[3] += st.w; s2[3] = fmaf(st.w, st.w, s2[3]);
            }
#pragma unroll
            for (int r = 0; r < 4; r++) {
#pragma unroll
                for (int msk = 1; msk <= 8; msk <<= 1) {
                    s[r] += __shfl_xor(s[r], msk, 64);
                    s2[r] += __shfl_xor(s2[r], msk, 64);
                }
                if (lr == 0) {
                    int ol = m * 16 + lg * 4 + r;
                    sred[wm][wn][ol][0] = s[r];
                    sred[wm][wn][ol][1] = s2[r];
                }
            }
        }
        __syncthreads();
        if (tid < 128) {
            int wmv = tid >> 6, ol = tid & 63;
            float s = sred[wmv][0][ol][0] + sred[wmv][1][ol][0];
            float s2 = sred[wmv][0][ol][1] + sred[wmv][1][ol][1];
            int o = oB + wmv * 64 + ol;
            float* pp = &part[((size_t)(o * 8 + b) * 16 + blockIdx.x) * 2];
            pp[0] = s; pp[1] = s2;
        }
    }
}

// ---------------------------------------------------------------------------
// g2 stats finish: reduce 8b x 16nb (sum,sumsq) partials -> scale/shift.
// ---------------------------------------------------------------------------
__global__ __launch_bounds__(128) void bnfin_kernel(const float* __restrict__ part,
                                                    const float* __restrict__ gm,
                                                    const float* __restrict__ bt,
                                                    float* __restrict__ scale,
                                                    float* __restrict__ shift) {
    int o = blockIdx.x;
    int t = threadIdx.x;  // 128 = 8 b x 16 nb
    const float* p = &part[((size_t)(o * 8 + (t >> 4)) * 16 + (t & 15)) * 2];
    float s = p[0], s2 = p[1];
#pragma unroll
    for (int msk = 1; msk <= 32; msk <<= 1) {
        s += __shfl_xor(s, msk, 64);
        s2 += __shfl_xor(s2, msk, 64);
    }
    __shared__ float red[4];
    int wv = t >> 6, lane = t & 63;
    if (lane == 0) { red[wv] = s; red[2 + wv] = s2; }
    __syncthreads();
    if (t == 0) {
        float S = red[0] + red[1], S2 = red[2] + red[3];
        float mu = S * (1.f / (B_ * N_));
        float var = S2 * (1.f / (B_ * N_)) - mu * mu;
        float inv = 1.f / sqrtf(var + 1e-5f);
        float sc = gm[o] * inv;
        scale[o] = sc;
        shift[o] = fmaf(-mu, sc, bt[o]);
    }
}

// ---------------------------------------------------------------------------
// g2 apply: (B,N,1024) fp32 -> BN+ReLU -> bf16 (B,N,1024). Elementwise.
// ---------------------------------------------------------------------------
__global__ __launch_bounds__(256) void applycvt_kernel(const float* __restrict__ yt,
                                                       const float* __restrict__ scale,
                                                       const float* __restrict__ shift,
                                                       unsigned short* __restrict__ outh) {
    size_t i = ((size_t)blockIdx.x * 256 + threadIdx.x) * 8;
    int o = (int)(i & 1023u);
    float4 a = *reinterpret_cast<const float4*>(&yt[i]);
    float4 c = *reinterpret_cast<const float4*>(&yt[i + 4]);
    float4 s0 = *reinterpret_cast<const float4*>(&scale[o]);
    float4 s1 = *reinterpret_cast<const float4*>(&scale[o + 4]);
    float4 h0 = *reinterpret_cast<const float4*>(&shift[o]);
    float4 h1 = *reinterpret_cast<const float4*>(&shift[o + 4]);
    unsigned short u[8];
    u[0] = f2bf(fmaxf(fmaf(a.x, s0.x, h0.x), 0.f));
    u[1] = f2bf(fmaxf(fmaf(a.y, s0.y, h0.y), 0.f));
    u[2] = f2bf(fmaxf(fmaf(a.z, s0.z, h0.z), 0.f));
    u[3] = f2bf(fmaxf(fmaf(a.w, s0.w, h0.w), 0.f));
    u[4] = f2bf(fmaxf(fmaf(c.x, s1.x, h1.x), 0.f));
    u[5] = f2bf(fmaxf(fmaf(c.y, s1.y, h1.y), 0.f));
    u[6] = f2bf(fmaxf(fmaf(c.z, s1.z, h1.z), 0.f));
    u[7] = f2bf(fmaxf(fmaf(c.w, s1.w, h1.w), 0.f));
    uint4 pk;
    pk.x = (unsigned)u[0] | ((unsigned)u[1] << 16);
    pk.y = (unsigned)u[2] | ((unsigned)u[3] << 16);
    pk.z = (unsigned)u[4] | ((unsigned)u[5] << 16);
    pk.w = (unsigned)u[6] | ((unsigned)u[7] << 16);
    *reinterpret_cast<uint4*>(&outh[i]) = pk;
}

// ---------------------------------------------------------------------------
// conv4 finish: reduce partials -> BN stats; out = scale*max+shift (min if <0).
// ---------------------------------------------------------------------------
__global__ __launch_bounds__(128) void bnmax_kernel(const float* __restrict__ part,
                                                    const float* __restrict__ gm,
                                                    const float* __restrict__ bt,
                                                    float* __restrict__ out) {
    int o = blockIdx.x;
    int t = threadIdx.x;          // 128 = 8 b x 16 nb
    int b = t >> 4, nb = t & 15;
    const float* p = &part[((size_t)(o * 8 + b) * 16 + nb) * 4];
    float mx = p[0], mn = p[1], s = p[2], s2 = p[3];

    float ss = s, ss2 = s2;
#pragma unroll
    for (int msk = 1; msk <= 32; msk <<= 1) {
        ss += __shfl_xor(ss, msk, 64);
        ss2 += __shfl_xor(ss2, msk, 64);
    }
    __shared__ float red[4];
    int wv = t >> 6, lane = t & 63;
    if (lane == 0) { red[wv] = ss; red[2 + wv] = ss2; }
    __syncthreads();
    float S = red[0] + red[1], S2 = red[2] + red[3];
    float mu = S * (1.f / (B_ * N_));
    float var = S2 * (1.f / (B_ * N_)) - mu * mu;
    float inv = 1.f / sqrtf(var + 1e-5f);
    float sc = gm[o] * inv;
    float sh = fmaf(-mu, sc, bt[o]);

#pragma unroll
    for (int msk = 1; msk <= 8; msk <<= 1) {
        mx = fmaxf(mx, __shfl_xor(mx, msk, 64));
        mn = fminf(mn, __shfl_xor(mn, msk, 64));
    }
    if (nb == 0) out[b * 512 + o] = fmaf(sc, sc >= 0.f ? mx : mn, sh);
}

// ---------------------------------------------------------------------------
// Per-channel BN stats over (B,N)
// ---------------------------------------------------------------------------
__global__ __launch_bounds__(256) void bnstats_kernel(const float* __restrict__ y,
                                                      const float* __restrict__ gm,
                                                      const float* __restrict__ bt,
                                                      float* __restrict__ scale,
                                                      float* __restrict__ shift, int O) {
    int o = blockIdx.x;
    float s = 0.f, s2 = 0.f;
    for (int e = threadIdx.x; e < B_ * N_; e += 256) {
        int b = e >> 11, n = e & (N_ - 1);
        float v = y[((size_t)b * O + o) * N_ + n];
        s += v;
        s2 = fmaf(v, v, s2);
    }
#pragma unroll
    for (int off = 32; off; off >>= 1) {
        s += __shfl_down(s, off, 64);
        s2 += __shfl_down(s2, off, 64);
    }
    __shared__ float red[8];
    int lane = threadIdx.x & 63, w = threadIdx.x >> 6;
    if (lane == 0) { red[w] = s; red[4 + w] = s2; }
    __syncthreads();
    if (threadIdx.x == 0) {
        s = red[0] + red[1] + red[2] + red[3];
        s2 = red[4] + red[5] + red[6] + red[7];
        float mu = s * (1.f / (B_ * N_));
        float var = s2 * (1.f / (B_ * N_)) - mu * mu;
        float inv = 1.f / sqrtf(var + 1e-5f);
        float sc = gm[o] * inv;
        scale[o] = sc;
        shift[o] = fmaf(-mu, sc, bt[o]);
    }
}

// ---------------------------------------------------------------------------
// Apply BN + ReLU in place; optional transposed fp32 (B,N,C) copy.
// ---------------------------------------------------------------------------
__global__ __launch_bounds__(256) void bnapply_kernel(float* __restrict__ y,
                                                      const float* __restrict__ scale,
                                                      const float* __restrict__ shift,
                                                      int oLog, int relu,
                                                      float* __restrict__ ft) {
    size_t i = (size_t)blockIdx.x * 256 + threadIdx.x;
    int n = (int)(i & (N_ - 1));
    size_t t = i >> 11;
    int o = (int)(t & ((1u << oLog) - 1));
    int b = (int)(t >> oLog);
    float v = fmaf(y[i], scale[o], shift[o]);
    if (relu) v = fmaxf(v, 0.f);
    y[i] = v;
    if (ft) ft[(((size_t)b << 11) + n) * (1u << oLog) + o] = v;
}

// ---------------------------------------------------------------------------
// Squared norms per point from (B,C,N) fp32 (ascending-c fma == GEMM order).
// ---------------------------------------------------------------------------
__global__ __launch_bounds__(256) void norms_kernel(const float* __restrict__ h,
                                                    float* __restrict__ nrm, int C) {
    int b = blockIdx.y;
    int i = blockIdx.x * 256 + threadIdx.x;
    const float* hp = h + (size_t)b * C * N_;
    float s = 0.f;
    for (int c = 0; c < C; c++) {
        float v = hp[(size_t)c * N_ + i];
        s = fmaf(v, v, s);
    }
    nrm[(b << 11) + i] = s;
}

// ---------------------------------------------------------------------------
// Top-16 per row of a (4*2048) x 2048 distance block (PRE-FLIPPED u32 keys).
// ---------------------------------------------------------------------------
__global__ __launch_bounds__(256, 4) void topk_kernel(const float* __restrict__ D,
                                                      int* __restrict__ idx) {
    int wave = threadIdx.x >> 6, lane = threadIdx.x & 63;
    int i = blockIdx.x * 4 + wave;
    const unsigned int* dp = (const unsigned int*)(D + (size_t)i * N_);

    unsigned long long kA[16], kB[16];
#pragma unroll
    for (int t = 0; t < 4; t++) {
        uint4 v = *reinterpret_cast<const uint4*>(&dp[t * 256 + lane * 4]);
        int j0 = t * 256 + lane * 4;
        kA[t * 4 + 0] = ((unsigned long long)v.x << 11) | (unsigned int)(j0 + 0);
        kA[t * 4 + 1] = ((unsigned long long)v.y << 11) | (unsigned int)(j0 + 1);
        kA[t * 4 + 2] = ((unsigned long long)v.z << 11) | (unsigned int)(j0 + 2);
        kA[t * 4 + 3] = ((unsigned long long)v.w << 11) | (unsigned int)(j0 + 3);
    }
#pragma unroll
    for (int t = 4; t < 8; t++) {
        uint4 v = *reinterpret_cast<const uint4*>(&dp[t * 256 + lane * 4]);
        int j0 = t * 256 + lane * 4;
        kB[(t - 4) * 4 + 0] = ((unsigned long long)v.x << 11) | (unsigned int)(j0 + 0);
        kB[(t - 4) * 4 + 1] = ((unsigned long long)v.y << 11) | (unsigned int)(j0 + 1);
        kB[(t - 4) * 4 + 2] = ((unsigned long long)v.z << 11) | (unsigned int)(j0 + 2);
        kB[(t - 4) * 4 + 3] = ((unsigned long long)v.w << 11) | (unsigned int)(j0 + 3);
    }

    unsigned long long q[16];
    TOP16OF32(kA, kB, q);

    int* op = idx + (size_t)i * KNN;
    EXTRACT16(q, op);
}

// ---------------------------------------------------------------------------
// Gather 16 neighbor fp32 rows (B,N,C), max over k -> fp32 (B,N,C).
// ---------------------------------------------------------------------------
__global__ __launch_bounds__(256) void gathermax_kernel(const float* __restrict__ ft,
                                                        const int* __restrict__ idx,
                                                        float* __restrict__ out, int cLog) {
    int C = 1 << cLog;
    int b = blockIdx.y;
    int nb = (blockIdx.x << (8 - cLog)) + (threadIdx.x >> cLog);
    int c = threadIdx.x & (C - 1);
    const int* ip = idx + (((size_t)b << 11) + nb) * KNN;
    float m = -3.4e38f;
#pragma unroll
    for (int k = 0; k < KNN; k++) {
        int j = ip[k];
        m = fmaxf(m, ft[(((size_t)b << 11) + j) * C + c]);
    }
    out[(((size_t)b << 11) + nb) * C + c] = m;
}

// ---------------------------------------------------------------------------
// Gather-max: fp32 (B,N,128) in -> bf16 (B,N,128) out (feeds g2 MFMA only).
// ---------------------------------------------------------------------------
__global__ __launch_bounds__(256) void gmaxh2_kernel(const float* __restrict__ ft,
                                                     const int* __restrict__ idx,
                                                     unsigned short* __restrict__ out) {
    const int C = 128;
    int b = blockIdx.y;
    int nb = blockIdx.x * 16 + (threadIdx.x >> 4);
    int cc = (threadIdx.x & 15) * 8;
    const int* ip = idx + (((size_t)b << 11) + nb) * KNN;
    float m[8];
#pragma unroll
    for (int q = 0; q < 8; q++) m[q] = -3.4e38f;
#pragma unroll
    for (int k = 0; k < KNN; k++) {
        int j = ip[k];
        const float* p = &ft[(((size_t)b << 11) + j) * C + cc];
        float4 a = *reinterpret_cast<const float4*>(p);
        float4 c2 = *reinterpret_cast<const float4*>(p + 4);
        m[0] = fmaxf(m[0], a.x); m[1] = fmaxf(m[1], a.y);
        m[2] = fmaxf(m[2], a.z); m[3] = fmaxf(m[3], a.w);
        m[4] = fmaxf(m[4], c2.x); m[5] = fmaxf(m[5], c2.y);
        m[6] = fmaxf(m[6], c2.z); m[7] = fmaxf(m[7], c2.w);
    }
    unsigned short u[8];
#pragma unroll
    for (int q = 0; q < 8; q++) u[q] = f2bf(m[q]);
    uint4 pk;
    pk.x = (unsigned)u[0] | ((unsigned)u[1] << 16);
    pk.y = (unsigned)u[2] | ((unsigned)u[3] << 16);
    pk.z = (unsigned)u[4] | ((unsigned)u[5] << 16);
    pk.w = (unsigned)u[6] | ((unsigned)u[7] << 16);
    *reinterpret_cast<uint4*>(&out[(((size_t)b << 11) + nb) * C + cc]) = pk;
}

// ---------------------------------------------------------------------------
// fp32 -> bf16 weight conversion (both value-path weight arrays, one launch)
// ---------------------------------------------------------------------------
__global__ __launch_bounds__(256) void wcvt2_kernel(const float* __restrict__ w1,
                                                    unsigned short* __restrict__ o1, int c1,
                                                    const float* __restrict__ w2,
                                                    unsigned short* __restrict__ o2, int c2) {
    int i = blockIdx.x * 256 + threadIdx.x;
    if (i < c1) o1[i] = f2bf(w1[i]);
    else if (i < c1 + c2) o2[i - c1] = f2bf(w2[i - c1]);
}

// ---------------------------------------------------------------------------
extern "C" void kernel_launch(void* const* d_in, const int* in_sizes, int n_in,
                              void* d_out, int out_size, void* d_ws, size_t ws_size,
                              hipStream_t stream) {
    const float* x = (const float*)d_in[0];
    const float* W1 = (const float*)d_in[1];
    const float* b1 = (const float*)d_in[2];
    const float* gm1 = (const float*)d_in[3];
    const float* bt1 = (const float*)d_in[4];
    const float* W2 = (const float*)d_in[5];
    const float* b2 = (const float*)d_in[6];
    const float* gm2 = (const float*)d_in[7];
    const float* bt2 = (const float*)d_in[8];
    const float* W3 = (const float*)d_in[9];
    const float* b3 = (const float*)d_in[10];
    const float* gm3 = (const float*)d_in[11];
    const float* bt3 = (const float*)d_in[12];
    const float* Wg1 = (const float*)d_in[13];
    const float* bg1 = (const float*)d_in[14];
    const float* gmg1 = (const float*)d_in[15];
    const float* btg1 = (const float*)d_in[16];
    const float* Wg2 = (const float*)d_in[17];
    const float* bg2 = (const float*)d_in[18];
    const float* gmg2 = (const float*)d_in[19];
    const float* btg2 = (const float*)d_in[20];
    const float* W4 = (const float*)d_in[21];
    const float* b4 = (const float*)d_in[22];
    const float* gm4 = (const float*)d_in[23];
    const float* bt4 = (const float*)d_in[24];
    float* out = (float*)d_out;
    (void)b4;

    // ---- workspace arena (byte offsets), total 154,214,400 bytes ----
    if (ws_size < 154214400ull) return;
    char* base = (char*)d_ws;
    float* scale = (float*)(base + 0);
    float* shift = (float*)(base + 4096);
    float* nrm = (float*)(base + 8192);
    int* idx = (int*)(base + 73728);
    unsigned short* Wg2h = (unsigned short*)(base + 1122304);
    unsigned short* W4h = (unsigned short*)(base + 1384448);
    // bufD4 (distance keys) / bufLt (g2 transposed fp32 out) share the region:
    // bufD4 dead after the last topk; bufLt written by g2 mgemm afterward.
    float* bufD4 = (float*)(base + 19210240);
    float* bufLt = (float*)(base + 19210240);                   // (8,2048,1024) f32
    unsigned short* bufLh = (unsigned short*)(base + 86319104); // (8,2048,1024) bf16
    char* E = base + 119873536;                                 // early region
    float* h0 = (float*)(E + 0);                                // (8,12,2048)
    float* bufA = (float*)(E + 786432);                         // (8,64,2048)
    float* bufB = (float*)(E + 4980736);                        // (8,64,2048)
    float* bufC = (float*)(E + 9175040);                        // (8,2048,64)
    float* bufM1 = (float*)(E + 13369344);                      // (8,128,2048)
    float* bufM2 = (float*)(E + 21757952);                      // (8,2048,128)
    unsigned short* bufM3h = (unsigned short*)(E + 30146560);   // (8,2048,128) bf16
    float* part = (float*)(E + 0);   // partials (<=1 MB), early bufs dead by g2

    // weight conversion (value-path weights, single launch)
    wcvt2_kernel<<<2560, 256, 0, stream>>>(Wg2, Wg2h, 1024 * 128, W4, W4h, 512 * 1024);

    // Stage 0/1: 3D KNN + fused covariance features
    knn3_kernel<<<dim3(512, 8), 256, 0, stream>>>(x, idx, h0);

    // conv1: 12 -> 64 (fp32); raw output, BN1 fused into conv2
    gemm_kernel<<<dim3(16, 1, 8), 256, 0, stream>>>(W1, h0, b1, bufA, 64, 12);
    bnstats_kernel<<<64, 256, 0, stream>>>(bufA, gm1, bt1, scale, shift, 64);

    // conv2: 64 -> 64 (BN1+ReLU fused on load); raw out, BN2 fused next
    cgemm_kernel<0, 1><<<dim3(32, 1, 8), 256, 0, stream>>>(W2, bufA, b2, bufB, 64, 64, scale, shift);
    bnstats_kernel<<<64, 256, 0, stream>>>(bufB, gm2, bt2, scale, shift, 64);

    // conv3: 64 -> 64 (BN2+ReLU fused on load) -> raw bufA
    cgemm_kernel<0, 1><<<dim3(32, 1, 8), 256, 0, stream>>>(W3, bufB, b3, bufA, 64, 64, scale, shift);
    bnstats_kernel<<<64, 256, 0, stream>>>(bufA, gm3, bt3, scale, shift, 64);
    bnapply_kernel<<<4096, 256, 0, stream>>>(bufA, scale, shift, 6, 1, bufC);

    // graph layer 1 KNN (C=64, symmetric fp32 distances), 4-batch chunks
    norms_kernel<<<dim3(8, 8), 256, 0, stream>>>(bufA, nrm, 64);
    for (int c = 0; c < 2; c++) {
        dgemm_kernel<<<dim3(136, 1, 4), 256, 0, stream>>>(
            bufA + (size_t)c * 4 * 64 * N_, nrm + (size_t)c * 4 * N_, bufD4, 64);
        topk_kernel<<<2048, 256, 0, stream>>>(bufD4, idx + (size_t)c * 4 * N_ * KNN);
    }
    gathermax_kernel<<<dim3(512, 8), 256, 0, stream>>>(bufC, idx, bufB, 6);

    // conv g1: 64 -> 128 (input (B,N,64))
    cgemm_kernel<1, 0><<<dim3(32, 2, 8), 256, 0, stream>>>(Wg1, bufB, bg1, bufM1, 128, 64, nullptr, nullptr);
    bnstats_kernel<<<128, 256, 0, stream>>>(bufM1, gmg1, btg1, scale, shift, 128);
    bnapply_kernel<<<8192, 256, 0, stream>>>(bufM1, scale, shift, 7, 1, bufM2);

    // graph layer 2 KNN (C=128, symmetric fp32 distances), 4-batch chunks
    norms_kernel<<<dim3(8, 8), 256, 0, stream>>>(bufM1, nrm, 128);
    for (int c = 0; c < 2; c++) {
        dgemm_kernel<<<dim3(136, 1, 4), 256, 0, stream>>>(
            bufM1 + (size_t)c * 4 * 128 * N_, nrm + (size_t)c * 4 * N_, bufD4, 128);
        topk_kernel<<<2048, 256, 0, stream>>>(bufD4, idx + (size_t)c * 4 * N_ * KNN);
    }
    gmaxh2_kernel<<<dim3(128, 8), 256, 0, stream>>>(bufM2, idx, bufM3h);

    // conv g2: 128 -> 1024 (bf16 MFMA, transposed fp32 out + fused stats)
    mgemm_kernel<2><<<dim3(16, 8, 8), 256, 0, stream>>>(Wg2h, bufM3h, bg2, bufLt, 1024, 128, part);
    bnfin_kernel<<<1024, 128, 0, stream>>>(part, gmg2, btg2, scale, shift);
    applycvt_kernel<<<8192, 256, 0, stream>>>(bufLt, scale, shift, bufLh);

    // conv4: 1024 -> 512 (bf16 MFMA, fused BN-stats+max epilogue)
    mgemm_kernel<1><<<dim3(16, 4, 8), 256, 0, stream>>>(W4h, bufLh, nullptr, nullptr, 512, 1024, part);
    bnmax_kernel<<<512, 128, 0, stream>>>(part, gm4, bt4, out);
}